// Round 2
// baseline (2267.041 us; speedup 1.0000x reference)
//
#include <hip/hip_runtime.h>
#include <hip/hip_bf16.h>

typedef __attribute__((ext_vector_type(8))) short short8;        // 8 bf16 = 4 VGPRs
typedef __attribute__((ext_vector_type(8))) unsigned short ushort8;
typedef __attribute__((ext_vector_type(4))) float f32x4;
typedef __attribute__((ext_vector_type(4))) unsigned int u32x4;

#define DEV __device__ __forceinline__

DEV float gelu_f(float x) { return 0.5f * x * (1.f + erff(x * 0.70710678118654752440f)); }

DEV float bf2f(unsigned short s) {
  unsigned int t = ((unsigned int)s) << 16;
  float f; __builtin_memcpy(&f, &t, 4); return f;
}
DEV unsigned short f2bf(float f) {
  __hip_bfloat16 b = __float2bfloat16(f);
  unsigned short s; __builtin_memcpy(&s, &b, 2); return s;
}

// block-wide (256 thr) sum of two values; every thread gets the totals
DEV void block_reduce2(float& s, float& s2) {
  __shared__ float red[8];
  int tid = threadIdx.x;
#pragma unroll
  for (int o = 32; o > 0; o >>= 1) { s += __shfl_down(s, o); s2 += __shfl_down(s2, o); }
  if ((tid & 63) == 0) { red[tid >> 6] = s; red[4 + (tid >> 6)] = s2; }
  __syncthreads();
  s  = red[0] + red[1] + red[2] + red[3];
  s2 = red[4] + red[5] + red[6] + red[7];
}

// ---------------- weight fp32 -> bf16 ----------------
__global__ __launch_bounds__(256) void f2b_kernel(const float* __restrict__ in,
                                                  __hip_bfloat16* __restrict__ o, int n) {
  int i = blockIdx.x * 256 + threadIdx.x;
  if (i < n) o[i] = __float2bfloat16(in[i]);
}

// ---------------- LN1 + cyclic shift + window partition -> bf16 ----------------
__global__ __launch_bounds__(256) void ln1_window_kernel(
    const float* __restrict__ x, const float* __restrict__ w, const float* __restrict__ b,
    __hip_bfloat16* __restrict__ xw) {
  int t = blockIdx.x;                 // 0..25087
  int b_ = t / 49, n = t % 49;
  int bb = b_ >> 8, win = b_ & 255;
  int wi = win >> 4, wj = win & 15;
  int ii = n / 7, jj = n % 7;
  int sh = (wi * 7 + ii + 3) % 112;
  int sw = (wj * 7 + jj + 3) % 112;
  const float* row = x + ((size_t)bb * 12544 + sh * 112 + sw) * 512;
  int tid = threadIdx.x;
  float v0 = row[tid], v1 = row[tid + 256];
  float s = v0 + v1, s2 = v0 * v0 + v1 * v1;
  block_reduce2(s, s2);
  float mu = s * (1.f / 512.f);
  float rstd = rsqrtf(s2 * (1.f / 512.f) - mu * mu + 1e-5f);
  __hip_bfloat16* orow = xw + (size_t)t * 512;
  orow[tid]       = __float2bfloat16((v0 - mu) * rstd * w[tid] + b[tid]);
  orow[tid + 256] = __float2bfloat16((v1 - mu) * rstd * w[tid + 256] + b[tid + 256]);
}

// ---------------- generic bf16 MFMA GEMM:  C = A(MxK) @ B(NxK)^T + bias ----------------
// EPI: 1 = bias -> bf16 store ; 2 = bias+gelu -> bf16 ; 3 = bias -> f32 +=
template <int EPI>
__global__ __launch_bounds__(256) void gemm_bt(
    const __hip_bfloat16* __restrict__ A, const __hip_bfloat16* __restrict__ B,
    const float* __restrict__ bias, float* __restrict__ outF,
    __hip_bfloat16* __restrict__ outB, int M, int N, int K) {
  __shared__ __align__(16) __hip_bfloat16 As[128][72];   // 64 data + 8 pad
  __shared__ __align__(16) __hip_bfloat16 Bs[128][72];
  int m0 = blockIdx.x * 128, n0 = blockIdx.y * 128;
  int tid = threadIdx.x;
  int wave = tid >> 6, lane = tid & 63;
  int wm = (wave & 1) * 64, wn = (wave >> 1) * 64;
  int lrow = lane & 15, kq = lane >> 4;
  f32x4 acc[4][4] = {};
  for (int k0 = 0; k0 < K; k0 += 64) {
#pragma unroll
    for (int i = 0; i < 4; i++) {
      int chunk = tid + i * 256;
      int row = chunk >> 3, c8 = chunk & 7;
      *reinterpret_cast<u32x4*>(&As[row][c8 * 8]) =
          *reinterpret_cast<const u32x4*>(&A[(size_t)(m0 + row) * K + k0 + c8 * 8]);
      *reinterpret_cast<u32x4*>(&Bs[row][c8 * 8]) =
          *reinterpret_cast<const u32x4*>(&B[(size_t)(n0 + row) * K + k0 + c8 * 8]);
    }
    __syncthreads();
#pragma unroll
    for (int ks = 0; ks < 2; ks++) {
      short8 af[4], bf[4];
#pragma unroll
      for (int t = 0; t < 4; t++) {
        af[t] = *reinterpret_cast<const short8*>(&As[wm + t * 16 + lrow][ks * 32 + kq * 8]);
        bf[t] = *reinterpret_cast<const short8*>(&Bs[wn + t * 16 + lrow][ks * 32 + kq * 8]);
      }
#pragma unroll
      for (int tm = 0; tm < 4; tm++)
#pragma unroll
        for (int tn = 0; tn < 4; tn++)
          acc[tm][tn] = __builtin_amdgcn_mfma_f32_16x16x32_bf16(af[tm], bf[tn], acc[tm][tn], 0, 0, 0);
    }
    __syncthreads();
  }
  // D: row=(lane>>4)*4+r, col=lane&15 (verified gfx950 C/D layout)
#pragma unroll
  for (int tm = 0; tm < 4; tm++) {
#pragma unroll
    for (int tn = 0; tn < 4; tn++) {
      int col = n0 + wn + tn * 16 + lrow;
      float bv = bias[col];
#pragma unroll
      for (int r = 0; r < 4; r++) {
        int row = m0 + wm + tm * 16 + kq * 4 + r;
        float v = acc[tm][tn][r] + bv;
        size_t o = (size_t)row * N + col;
        if (EPI == 1) outB[o] = __float2bfloat16(v);
        else if (EPI == 2) outB[o] = __float2bfloat16(gelu_f(v));
        else outF[o] += v;
      }
    }
  }
}

// ---------------- reference-token projection (tiny) ----------------
__global__ __launch_bounds__(256) void ref_kernel(
    const float* __restrict__ x_ref, const float* __restrict__ w, const float* __restrict__ bias,
    const float* __restrict__ diff_mu, const float* __restrict__ diff_ls,
    float* __restrict__ refq, float* __restrict__ refv) {
  int blk = blockIdx.x;               // 0..199
  int b = blk / 100, r = blk % 100;
  __shared__ float xs[512];
  int tid = threadIdx.x;
  const float* xr = x_ref + (size_t)(b * 100 + r) * 512;
  xs[tid] = xr[tid];
  xs[tid + 256] = xr[tid + 256];
  __syncthreads();
#pragma unroll
  for (int cc = 0; cc < 4; cc++) {
    int c = cc * 256 + tid;
    const float* wr = w + (size_t)c * 512;
    float s = bias[c];
    for (int k = 0; k < 512; k++) s += xs[k] * wr[k];
    if (c < 512) {
      float v = diff_mu[c] + expf(diff_ls[c]) * s;
      int hh = c >> 5, d = c & 31;
      refq[((size_t)(b * 16 + hh) * 100 + r) * 32 + d] = v;
    } else {
      int c2 = c - 512, hh = c2 >> 5, d = c2 & 31;
      refv[((size_t)(b * 16 + hh) * 100 + r) * 32 + d] = s;
    }
  }
}

// ---------------- ra = q @ ref_q^T ; block per (b_, head) ; ra stored bf16 ----------------
__global__ __launch_bounds__(256) void ra_kernel(
    const __hip_bfloat16* __restrict__ q, const float* __restrict__ refq,
    __hip_bfloat16* __restrict__ ra) {
  int blk = blockIdx.x;               // 8192
  int b_ = blk >> 4, h = blk & 15;
  int rb = b_ >> 8, win = b_ & 255;
  __shared__ float q_s[49][33];
  __shared__ float rq_s[100][33];
  int tid = threadIdx.x;
  const __hip_bfloat16* qb = q + (size_t)b_ * 49 * 512 + h * 32;
  for (int i = tid; i < 1568; i += 256) {
    int n = i >> 5, d = i & 31;
    q_s[n][d] = __bfloat162float(qb[n * 512 + d]);
  }
  const float* rq = refq + (size_t)(rb * 16 + h) * 3200;
  for (int i = tid; i < 3200; i += 256) rq_s[i >> 5][i & 31] = rq[i];
  __syncthreads();
  __hip_bfloat16* ra_base = ra + ((size_t)(rb * 16 + h) * 12544 + win * 49) * 100;
  for (int i = tid; i < 4900; i += 256) {
    int n = i / 100, r = i % 100;
    float s = 0.f;
#pragma unroll
    for (int d = 0; d < 32; d++) s += q_s[n][d] * rq_s[r][d];
    ra_base[i] = __float2bfloat16(s);
  }
}

// ---------------- 16ch 3x3 conv (bf16 in/out, fp32 acc) + per-(b,ch) partial stats ----------------
__global__ __launch_bounds__(256) void conv_kernel(
    const __hip_bfloat16* __restrict__ ra, const float* __restrict__ cw, const float* __restrict__ cb,
    __hip_bfloat16* __restrict__ u, float* __restrict__ psum, float* __restrict__ psumsq) {
  __shared__ float in_s[16][18][18];
  __shared__ float w_s[2304];
  int tile = blockIdx.x;              // 0..5487  (784 h-tiles x 7 w-tiles)
  int bb = blockIdx.y;
  int th = tile / 7, tw = tile % 7;
  int h0 = th * 16, w0 = tw * 16;
  int tid = threadIdx.x;
  for (int i = tid; i < 2304; i += 256) w_s[i] = cw[i];
  for (int i = tid; i < 16 * 18 * 18; i += 256) {
    int ci = i / 324, rem = i % 324, dy = rem / 18, dx = rem % 18;
    int gh = h0 - 1 + dy, gw = w0 - 1 + dx;
    float v = 0.f;
    if (gh >= 0 && gh < 12544 && gw >= 0 && gw < 100)
      v = __bfloat162float(ra[(((size_t)bb * 16 + ci) * 12544 + gh) * 100 + gw]);
    in_s[ci][dy][dx] = v;
  }
  __syncthreads();
  int co = tid >> 4, tx = tid & 15;
  int gw = w0 + tx;
  float bias = cb[co];
  float acc[16];
#pragma unroll
  for (int ty = 0; ty < 16; ty++) acc[ty] = bias;
  for (int ci = 0; ci < 16; ci++) {
    float wr[9];
#pragma unroll
    for (int k = 0; k < 9; k++) wr[k] = w_s[co * 144 + ci * 9 + k];
#pragma unroll
    for (int kx = 0; kx < 3; kx++) {
      float col[18];
#pragma unroll
      for (int rr = 0; rr < 18; rr++) col[rr] = in_s[ci][rr][tx + kx];
#pragma unroll
      for (int ky = 0; ky < 3; ky++)
#pragma unroll
        for (int ty = 0; ty < 16; ty++) acc[ty] += wr[ky * 3 + kx] * col[ty + ky];
    }
  }
  float s = 0.f, s2 = 0.f;
  bool valid = gw < 100;
#pragma unroll
  for (int ty = 0; ty < 16; ty++) {
    if (valid) {
      u[(((size_t)bb * 16 + co) * 12544 + h0 + ty) * 100 + gw] = __float2bfloat16(acc[ty]);
      s += acc[ty];
      s2 += acc[ty] * acc[ty];
    }
  }
#pragma unroll
  for (int o = 8; o > 0; o >>= 1) { s += __shfl_down(s, o, 16); s2 += __shfl_down(s2, o, 16); }
  if (tx == 0) {
    size_t pi = ((size_t)bb * 5488 + tile) * 16 + co;
    psum[pi] = s;
    psumsq[pi] = s2;
  }
}

__global__ __launch_bounds__(256) void conv_stats_kernel(
    const float* __restrict__ psum, const float* __restrict__ psumsq, float* __restrict__ stats) {
  int g = blockIdx.x;                 // 32 = (b, co)
  int bb = g >> 4, co = g & 15;
  int tid = threadIdx.x;
  float s = 0.f, s2 = 0.f;
  for (int t = tid; t < 5488; t += 256) {
    size_t pi = ((size_t)bb * 5488 + t) * 16 + co;
    s += psum[pi];
    s2 += psumsq[pi];
  }
  block_reduce2(s, s2);
  if (tid == 0) {
    const float inv = 1.f / 1254400.f;
    float mu = s * inv;
    float var = s2 * inv - mu * mu;
    stats[g * 2] = mu;
    stats[g * 2 + 1] = rsqrtf(var + 1e-5f);
  }
}

__global__ __launch_bounds__(256) void conv_apply_kernel(
    __hip_bfloat16* __restrict__ ra, const __hip_bfloat16* __restrict__ u,
    const float* __restrict__ stats) {
  const int total8 = 5017600;         // 40,140,800 / 8
  int stride = gridDim.x * 256;
  for (int i = blockIdx.x * 256 + threadIdx.x; i < total8; i += stride) {
    int g = i / 156800;               // 1,254,400 / 8 per (b,ch) group
    float mu = stats[g * 2], rstd = stats[g * 2 + 1];
    ushort8 uu = reinterpret_cast<const ushort8*>(u)[i];
    ushort8 rr = reinterpret_cast<const ushort8*>(ra)[i];
    ushort8 oo;
#pragma unroll
    for (int j = 0; j < 8; j++) {
      float rv = bf2f(rr[j]) + gelu_f((bf2f(uu[j]) - mu) * rstd);
      oo[j] = f2bf(rv);
    }
    reinterpret_cast<ushort8*>(ra)[i] = oo;
  }
}

// ---------------- fused: softmax(ra) -> q_new -> attn(+rpb+mask) -> softmax -> @v ----------------
__global__ __launch_bounds__(256) void attn_kernel(
    const __hip_bfloat16* __restrict__ ra, const float* __restrict__ refv,
    const __hip_bfloat16* __restrict__ kv, const float* __restrict__ rpb_table,
    const float* __restrict__ mask, __hip_bfloat16* __restrict__ att) {
  int blk = blockIdx.x;               // 8192
  int b_ = blk >> 4, h = blk & 15;
  int rb = b_ >> 8, win = b_ & 255;
  int tid = threadIdx.x;
  __shared__ float ra_s[49][101];
  __shared__ float rv_s[100][33];
  __shared__ float qn_s[49][33];
  __shared__ float k_s[49][33];
  __shared__ float v_s[49][33];
  __shared__ float at_s[49][50];

  const __hip_bfloat16* rab = ra + ((size_t)(rb * 16 + h) * 12544 + win * 49) * 100;
  for (int i = tid; i < 4900; i += 256) ra_s[i / 100][i % 100] = __bfloat162float(rab[i]);
  const float* rv = refv + (size_t)(rb * 16 + h) * 3200;
  for (int i = tid; i < 3200; i += 256) rv_s[i >> 5][i & 31] = rv[i];
  const __hip_bfloat16* kvb = kv + (size_t)b_ * 49 * 1024;
  for (int i = tid; i < 1568; i += 256) {
    int m = i >> 5, d = i & 31;
    k_s[m][d] = __bfloat162float(kvb[m * 1024 + h * 32 + d]);
    v_s[m][d] = __bfloat162float(kvb[m * 1024 + 512 + h * 32 + d]);
  }
  __syncthreads();
  // softmax over 100 ref slots, 4 lanes per row
  if (tid < 196) {
    int n = tid >> 2, q = tid & 3;
    float mx = -1e30f;
    for (int r = q * 25; r < q * 25 + 25; r++) mx = fmaxf(mx, ra_s[n][r]);
    mx = fmaxf(mx, __shfl_xor(mx, 1, 4));
    mx = fmaxf(mx, __shfl_xor(mx, 2, 4));
    float sm = 0.f;
    for (int r = q * 25; r < q * 25 + 25; r++) { float e = __expf(ra_s[n][r] - mx); ra_s[n][r] = e; sm += e; }
    sm += __shfl_xor(sm, 1, 4);
    sm += __shfl_xor(sm, 2, 4);
    float inv = 1.f / sm;
    for (int r = q * 25; r < q * 25 + 25; r++) ra_s[n][r] *= inv;
  }
  __syncthreads();
  // q_new = P @ ref_v * SCALE
  for (int i = tid; i < 1568; i += 256) {
    int n = i >> 5, d = i & 31;
    float s = 0.f;
#pragma unroll 4
    for (int r = 0; r < 100; r++) s += ra_s[n][r] * rv_s[r][d];
    qn_s[n][d] = s * 0.17677669529663688f;   // 32^-0.5
  }
  __syncthreads();
  // attn logits + rpb + mask
  for (int i = tid; i < 2401; i += 256) {
    int n = i / 49, m = i % 49;
    float s = 0.f;
#pragma unroll
    for (int d = 0; d < 32; d++) s += qn_s[n][d] * k_s[m][d];
    int i1 = n / 7, j1 = n % 7, i2 = m / 7, j2 = m % 7;
    int rp = (i1 - i2 + 6) * 13 + (j1 - j2 + 6);
    s += rpb_table[rp * 16 + h];
    s += mask[((size_t)win * 49 + n) * 49 + m];
    at_s[n][m] = s;
  }
  __syncthreads();
  // softmax over 49
  if (tid < 196) {
    int n = tid >> 2, q = tid & 3;
    float mx = -1e30f;
    for (int m = q; m < 49; m += 4) mx = fmaxf(mx, at_s[n][m]);
    mx = fmaxf(mx, __shfl_xor(mx, 1, 4));
    mx = fmaxf(mx, __shfl_xor(mx, 2, 4));
    float sm = 0.f;
    for (int m = q; m < 49; m += 4) { float e = __expf(at_s[n][m] - mx); at_s[n][m] = e; sm += e; }
    sm += __shfl_xor(sm, 1, 4);
    sm += __shfl_xor(sm, 2, 4);
    float inv = 1.f / sm;
    for (int m = q; m < 49; m += 4) at_s[n][m] *= inv;
  }
  __syncthreads();
  // out = attn @ v -> bf16 (per-head slice of (25088,512))
  __hip_bfloat16* ab = att + (size_t)b_ * 49 * 512 + h * 32;
  for (int i = tid; i < 1568; i += 256) {
    int n = i >> 5, d = i & 31;
    float s = 0.f;
#pragma unroll
    for (int m = 0; m < 49; m++) s += at_s[n][m] * v_s[m][d];
    ab[n * 512 + d] = __float2bfloat16(s);
  }
}

// ---------------- window-reverse gather + residual + LN2 ----------------
__global__ __launch_bounds__(256) void resid_ln2_kernel(
    const float* __restrict__ x, const __hip_bfloat16* __restrict__ proj_out,
    const float* __restrict__ w2, const float* __restrict__ b2,
    float* __restrict__ out, __hip_bfloat16* __restrict__ hout) {
  int blk = blockIdx.x;               // b*12544 + l
  int bb = blk / 12544, l = blk % 12544;
  int hh = l / 112, ww = l % 112;
  int hs = (hh + 109) % 112, wsx = (ww + 109) % 112;   // (h-3) mod 112
  int t = (bb * 256 + (hs / 7) * 16 + (wsx / 7)) * 49 + (hs % 7) * 7 + (wsx % 7);
  const float* xr = x + (size_t)blk * 512;
  const __hip_bfloat16* pr = proj_out + (size_t)t * 512;
  int tid = threadIdx.x;
  float v0 = xr[tid] + __bfloat162float(pr[tid]);
  float v1 = xr[tid + 256] + __bfloat162float(pr[tid + 256]);
  float* orow = out + (size_t)blk * 512;
  orow[tid] = v0;
  orow[tid + 256] = v1;
  float s = v0 + v1, s2 = v0 * v0 + v1 * v1;
  block_reduce2(s, s2);
  float mu = s * (1.f / 512.f);
  float rstd = rsqrtf(s2 * (1.f / 512.f) - mu * mu + 1e-5f);
  __hip_bfloat16* hrow = hout + (size_t)blk * 512;
  hrow[tid]       = __float2bfloat16((v0 - mu) * rstd * w2[tid] + b2[tid]);
  hrow[tid + 256] = __float2bfloat16((v1 - mu) * rstd * w2[tid + 256] + b2[tid + 256]);
}

// =======================================================================
extern "C" void kernel_launch(void* const* d_in, const int* in_sizes, int n_in,
                              void* d_out, int out_size, void* d_ws, size_t ws_size,
                              hipStream_t stream) {
  const float* x       = (const float*)d_in[0];
  const float* x_ref   = (const float*)d_in[1];
  const float* mask    = (const float*)d_in[2];
  const float* n1w     = (const float*)d_in[3];
  const float* n1b     = (const float*)d_in[4];
  const float* qkv_w   = (const float*)d_in[5];
  const float* qkv_b   = (const float*)d_in[6];
  const float* diff_mu = (const float*)d_in[7];
  const float* diff_ls = (const float*)d_in[8];
  const float* rpb     = (const float*)d_in[9];
  const float* ref_w   = (const float*)d_in[10];
  const float* ref_b   = (const float*)d_in[11];
  const float* conv_w  = (const float*)d_in[12];
  const float* conv_b  = (const float*)d_in[13];
  const float* proj_w  = (const float*)d_in[14];
  const float* proj_b  = (const float*)d_in[15];
  const float* n2w     = (const float*)d_in[16];
  const float* n2b     = (const float*)d_in[17];
  const float* fc1_w   = (const float*)d_in[18];
  const float* fc1_b   = (const float*)d_in[19];
  const float* fc2_w   = (const float*)d_in[20];
  const float* fc2_b   = (const float*)d_in[21];
  float* out = (float*)d_out;

  char* ws = (char*)d_ws;
  size_t off = 0;
  auto alloc = [&](size_t bytes) -> char* {
    char* p = ws + off;
    off += (bytes + 255) & ~(size_t)255;
    return p;
  };
  // ---- persistent small buffers (~8.5 MB) ----
  __hip_bfloat16* wq_bf = (__hip_bfloat16*)alloc(1536ULL * 512 * 2);   // q rows 0..511, kv rows 512..1535
  __hip_bfloat16* wp_bf = (__hip_bfloat16*)alloc(512ULL * 512 * 2);
  __hip_bfloat16* w1_bf = (__hip_bfloat16*)alloc(2048ULL * 512 * 2);
  __hip_bfloat16* w2_bf = (__hip_bfloat16*)alloc(512ULL * 2048 * 2);
  float* refq  = (float*)alloc(2ULL * 16 * 100 * 32 * 4);
  float* refv  = (float*)alloc(2ULL * 16 * 100 * 32 * 4);
  float* psum  = (float*)alloc(2ULL * 5488 * 16 * 4);
  float* psumq = (float*)alloc(2ULL * 5488 * 16 * 4);
  float* stats = (float*)alloc(64 * 4);
  // ---- aliased regions ----
  char* regX  = alloc(25088ULL * 512 * 2);      // xw_bf -> att_bf            (25.7 MB)
  char* regQ  = alloc(25088ULL * 512 * 2);      // q_bf  -> h_bf              (25.7 MB)
  char* regRA = alloc(2ULL * 16 * 12544 * 100 * 2);  // ra    -> hg (per-chunk) (80.3 MB)
  char* regU  = alloc(2ULL * 16 * 12544 * 100 * 2);  // u -> kv_bf + proj_bf    (80.3 MB)
  // total ~210 MiB

  __hip_bfloat16* xw_bf   = (__hip_bfloat16*)regX;
  __hip_bfloat16* att_bf  = (__hip_bfloat16*)regX;                      // after kv GEMM
  __hip_bfloat16* q_bf    = (__hip_bfloat16*)regQ;
  __hip_bfloat16* h_bf    = (__hip_bfloat16*)regQ;                      // after ra_kernel
  __hip_bfloat16* ra      = (__hip_bfloat16*)regRA;
  __hip_bfloat16* hg      = (__hip_bfloat16*)regRA;                     // after attn (51.4MB/chunk)
  __hip_bfloat16* u       = (__hip_bfloat16*)regU;
  __hip_bfloat16* kv_bf   = (__hip_bfloat16*)regU;                      // after conv rounds (51.4MB)
  __hip_bfloat16* proj_bf = (__hip_bfloat16*)(regU + 51380224);         // after attn (25.7MB)

  // 1. weights -> bf16
  f2b_kernel<<<3072, 256, 0, stream>>>(qkv_w, wq_bf, 786432);
  f2b_kernel<<<1024, 256, 0, stream>>>(proj_w, wp_bf, 262144);
  f2b_kernel<<<4096, 256, 0, stream>>>(fc1_w, w1_bf, 1048576);
  f2b_kernel<<<4096, 256, 0, stream>>>(fc2_w, w2_bf, 1048576);
  // 2. LN1 + shift + window partition
  ln1_window_kernel<<<25088, 256, 0, stream>>>(x, n1w, n1b, xw_bf);
  // 3. q GEMM (bias -> bf16)
  gemm_bt<1><<<dim3(196, 4), 256, 0, stream>>>(xw_bf, wq_bf, qkv_b, nullptr, q_bf,
                                               25088, 512, 512);
  // 4. reference tokens
  ref_kernel<<<200, 256, 0, stream>>>(x_ref, ref_w, ref_b, diff_mu, diff_ls, refq, refv);
  // 5. ra = q @ ref_q^T   (q region free afterwards)
  ra_kernel<<<8192, 256, 0, stream>>>(q_bf, refq, ra);
  // 6. conv diffusion x3
  for (int rd = 0; rd < 3; rd++) {
    conv_kernel<<<dim3(5488, 2), 256, 0, stream>>>(ra, conv_w, conv_b, u, psum, psumq);
    conv_stats_kernel<<<32, 256, 0, stream>>>(psum, psumq, stats);
    conv_apply_kernel<<<4096, 256, 0, stream>>>(ra, u, stats);
  }
  // 7. kv GEMM into dead u region (xw still live as A input)
  gemm_bt<1><<<dim3(196, 8), 256, 0, stream>>>(xw_bf, wq_bf + 512 * 512, qkv_b + 512,
                                               nullptr, kv_bf, 25088, 1024, 512);
  // 8. fused attention (xw dead -> att_bf)
  attn_kernel<<<8192, 256, 0, stream>>>(ra, refv, kv_bf, rpb, mask, att_bf);
  // 9. proj GEMM (bias -> bf16, into regU tail)
  gemm_bt<1><<<dim3(196, 4), 256, 0, stream>>>(att_bf, wp_bf, proj_b, nullptr, proj_bf,
                                               25088, 512, 512);
  // 10. window reverse + residual + LN2 (h_bf into dead q region)
  resid_ln2_kernel<<<25088, 256, 0, stream>>>(x, proj_bf, n2w, n2b, out, h_bf);
  // 11. MLP in two M-chunks; hg reuses dead ra region
  for (int ch = 0; ch < 2; ch++) {
    const __hip_bfloat16* hA = h_bf + (size_t)ch * 12544 * 512;
    gemm_bt<2><<<dim3(98, 16), 256, 0, stream>>>(hA, w1_bf, fc1_b, nullptr, hg,
                                                 12544, 2048, 512);
    gemm_bt<3><<<dim3(98, 4), 256, 0, stream>>>(hg, w2_bf, fc2_b,
                                                out + (size_t)ch * 12544 * 512, nullptr,
                                                12544, 512, 2048);
  }
}

// Round 3
// 2009.587 us; speedup vs baseline: 1.1281x; 1.1281x over previous
//
#include <hip/hip_runtime.h>
#include <hip/hip_bf16.h>

typedef __attribute__((ext_vector_type(8))) short short8;        // 8 bf16 = 4 VGPRs
typedef __attribute__((ext_vector_type(8))) unsigned short ushort8;
typedef __attribute__((ext_vector_type(4))) float f32x4;
typedef __attribute__((ext_vector_type(4))) unsigned int u32x4;

#define DEV __device__ __forceinline__

DEV float gelu_f(float x) { return 0.5f * x * (1.f + erff(x * 0.70710678118654752440f)); }

DEV float bf2f(unsigned short s) {
  unsigned int t = ((unsigned int)s) << 16;
  float f; __builtin_memcpy(&f, &t, 4); return f;
}
DEV unsigned short f2bf(float f) {
  __hip_bfloat16 b = __float2bfloat16(f);
  unsigned short s; __builtin_memcpy(&s, &b, 2); return s;
}

// block-wide (256 thr) sum of two values; every thread gets the totals
DEV void block_reduce2(float& s, float& s2) {
  __shared__ float red[8];
  int tid = threadIdx.x;
#pragma unroll
  for (int o = 32; o > 0; o >>= 1) { s += __shfl_down(s, o); s2 += __shfl_down(s2, o); }
  if ((tid & 63) == 0) { red[tid >> 6] = s; red[4 + (tid >> 6)] = s2; }
  __syncthreads();
  s  = red[0] + red[1] + red[2] + red[3];
  s2 = red[4] + red[5] + red[6] + red[7];
}

// ---------------- weight fp32 -> bf16 ----------------
__global__ __launch_bounds__(256) void f2b_kernel(const float* __restrict__ in,
                                                  __hip_bfloat16* __restrict__ o, int n) {
  int i = blockIdx.x * 256 + threadIdx.x;
  if (i < n) o[i] = __float2bfloat16(in[i]);
}

// ---------------- LN1 + cyclic shift + window partition -> bf16 ----------------
__global__ __launch_bounds__(256) void ln1_window_kernel(
    const float* __restrict__ x, const float* __restrict__ w, const float* __restrict__ b,
    __hip_bfloat16* __restrict__ xw) {
  int t = blockIdx.x;                 // 0..25087
  int b_ = t / 49, n = t % 49;
  int bb = b_ >> 8, win = b_ & 255;
  int wi = win >> 4, wj = win & 15;
  int ii = n / 7, jj = n % 7;
  int sh = (wi * 7 + ii + 3) % 112;
  int sw = (wj * 7 + jj + 3) % 112;
  const float* row = x + ((size_t)bb * 12544 + sh * 112 + sw) * 512;
  int tid = threadIdx.x;
  float v0 = row[tid], v1 = row[tid + 256];
  float s = v0 + v1, s2 = v0 * v0 + v1 * v1;
  block_reduce2(s, s2);
  float mu = s * (1.f / 512.f);
  float rstd = rsqrtf(s2 * (1.f / 512.f) - mu * mu + 1e-5f);
  __hip_bfloat16* orow = xw + (size_t)t * 512;
  orow[tid]       = __float2bfloat16((v0 - mu) * rstd * w[tid] + b[tid]);
  orow[tid + 256] = __float2bfloat16((v1 - mu) * rstd * w[tid + 256] + b[tid + 256]);
}

// ---------------- generic bf16 MFMA GEMM:  C = A(MxK) @ B(NxK)^T + bias ----------------
// EPI: 1 = bias -> bf16 store ; 2 = bias+gelu -> bf16 ; 3 = bias -> f32 +=
template <int EPI>
__global__ __launch_bounds__(256) void gemm_bt(
    const __hip_bfloat16* __restrict__ A, const __hip_bfloat16* __restrict__ B,
    const float* __restrict__ bias, float* __restrict__ outF,
    __hip_bfloat16* __restrict__ outB, int M, int N, int K) {
  __shared__ __align__(16) __hip_bfloat16 As[128][72];   // 64 data + 8 pad
  __shared__ __align__(16) __hip_bfloat16 Bs[128][72];
  int m0 = blockIdx.x * 128, n0 = blockIdx.y * 128;
  int tid = threadIdx.x;
  int wave = tid >> 6, lane = tid & 63;
  int wm = (wave & 1) * 64, wn = (wave >> 1) * 64;
  int lrow = lane & 15, kq = lane >> 4;
  f32x4 acc[4][4] = {};
  for (int k0 = 0; k0 < K; k0 += 64) {
#pragma unroll
    for (int i = 0; i < 4; i++) {
      int chunk = tid + i * 256;
      int row = chunk >> 3, c8 = chunk & 7;
      *reinterpret_cast<u32x4*>(&As[row][c8 * 8]) =
          *reinterpret_cast<const u32x4*>(&A[(size_t)(m0 + row) * K + k0 + c8 * 8]);
      *reinterpret_cast<u32x4*>(&Bs[row][c8 * 8]) =
          *reinterpret_cast<const u32x4*>(&B[(size_t)(n0 + row) * K + k0 + c8 * 8]);
    }
    __syncthreads();
#pragma unroll
    for (int ks = 0; ks < 2; ks++) {
      short8 af[4], bf[4];
#pragma unroll
      for (int t = 0; t < 4; t++) {
        af[t] = *reinterpret_cast<const short8*>(&As[wm + t * 16 + lrow][ks * 32 + kq * 8]);
        bf[t] = *reinterpret_cast<const short8*>(&Bs[wn + t * 16 + lrow][ks * 32 + kq * 8]);
      }
#pragma unroll
      for (int tm = 0; tm < 4; tm++)
#pragma unroll
        for (int tn = 0; tn < 4; tn++)
          acc[tm][tn] = __builtin_amdgcn_mfma_f32_16x16x32_bf16(af[tm], bf[tn], acc[tm][tn], 0, 0, 0);
    }
    __syncthreads();
  }
  // D: row=(lane>>4)*4+r, col=lane&15 (verified gfx950 C/D layout)
#pragma unroll
  for (int tm = 0; tm < 4; tm++) {
#pragma unroll
    for (int tn = 0; tn < 4; tn++) {
      int col = n0 + wn + tn * 16 + lrow;
      float bv = bias[col];
#pragma unroll
      for (int r = 0; r < 4; r++) {
        int row = m0 + wm + tm * 16 + kq * 4 + r;
        float v = acc[tm][tn][r] + bv;
        size_t o = (size_t)row * N + col;
        if (EPI == 1) outB[o] = __float2bfloat16(v);
        else if (EPI == 2) outB[o] = __float2bfloat16(gelu_f(v));
        else outF[o] += v;
      }
    }
  }
}

// ---------------- reference-token projection (tiny) ----------------
__global__ __launch_bounds__(256) void ref_kernel(
    const float* __restrict__ x_ref, const float* __restrict__ w, const float* __restrict__ bias,
    const float* __restrict__ diff_mu, const float* __restrict__ diff_ls,
    float* __restrict__ refq, float* __restrict__ refv) {
  int blk = blockIdx.x;               // 0..199
  int b = blk / 100, r = blk % 100;
  __shared__ float xs[512];
  int tid = threadIdx.x;
  const float* xr = x_ref + (size_t)(b * 100 + r) * 512;
  xs[tid] = xr[tid];
  xs[tid + 256] = xr[tid + 256];
  __syncthreads();
#pragma unroll
  for (int cc = 0; cc < 4; cc++) {
    int c = cc * 256 + tid;
    const float* wr = w + (size_t)c * 512;
    float s = bias[c];
    for (int k = 0; k < 512; k++) s += xs[k] * wr[k];
    if (c < 512) {
      float v = diff_mu[c] + expf(diff_ls[c]) * s;
      int hh = c >> 5, d = c & 31;
      refq[((size_t)(b * 16 + hh) * 100 + r) * 32 + d] = v;
    } else {
      int c2 = c - 512, hh = c2 >> 5, d = c2 & 31;
      refv[((size_t)(b * 16 + hh) * 100 + r) * 32 + d] = s;
    }
  }
}

// ---------------- ra = q @ ref_q^T ; block per (b_, head) ; ra stored bf16 ----------------
__global__ __launch_bounds__(256) void ra_kernel(
    const __hip_bfloat16* __restrict__ q, const float* __restrict__ refq,
    __hip_bfloat16* __restrict__ ra) {
  int blk = blockIdx.x;               // 8192
  int b_ = blk >> 4, h = blk & 15;
  int rb = b_ >> 8, win = b_ & 255;
  __shared__ float q_s[49][33];
  __shared__ float rq_s[100][33];
  int tid = threadIdx.x;
  const __hip_bfloat16* qb = q + (size_t)b_ * 49 * 512 + h * 32;
  for (int i = tid; i < 1568; i += 256) {
    int n = i >> 5, d = i & 31;
    q_s[n][d] = __bfloat162float(qb[n * 512 + d]);
  }
  const float* rq = refq + (size_t)(rb * 16 + h) * 3200;
  for (int i = tid; i < 3200; i += 256) rq_s[i >> 5][i & 31] = rq[i];
  __syncthreads();
  __hip_bfloat16* ra_base = ra + ((size_t)(rb * 16 + h) * 12544 + win * 49) * 100;
  for (int i = tid; i < 4900; i += 256) {
    int n = i / 100, r = i % 100;
    float s = 0.f;
#pragma unroll
    for (int d = 0; d < 32; d++) s += q_s[n][d] * rq_s[r][d];
    ra_base[i] = __float2bfloat16(s);
  }
}

// ---------------- 16ch 3x3 conv (bf16 in/out, fp32 acc) + per-(b,ch) partial stats ----------------
__global__ __launch_bounds__(256) void conv_kernel(
    const __hip_bfloat16* __restrict__ ra, const float* __restrict__ cw, const float* __restrict__ cb,
    __hip_bfloat16* __restrict__ u, float* __restrict__ psum, float* __restrict__ psumsq) {
  __shared__ float in_s[16][18][18];
  __shared__ float w_s[2304];
  int tile = blockIdx.x;              // 0..5487  (784 h-tiles x 7 w-tiles)
  int bb = blockIdx.y;
  int th = tile / 7, tw = tile % 7;
  int h0 = th * 16, w0 = tw * 16;
  int tid = threadIdx.x;
  for (int i = tid; i < 2304; i += 256) w_s[i] = cw[i];
  for (int i = tid; i < 16 * 18 * 18; i += 256) {
    int ci = i / 324, rem = i % 324, dy = rem / 18, dx = rem % 18;
    int gh = h0 - 1 + dy, gw = w0 - 1 + dx;
    float v = 0.f;
    if (gh >= 0 && gh < 12544 && gw >= 0 && gw < 100)
      v = __bfloat162float(ra[(((size_t)bb * 16 + ci) * 12544 + gh) * 100 + gw]);
    in_s[ci][dy][dx] = v;
  }
  __syncthreads();
  int co = tid >> 4, tx = tid & 15;
  int gw = w0 + tx;
  float bias = cb[co];
  float acc[16];
#pragma unroll
  for (int ty = 0; ty < 16; ty++) acc[ty] = bias;
  for (int ci = 0; ci < 16; ci++) {
    float wr[9];
#pragma unroll
    for (int k = 0; k < 9; k++) wr[k] = w_s[co * 144 + ci * 9 + k];
#pragma unroll
    for (int kx = 0; kx < 3; kx++) {
      float col[18];
#pragma unroll
      for (int rr = 0; rr < 18; rr++) col[rr] = in_s[ci][rr][tx + kx];
#pragma unroll
      for (int ky = 0; ky < 3; ky++)
#pragma unroll
        for (int ty = 0; ty < 16; ty++) acc[ty] += wr[ky * 3 + kx] * col[ty + ky];
    }
  }
  float s = 0.f, s2 = 0.f;
  bool valid = gw < 100;
#pragma unroll
  for (int ty = 0; ty < 16; ty++) {
    if (valid) {
      u[(((size_t)bb * 16 + co) * 12544 + h0 + ty) * 100 + gw] = __float2bfloat16(acc[ty]);
      s += acc[ty];
      s2 += acc[ty] * acc[ty];
    }
  }
#pragma unroll
  for (int o = 8; o > 0; o >>= 1) { s += __shfl_down(s, o, 16); s2 += __shfl_down(s2, o, 16); }
  if (tx == 0) {
    size_t pi = ((size_t)bb * 5488 + tile) * 16 + co;
    psum[pi] = s;
    psumsq[pi] = s2;
  }
}

__global__ __launch_bounds__(256) void conv_stats_kernel(
    const float* __restrict__ psum, const float* __restrict__ psumsq, float* __restrict__ stats) {
  int g = blockIdx.x;                 // 32 = (b, co)
  int bb = g >> 4, co = g & 15;
  int tid = threadIdx.x;
  float s = 0.f, s2 = 0.f;
  for (int t = tid; t < 5488; t += 256) {
    size_t pi = ((size_t)bb * 5488 + t) * 16 + co;
    s += psum[pi];
    s2 += psumsq[pi];
  }
  block_reduce2(s, s2);
  if (tid == 0) {
    const float inv = 1.f / 1254400.f;
    float mu = s * inv;
    float var = s2 * inv - mu * mu;
    stats[g * 2] = mu;
    stats[g * 2 + 1] = rsqrtf(var + 1e-5f);
  }
}

__global__ __launch_bounds__(256) void conv_apply_kernel(
    __hip_bfloat16* __restrict__ ra, const __hip_bfloat16* __restrict__ u,
    const float* __restrict__ stats) {
  const int total8 = 5017600;         // 40,140,800 / 8
  int stride = gridDim.x * 256;
  for (int i = blockIdx.x * 256 + threadIdx.x; i < total8; i += stride) {
    int g = i / 156800;               // 1,254,400 / 8 per (b,ch) group
    float mu = stats[g * 2], rstd = stats[g * 2 + 1];
    ushort8 uu = reinterpret_cast<const ushort8*>(u)[i];
    ushort8 rr = reinterpret_cast<const ushort8*>(ra)[i];
    ushort8 oo;
#pragma unroll
    for (int j = 0; j < 8; j++) {
      float rv = bf2f(rr[j]) + gelu_f((bf2f(uu[j]) - mu) * rstd);
      oo[j] = f2bf(rv);
    }
    reinterpret_cast<ushort8*>(ra)[i] = oo;
  }
}

// ---------------- fused MFMA attention ----------------
// per block: (window b_, head h). Three MFMA stages + fp32 softmaxes.
// LDS map (bytes):
//   [0      .. 17408)  P1  bf16 [64][136]   (phase A: softmaxed ra, K-pad 128)
//   [17408  .. 26112)  rvT bf16 [32][136]   (phase A: refv^T, K-pad 128)
//   [0      ..  9216)  P2  bf16 [64][72]    (phase B: 2nd softmax probs, K-pad 64)
//   [9216   .. 13824)  vT  bf16 [32][72]    (phase B: v^T)
//   [26112  .. 31232)  qn  bf16 [64][40]
//   [31232  .. 36352)  kb  bf16 [64][40]
//   [36352  .. 41856)  msk bf16 [49][56]
//   [41856  .. 42560)  rpb f32  [169]
__global__ __launch_bounds__(256) void attn_kernel(
    const __hip_bfloat16* __restrict__ ra_, const float* __restrict__ refv,
    const __hip_bfloat16* __restrict__ kv_, const float* __restrict__ rpb_table,
    const float* __restrict__ mask, __hip_bfloat16* __restrict__ att_) {
  __shared__ __align__(16) char smem[42560];
  unsigned short* P1  = (unsigned short*)smem;              // stride 136
  unsigned short* rvT = (unsigned short*)(smem + 17408);    // stride 136
  unsigned short* P2  = (unsigned short*)smem;              // stride 72
  unsigned short* vT  = (unsigned short*)(smem + 9216);     // stride 72
  unsigned short* qn  = (unsigned short*)(smem + 26112);    // stride 40
  unsigned short* kb  = (unsigned short*)(smem + 31232);    // stride 40
  unsigned short* msk = (unsigned short*)(smem + 36352);    // stride 56
  float* rpb_s        = (float*)(smem + 41856);

  int blk = blockIdx.x;               // 8192
  int b_ = blk >> 4, h = blk & 15;
  int rb = b_ >> 8, win = b_ & 255;
  int tid = threadIdx.x;
  int wave = tid >> 6, lane = tid & 63;
  int lrow = lane & 15, kq = lane >> 4;
  const unsigned short* ra = (const unsigned short*)ra_;
  const unsigned short* kv = (const unsigned short*)kv_;
  unsigned short* att = (unsigned short*)att_;

  // ---- phase A loads ----
  const unsigned short* rab = ra + ((size_t)(rb * 16 + h) * 12544 + win * 49) * 100;
  for (int i = tid; i < 4900; i += 256) P1[(i / 100) * 136 + i % 100] = rab[i];
  for (int i = tid; i < 49 * 28; i += 256) P1[(i / 28) * 136 + 100 + i % 28] = 0;
  const float* rv = refv + (size_t)(rb * 16 + h) * 3200;
  for (int i = tid; i < 3200; i += 256) { int r = i >> 5, d = i & 31; rvT[d * 136 + r] = f2bf(rv[i]); }
  for (int i = tid; i < 32 * 28; i += 256) rvT[(i / 28) * 136 + 100 + i % 28] = 0;
  const unsigned short* kvb = kv + (size_t)b_ * 49 * 1024;
  for (int i = tid; i < 1568; i += 256) { int m = i >> 5, d = i & 31; kb[m * 40 + d] = kvb[m * 1024 + h * 32 + d]; }
  for (int i = tid; i < 2401; i += 256) msk[(i / 49) * 56 + i % 49] = f2bf(mask[(size_t)win * 2401 + i]);
  for (int i = tid; i < 169; i += 256) rpb_s[i] = rpb_table[i * 16 + h];
  __syncthreads();

  // ---- softmax over 100 ref slots (rows 0..48, bf16 in place) ----
  if (tid < 196) {
    int n = tid >> 2, q = tid & 3;
    unsigned short* row = P1 + n * 136;
    float mx = -1e30f;
    for (int r = q * 25; r < q * 25 + 25; r++) mx = fmaxf(mx, bf2f(row[r]));
    mx = fmaxf(mx, __shfl_xor(mx, 1));
    mx = fmaxf(mx, __shfl_xor(mx, 2));
    float sm = 0.f;
    for (int r = q * 25; r < q * 25 + 25; r++) {
      float e = __expf(bf2f(row[r]) - mx); sm += e; row[r] = f2bf(e);
    }
    sm += __shfl_xor(sm, 1);
    sm += __shfl_xor(sm, 2);
    float inv = 1.f / sm;
    for (int r = q * 25; r < q * 25 + 25; r++) row[r] = f2bf(bf2f(row[r]) * inv);
  }
  __syncthreads();

  // ---- qnew = P1 @ rvT^T  (M=64 tile/wave row-block, N=32, K=128) ----
  f32x4 acc1[2] = {};
#pragma unroll
  for (int ks = 0; ks < 4; ks++) {
    short8 a = *reinterpret_cast<const short8*>(&P1[(wave * 16 + lrow) * 136 + ks * 32 + kq * 8]);
#pragma unroll
    for (int dt = 0; dt < 2; dt++) {
      short8 b = *reinterpret_cast<const short8*>(&rvT[(dt * 16 + lrow) * 136 + ks * 32 + kq * 8]);
      acc1[dt] = __builtin_amdgcn_mfma_f32_16x16x32_bf16(a, b, acc1[dt], 0, 0, 0);
    }
  }
#pragma unroll
  for (int dt = 0; dt < 2; dt++)
#pragma unroll
    for (int r = 0; r < 4; r++) {
      int n = wave * 16 + kq * 4 + r;
      qn[n * 40 + dt * 16 + lrow] = f2bf(acc1[dt][r] * 0.17677669529663688f);
    }
  __syncthreads();

  // ---- phase B: stage v^T (P1/rvT dead) ----
  for (int i = tid; i < 1568; i += 256) { int m = i >> 5, d = i & 31; vT[d * 72 + m] = kvb[m * 1024 + 512 + h * 32 + d]; }
  for (int i = tid; i < 32 * 15; i += 256) vT[(i / 15) * 72 + 49 + i % 15] = 0;

  // ---- logits = qn @ kb^T  (N=64 tiles, K=32), bias, register softmax ----
  short8 aq = *reinterpret_cast<const short8*>(&qn[(wave * 16 + lrow) * 40 + kq * 8]);
  f32x4 zero = {};
  float val[4][4];
#pragma unroll
  for (int mt = 0; mt < 4; mt++) {
    short8 bk = *reinterpret_cast<const short8*>(&kb[(mt * 16 + lrow) * 40 + kq * 8]);
    f32x4 lg = __builtin_amdgcn_mfma_f32_16x16x32_bf16(aq, bk, zero, 0, 0, 0);
    int m = mt * 16 + lrow;
    int i2 = m / 7, j2 = m % 7;
#pragma unroll
    for (int r = 0; r < 4; r++) {
      int n = wave * 16 + kq * 4 + r;
      float v;
      if (m < 49 && n < 49) {
        int i1 = n / 7, j1 = n % 7;
        v = lg[r] + rpb_s[(i1 - i2 + 6) * 13 + (j1 - j2 + 6)] + bf2f(msk[n * 56 + m]);
      } else v = -1e30f;
      val[mt][r] = v;
    }
  }
#pragma unroll
  for (int r = 0; r < 4; r++) {
    float mx = -1e30f;
#pragma unroll
    for (int mt = 0; mt < 4; mt++) mx = fmaxf(mx, val[mt][r]);
    mx = fmaxf(mx, __shfl_xor(mx, 1)); mx = fmaxf(mx, __shfl_xor(mx, 2));
    mx = fmaxf(mx, __shfl_xor(mx, 4)); mx = fmaxf(mx, __shfl_xor(mx, 8));
    float sm = 0.f, e[4];
#pragma unroll
    for (int mt = 0; mt < 4; mt++) { e[mt] = __expf(val[mt][r] - mx); sm += e[mt]; }
    sm += __shfl_xor(sm, 1); sm += __shfl_xor(sm, 2);
    sm += __shfl_xor(sm, 4); sm += __shfl_xor(sm, 8);
    float inv = 1.f / sm;
    int n = wave * 16 + kq * 4 + r;
#pragma unroll
    for (int mt = 0; mt < 4; mt++) P2[n * 72 + mt * 16 + lrow] = f2bf(e[mt] * inv);
  }
  __syncthreads();

  // ---- out = P2 @ vT^T  (N=32, K=64) -> global bf16 ----
  f32x4 acc2[2] = {};
#pragma unroll
  for (int ks = 0; ks < 2; ks++) {
    short8 ap = *reinterpret_cast<const short8*>(&P2[(wave * 16 + lrow) * 72 + ks * 32 + kq * 8]);
#pragma unroll
    for (int dt = 0; dt < 2; dt++) {
      short8 bv = *reinterpret_cast<const short8*>(&vT[(dt * 16 + lrow) * 72 + ks * 32 + kq * 8]);
      acc2[dt] = __builtin_amdgcn_mfma_f32_16x16x32_bf16(ap, bv, acc2[dt], 0, 0, 0);
    }
  }
  unsigned short* ab = att + (size_t)b_ * 49 * 512 + h * 32;
#pragma unroll
  for (int dt = 0; dt < 2; dt++)
#pragma unroll
    for (int r = 0; r < 4; r++) {
      int n = wave * 16 + kq * 4 + r;
      if (n < 49) ab[n * 512 + dt * 16 + lrow] = f2bf(acc2[dt][r]);
    }
}

// ---------------- window-reverse gather + residual + LN2 ----------------
__global__ __launch_bounds__(256) void resid_ln2_kernel(
    const float* __restrict__ x, const __hip_bfloat16* __restrict__ proj_out,
    const float* __restrict__ w2, const float* __restrict__ b2,
    float* __restrict__ out, __hip_bfloat16* __restrict__ hout) {
  int blk = blockIdx.x;               // b*12544 + l
  int bb = blk / 12544, l = blk % 12544;
  int hh = l / 112, ww = l % 112;
  int hs = (hh + 109) % 112, wsx = (ww + 109) % 112;   // (h-3) mod 112
  int t = (bb * 256 + (hs / 7) * 16 + (wsx / 7)) * 49 + (hs % 7) * 7 + (wsx % 7);
  const float* xr = x + (size_t)blk * 512;
  const __hip_bfloat16* pr = proj_out + (size_t)t * 512;
  int tid = threadIdx.x;
  float v0 = xr[tid] + __bfloat162float(pr[tid]);
  float v1 = xr[tid + 256] + __bfloat162float(pr[tid + 256]);
  float* orow = out + (size_t)blk * 512;
  orow[tid] = v0;
  orow[tid + 256] = v1;
  float s = v0 + v1, s2 = v0 * v0 + v1 * v1;
  block_reduce2(s, s2);
  float mu = s * (1.f / 512.f);
  float rstd = rsqrtf(s2 * (1.f / 512.f) - mu * mu + 1e-5f);
  __hip_bfloat16* hrow = hout + (size_t)blk * 512;
  hrow[tid]       = __float2bfloat16((v0 - mu) * rstd * w2[tid] + b2[tid]);
  hrow[tid + 256] = __float2bfloat16((v1 - mu) * rstd * w2[tid + 256] + b2[tid + 256]);
}

// =======================================================================
extern "C" void kernel_launch(void* const* d_in, const int* in_sizes, int n_in,
                              void* d_out, int out_size, void* d_ws, size_t ws_size,
                              hipStream_t stream) {
  const float* x       = (const float*)d_in[0];
  const float* x_ref   = (const float*)d_in[1];
  const float* mask    = (const float*)d_in[2];
  const float* n1w     = (const float*)d_in[3];
  const float* n1b     = (const float*)d_in[4];
  const float* qkv_w   = (const float*)d_in[5];
  const float* qkv_b   = (const float*)d_in[6];
  const float* diff_mu = (const float*)d_in[7];
  const float* diff_ls = (const float*)d_in[8];
  const float* rpb     = (const float*)d_in[9];
  const float* ref_w   = (const float*)d_in[10];
  const float* ref_b   = (const float*)d_in[11];
  const float* conv_w  = (const float*)d_in[12];
  const float* conv_b  = (const float*)d_in[13];
  const float* proj_w  = (const float*)d_in[14];
  const float* proj_b  = (const float*)d_in[15];
  const float* n2w     = (const float*)d_in[16];
  const float* n2b     = (const float*)d_in[17];
  const float* fc1_w   = (const float*)d_in[18];
  const float* fc1_b   = (const float*)d_in[19];
  const float* fc2_w   = (const float*)d_in[20];
  const float* fc2_b   = (const float*)d_in[21];
  float* out = (float*)d_out;

  char* ws = (char*)d_ws;
  size_t off = 0;
  auto alloc = [&](size_t bytes) -> char* {
    char* p = ws + off;
    off += (bytes + 255) & ~(size_t)255;
    return p;
  };
  // ---- persistent small buffers (~8.5 MB) ----
  __hip_bfloat16* wq_bf = (__hip_bfloat16*)alloc(1536ULL * 512 * 2);   // q rows 0..511, kv rows 512..1535
  __hip_bfloat16* wp_bf = (__hip_bfloat16*)alloc(512ULL * 512 * 2);
  __hip_bfloat16* w1_bf = (__hip_bfloat16*)alloc(2048ULL * 512 * 2);
  __hip_bfloat16* w2_bf = (__hip_bfloat16*)alloc(512ULL * 2048 * 2);
  float* refq  = (float*)alloc(2ULL * 16 * 100 * 32 * 4);
  float* refv  = (float*)alloc(2ULL * 16 * 100 * 32 * 4);
  float* psum  = (float*)alloc(2ULL * 5488 * 16 * 4);
  float* psumq = (float*)alloc(2ULL * 5488 * 16 * 4);
  float* stats = (float*)alloc(64 * 4);
  // ---- aliased regions ----
  char* regX  = alloc(25088ULL * 512 * 2);      // xw_bf -> att_bf            (25.7 MB)
  char* regQ  = alloc(25088ULL * 512 * 2);      // q_bf  -> h_bf              (25.7 MB)
  char* regRA = alloc(2ULL * 16 * 12544 * 100 * 2);  // ra    -> hg (per-chunk) (80.3 MB)
  char* regU  = alloc(2ULL * 16 * 12544 * 100 * 2);  // u -> kv_bf + proj_bf    (80.3 MB)
  // total ~210 MiB

  __hip_bfloat16* xw_bf   = (__hip_bfloat16*)regX;
  __hip_bfloat16* att_bf  = (__hip_bfloat16*)regX;                      // after kv GEMM
  __hip_bfloat16* q_bf    = (__hip_bfloat16*)regQ;
  __hip_bfloat16* h_bf    = (__hip_bfloat16*)regQ;                      // after ra_kernel
  __hip_bfloat16* ra      = (__hip_bfloat16*)regRA;
  __hip_bfloat16* hg      = (__hip_bfloat16*)regRA;                     // after attn (51.4MB/chunk)
  __hip_bfloat16* u       = (__hip_bfloat16*)regU;
  __hip_bfloat16* kv_bf   = (__hip_bfloat16*)regU;                      // after conv rounds (51.4MB)
  __hip_bfloat16* proj_bf = (__hip_bfloat16*)(regU + 51380224);         // after attn (25.7MB)

  // 1. weights -> bf16
  f2b_kernel<<<3072, 256, 0, stream>>>(qkv_w, wq_bf, 786432);
  f2b_kernel<<<1024, 256, 0, stream>>>(proj_w, wp_bf, 262144);
  f2b_kernel<<<4096, 256, 0, stream>>>(fc1_w, w1_bf, 1048576);
  f2b_kernel<<<4096, 256, 0, stream>>>(fc2_w, w2_bf, 1048576);
  // 2. LN1 + shift + window partition
  ln1_window_kernel<<<25088, 256, 0, stream>>>(x, n1w, n1b, xw_bf);
  // 3. q GEMM (bias -> bf16)
  gemm_bt<1><<<dim3(196, 4), 256, 0, stream>>>(xw_bf, wq_bf, qkv_b, nullptr, q_bf,
                                               25088, 512, 512);
  // 4. reference tokens
  ref_kernel<<<200, 256, 0, stream>>>(x_ref, ref_w, ref_b, diff_mu, diff_ls, refq, refv);
  // 5. ra = q @ ref_q^T   (q region free afterwards)
  ra_kernel<<<8192, 256, 0, stream>>>(q_bf, refq, ra);
  // 6. conv diffusion x3
  for (int rd = 0; rd < 3; rd++) {
    conv_kernel<<<dim3(5488, 2), 256, 0, stream>>>(ra, conv_w, conv_b, u, psum, psumq);
    conv_stats_kernel<<<32, 256, 0, stream>>>(psum, psumq, stats);
    conv_apply_kernel<<<4096, 256, 0, stream>>>(ra, u, stats);
  }
  // 7. kv GEMM into dead u region (xw still live as A input)
  gemm_bt<1><<<dim3(196, 8), 256, 0, stream>>>(xw_bf, wq_bf + 512 * 512, qkv_b + 512,
                                               nullptr, kv_bf, 25088, 1024, 512);
  // 8. fused MFMA attention (xw dead -> att_bf)
  attn_kernel<<<8192, 256, 0, stream>>>(ra, refv, kv_bf, rpb, mask, att_bf);
  // 9. proj GEMM (bias -> bf16, into regU tail)
  gemm_bt<1><<<dim3(196, 4), 256, 0, stream>>>(att_bf, wp_bf, proj_b, nullptr, proj_bf,
                                               25088, 512, 512);
  // 10. window reverse + residual + LN2 (h_bf into dead q region)
  resid_ln2_kernel<<<25088, 256, 0, stream>>>(x, proj_bf, n2w, n2b, out, h_bf);
  // 11. MLP in two M-chunks; hg reuses dead ra region
  for (int ch = 0; ch < 2; ch++) {
    const __hip_bfloat16* hA = h_bf + (size_t)ch * 12544 * 512;
    gemm_bt<2><<<dim3(98, 16), 256, 0, stream>>>(hA, w1_bf, fc1_b, nullptr, hg,
                                                 12544, 2048, 512);
    gemm_bt<3><<<dim3(98, 4), 256, 0, stream>>>(hg, w2_bf, fc2_b,
                                                out + (size_t)ch * 12544 * 512, nullptr,
                                                12544, 512, 2048);
  }
}

// Round 4
// 1603.819 us; speedup vs baseline: 1.4135x; 1.2530x over previous
//
#include <hip/hip_runtime.h>
#include <hip/hip_bf16.h>

typedef __attribute__((ext_vector_type(8))) short short8;        // 8 bf16 = 4 VGPRs
typedef __attribute__((ext_vector_type(8))) unsigned short ushort8;
typedef __attribute__((ext_vector_type(4))) float f32x4;
typedef __attribute__((ext_vector_type(4))) unsigned int u32x4;

#define DEV __device__ __forceinline__

DEV float gelu_f(float x) { return 0.5f * x * (1.f + erff(x * 0.70710678118654752440f)); }

DEV float bf2f(unsigned short s) {
  unsigned int t = ((unsigned int)s) << 16;
  float f; __builtin_memcpy(&f, &t, 4); return f;
}
DEV unsigned short f2bf(float f) {
  __hip_bfloat16 b = __float2bfloat16(f);
  unsigned short s; __builtin_memcpy(&s, &b, 2); return s;
}

// block-wide (256 thr) sum of two values; every thread gets the totals
DEV void block_reduce2(float& s, float& s2) {
  __shared__ float red[8];
  int tid = threadIdx.x;
#pragma unroll
  for (int o = 32; o > 0; o >>= 1) { s += __shfl_down(s, o); s2 += __shfl_down(s2, o); }
  if ((tid & 63) == 0) { red[tid >> 6] = s; red[4 + (tid >> 6)] = s2; }
  __syncthreads();
  s  = red[0] + red[1] + red[2] + red[3];
  s2 = red[4] + red[5] + red[6] + red[7];
}

// ---------------- weight fp32 -> bf16 ----------------
__global__ __launch_bounds__(256) void f2b_kernel(const float* __restrict__ in,
                                                  __hip_bfloat16* __restrict__ o, int n) {
  int i = blockIdx.x * 256 + threadIdx.x;
  if (i < n) o[i] = __float2bfloat16(in[i]);
}

// ---------------- LN1 + cyclic shift + window partition -> bf16 ----------------
__global__ __launch_bounds__(256) void ln1_window_kernel(
    const float* __restrict__ x, const float* __restrict__ w, const float* __restrict__ b,
    __hip_bfloat16* __restrict__ xw) {
  int t = blockIdx.x;                 // 0..25087
  int b_ = t / 49, n = t % 49;
  int bb = b_ >> 8, win = b_ & 255;
  int wi = win >> 4, wj = win & 15;
  int ii = n / 7, jj = n % 7;
  int sh = (wi * 7 + ii + 3) % 112;
  int sw = (wj * 7 + jj + 3) % 112;
  const float* row = x + ((size_t)bb * 12544 + sh * 112 + sw) * 512;
  int tid = threadIdx.x;
  float v0 = row[tid], v1 = row[tid + 256];
  float s = v0 + v1, s2 = v0 * v0 + v1 * v1;
  block_reduce2(s, s2);
  float mu = s * (1.f / 512.f);
  float rstd = rsqrtf(s2 * (1.f / 512.f) - mu * mu + 1e-5f);
  __hip_bfloat16* orow = xw + (size_t)t * 512;
  orow[tid]       = __float2bfloat16((v0 - mu) * rstd * w[tid] + b[tid]);
  orow[tid + 256] = __float2bfloat16((v1 - mu) * rstd * w[tid + 256] + b[tid + 256]);
}

// ---------------- generic bf16 MFMA GEMM:  C = A(MxK) @ B(NxK)^T + bias ----------------
// EPI: 1 = bias -> bf16 store ; 2 = bias+gelu -> bf16 ; 3 = bias -> f32 +=
template <int EPI>
__global__ __launch_bounds__(256) void gemm_bt(
    const __hip_bfloat16* __restrict__ A, const __hip_bfloat16* __restrict__ B,
    const float* __restrict__ bias, float* __restrict__ outF,
    __hip_bfloat16* __restrict__ outB, int M, int N, int K) {
  __shared__ __align__(16) __hip_bfloat16 As[128][72];   // 64 data + 8 pad
  __shared__ __align__(16) __hip_bfloat16 Bs[128][72];
  int m0 = blockIdx.x * 128, n0 = blockIdx.y * 128;
  int tid = threadIdx.x;
  int wave = tid >> 6, lane = tid & 63;
  int wm = (wave & 1) * 64, wn = (wave >> 1) * 64;
  int lrow = lane & 15, kq = lane >> 4;
  f32x4 acc[4][4] = {};
  for (int k0 = 0; k0 < K; k0 += 64) {
#pragma unroll
    for (int i = 0; i < 4; i++) {
      int chunk = tid + i * 256;
      int row = chunk >> 3, c8 = chunk & 7;
      *reinterpret_cast<u32x4*>(&As[row][c8 * 8]) =
          *reinterpret_cast<const u32x4*>(&A[(size_t)(m0 + row) * K + k0 + c8 * 8]);
      *reinterpret_cast<u32x4*>(&Bs[row][c8 * 8]) =
          *reinterpret_cast<const u32x4*>(&B[(size_t)(n0 + row) * K + k0 + c8 * 8]);
    }
    __syncthreads();
#pragma unroll
    for (int ks = 0; ks < 2; ks++) {
      short8 af[4], bf[4];
#pragma unroll
      for (int t = 0; t < 4; t++) {
        af[t] = *reinterpret_cast<const short8*>(&As[wm + t * 16 + lrow][ks * 32 + kq * 8]);
        bf[t] = *reinterpret_cast<const short8*>(&Bs[wn + t * 16 + lrow][ks * 32 + kq * 8]);
      }
#pragma unroll
      for (int tm = 0; tm < 4; tm++)
#pragma unroll
        for (int tn = 0; tn < 4; tn++)
          acc[tm][tn] = __builtin_amdgcn_mfma_f32_16x16x32_bf16(af[tm], bf[tn], acc[tm][tn], 0, 0, 0);
    }
    __syncthreads();
  }
  // D: row=(lane>>4)*4+r, col=lane&15 (verified gfx950 C/D layout)
#pragma unroll
  for (int tm = 0; tm < 4; tm++) {
#pragma unroll
    for (int tn = 0; tn < 4; tn++) {
      int col = n0 + wn + tn * 16 + lrow;
      float bv = bias[col];
#pragma unroll
      for (int r = 0; r < 4; r++) {
        int row = m0 + wm + tm * 16 + kq * 4 + r;
        float v = acc[tm][tn][r] + bv;
        size_t o = (size_t)row * N + col;
        if (EPI == 1) outB[o] = __float2bfloat16(v);
        else if (EPI == 2) outB[o] = __float2bfloat16(gelu_f(v));
        else outF[o] += v;
      }
    }
  }
}

// ---------------- reference-token projection (tiny) ----------------
__global__ __launch_bounds__(256) void ref_kernel(
    const float* __restrict__ x_ref, const float* __restrict__ w, const float* __restrict__ bias,
    const float* __restrict__ diff_mu, const float* __restrict__ diff_ls,
    float* __restrict__ refq, float* __restrict__ refv) {
  int blk = blockIdx.x;               // 0..199
  int b = blk / 100, r = blk % 100;
  __shared__ float xs[512];
  int tid = threadIdx.x;
  const float* xr = x_ref + (size_t)(b * 100 + r) * 512;
  xs[tid] = xr[tid];
  xs[tid + 256] = xr[tid + 256];
  __syncthreads();
#pragma unroll
  for (int cc = 0; cc < 4; cc++) {
    int c = cc * 256 + tid;
    const float* wr = w + (size_t)c * 512;
    float s = bias[c];
    for (int k = 0; k < 512; k++) s += xs[k] * wr[k];
    if (c < 512) {
      float v = diff_mu[c] + expf(diff_ls[c]) * s;
      int hh = c >> 5, d = c & 31;
      refq[((size_t)(b * 16 + hh) * 100 + r) * 32 + d] = v;
    } else {
      int c2 = c - 512, hh = c2 >> 5, d = c2 & 31;
      refv[((size_t)(b * 16 + hh) * 100 + r) * 32 + d] = s;
    }
  }
}

// ---------------- ra = q @ ref_q^T ; block per (b_, head) ; ra stored bf16 ----------------
__global__ __launch_bounds__(256) void ra_kernel(
    const __hip_bfloat16* __restrict__ q, const float* __restrict__ refq,
    __hip_bfloat16* __restrict__ ra) {
  int blk = blockIdx.x;               // 8192
  int b_ = blk >> 4, h = blk & 15;
  int rb = b_ >> 8, win = b_ & 255;
  __shared__ float q_s[49][33];
  __shared__ float rq_s[100][33];
  int tid = threadIdx.x;
  const __hip_bfloat16* qb = q + (size_t)b_ * 49 * 512 + h * 32;
  for (int i = tid; i < 1568; i += 256) {
    int n = i >> 5, d = i & 31;
    q_s[n][d] = __bfloat162float(qb[n * 512 + d]);
  }
  const float* rq = refq + (size_t)(rb * 16 + h) * 3200;
  for (int i = tid; i < 3200; i += 256) rq_s[i >> 5][i & 31] = rq[i];
  __syncthreads();
  __hip_bfloat16* ra_base = ra + ((size_t)(rb * 16 + h) * 12544 + win * 49) * 100;
  for (int i = tid; i < 4900; i += 256) {
    int n = i / 100, r = i % 100;
    float s = 0.f;
#pragma unroll
    for (int d = 0; d < 32; d++) s += q_s[n][d] * rq_s[r][d];
    ra_base[i] = __float2bfloat16(s);
  }
}

// ---------------- implicit-GEMM MFMA conv: 16ch 3x3 over (2,16,12544,100) ----------------
// Block = (y-tile of 8 rows, batch). Input staged channel-last bf16 [yl][xl][ci],
// weights [co][k], k = (ky*3+kx)*16 + ci, padded 144->160 with zeros.
// D[co][px] per MFMA: A-frag = weights row (co), B-frag = pixel row (px).
__global__ __launch_bounds__(256) void conv_kernel(
    const __hip_bfloat16* __restrict__ ra_, const float* __restrict__ cw, const float* __restrict__ cb,
    __hip_bfloat16* __restrict__ u_, float* __restrict__ psum, float* __restrict__ psumsq) {
  __shared__ __align__(16) unsigned short in_s[10 * 103 * 16];   // 32,960 B
  __shared__ __align__(16) unsigned short w_s[16 * 160];         //  5,120 B
  __shared__ float sred_s[4][16], sred_s2[4][16];
  const unsigned short* ra = (const unsigned short*)ra_;
  unsigned short* u = (unsigned short*)u_;
  int yt = blockIdx.x, bb = blockIdx.y;
  int y0 = yt * 8;
  int tid = threadIdx.x;
  int wave = tid >> 6, lane = tid & 63;
  int lrow = lane & 15, kq = lane >> 4;
  // stage weights: w_s[co*160 + (p*16+ci)] = cw[co][ci][p], zeros for k>=144
  for (int i = tid; i < 2560; i += 256) {
    int co = i / 160, k = i % 160;
    unsigned short v = 0;
    if (k < 144) {
      int ci = k & 15, p = k >> 4;
      v = f2bf(cw[(co * 16 + ci) * 9 + p]);
    }
    w_s[i] = v;
  }
  // stage input tile channel-last; xl = gx+1 (0..102), yl = gy-y0+1 (0..9)
  for (int i = tid; i < 16480; i += 256) {
    int xl = i % 103, rem = i / 103;
    int yl = rem % 10, ci = rem / 10;
    int gy = y0 - 1 + yl, gx = xl - 1;
    unsigned short v = 0;
    if (gy >= 0 && gy < 12544 && gx >= 0 && gx < 100)
      v = ra[(((size_t)bb * 16 + ci) * 12544 + gy) * 100 + gx];
    in_s[(yl * 103 + xl) * 16 + ci] = v;
  }
  __syncthreads();

  // A-frags: lane m=lrow (co), k = c*32 + kq*8
  short8 afr[5];
#pragma unroll
  for (int c = 0; c < 5; c++)
    afr[c] = *reinterpret_cast<const short8*>(&w_s[lrow * 160 + c * 32 + kq * 8]);
  // per-chunk tap indices: p = c*2 + (kq>>1); p==9 is the zero-padded chunk
  int kqh = kq >> 1, ci0 = (kq & 1) * 8;
  int kyA[5], kxA[5];
#pragma unroll
  for (int c = 0; c < 5; c++) {
    int p = c * 2 + kqh; if (p > 8) p = 0;   // A is zero for k>=144; any safe addr
    kyA[c] = p / 3; kxA[c] = p % 3;
  }
  float bias_r[4];
#pragma unroll
  for (int r = 0; r < 4; r++) bias_r[r] = cb[kq * 4 + r];
  float s_r[4] = {0.f, 0.f, 0.f, 0.f}, s2_r[4] = {0.f, 0.f, 0.f, 0.f};

#pragma unroll
  for (int rowi = 0; rowi < 2; rowi++) {
    int yl = wave + rowi * 4;          // local row 0..7 (staged index yl+ky, ky in 0..2 -> +0..9? no: row y uses staged rows yl..yl+2)
#pragma unroll
    for (int xg = 0; xg < 7; xg++) {
      int px = xg * 16 + lrow;
      int pxc = px < 100 ? px : 99;    // clamp keeps LDS reads in-bounds; masked at store
      f32x4 acc = {};
#pragma unroll
      for (int c = 0; c < 5; c++) {
        short8 bfrag = *reinterpret_cast<const short8*>(
            &in_s[((yl + kyA[c]) * 103 + pxc + kxA[c]) * 16 + ci0]);
        acc = __builtin_amdgcn_mfma_f32_16x16x32_bf16(afr[c], bfrag, acc, 0, 0, 0);
      }
      int gy = y0 + yl;
      bool valid = px < 100;
#pragma unroll
      for (int r = 0; r < 4; r++) {
        float v = acc[r] + bias_r[r];
        if (valid) {
          u[(((size_t)bb * 16 + kq * 4 + r) * 12544 + gy) * 100 + px] = f2bf(v);
          s_r[r] += v; s2_r[r] += v * v;
        }
      }
    }
  }
  // stats: reduce across the 16 px lanes, then across waves via LDS
#pragma unroll
  for (int o = 1; o < 16; o <<= 1)
#pragma unroll
    for (int r = 0; r < 4; r++) { s_r[r] += __shfl_xor(s_r[r], o); s2_r[r] += __shfl_xor(s2_r[r], o); }
  if (lrow == 0)
#pragma unroll
    for (int r = 0; r < 4; r++) { sred_s[wave][kq * 4 + r] = s_r[r]; sred_s2[wave][kq * 4 + r] = s2_r[r]; }
  __syncthreads();
  if (tid < 16) {
    float s  = sred_s[0][tid] + sred_s[1][tid] + sred_s[2][tid] + sred_s[3][tid];
    float s2 = sred_s2[0][tid] + sred_s2[1][tid] + sred_s2[2][tid] + sred_s2[3][tid];
    size_t pi = ((size_t)bb * 1568 + yt) * 16 + tid;
    psum[pi] = s; psumsq[pi] = s2;
  }
}

__global__ __launch_bounds__(256) void conv_stats_kernel(
    const float* __restrict__ psum, const float* __restrict__ psumsq, float* __restrict__ stats) {
  int g = blockIdx.x;                 // 32 = (b, co)
  int bb = g >> 4, co = g & 15;
  int tid = threadIdx.x;
  float s = 0.f, s2 = 0.f;
  for (int t = tid; t < 1568; t += 256) {
    size_t pi = ((size_t)bb * 1568 + t) * 16 + co;
    s += psum[pi];
    s2 += psumsq[pi];
  }
  block_reduce2(s, s2);
  if (tid == 0) {
    const float inv = 1.f / 1254400.f;
    float mu = s * inv;
    float var = s2 * inv - mu * mu;
    stats[g * 2] = mu;
    stats[g * 2 + 1] = rsqrtf(var + 1e-5f);
  }
}

__global__ __launch_bounds__(256) void conv_apply_kernel(
    __hip_bfloat16* __restrict__ ra, const __hip_bfloat16* __restrict__ u,
    const float* __restrict__ stats) {
  const int total8 = 5017600;         // 40,140,800 / 8
  int stride = gridDim.x * 256;
  for (int i = blockIdx.x * 256 + threadIdx.x; i < total8; i += stride) {
    int g = i / 156800;               // 1,254,400 / 8 per (b,ch) group
    float mu = stats[g * 2], rstd = stats[g * 2 + 1];
    ushort8 uu = reinterpret_cast<const ushort8*>(u)[i];
    ushort8 rr = reinterpret_cast<const ushort8*>(ra)[i];
    ushort8 oo;
#pragma unroll
    for (int j = 0; j < 8; j++) {
      float rv = bf2f(rr[j]) + gelu_f((bf2f(uu[j]) - mu) * rstd);
      oo[j] = f2bf(rv);
    }
    reinterpret_cast<ushort8*>(ra)[i] = oo;
  }
}

// ---------------- fused MFMA attention ----------------
// per block: (window b_, head h). Three MFMA stages + fp32 softmaxes.
__global__ __launch_bounds__(256) void attn_kernel(
    const __hip_bfloat16* __restrict__ ra_, const float* __restrict__ refv,
    const __hip_bfloat16* __restrict__ kv_, const float* __restrict__ rpb_table,
    const float* __restrict__ mask, __hip_bfloat16* __restrict__ att_) {
  __shared__ __align__(16) char smem[42560];
  unsigned short* P1  = (unsigned short*)smem;              // stride 136
  unsigned short* rvT = (unsigned short*)(smem + 17408);    // stride 136
  unsigned short* P2  = (unsigned short*)smem;              // stride 72
  unsigned short* vT  = (unsigned short*)(smem + 9216);     // stride 72
  unsigned short* qn  = (unsigned short*)(smem + 26112);    // stride 40
  unsigned short* kb  = (unsigned short*)(smem + 31232);    // stride 40
  unsigned short* msk = (unsigned short*)(smem + 36352);    // stride 56
  float* rpb_s        = (float*)(smem + 41856);

  int blk = blockIdx.x;               // 8192
  int b_ = blk >> 4, h = blk & 15;
  int rb = b_ >> 8, win = b_ & 255;
  int tid = threadIdx.x;
  int wave = tid >> 6, lane = tid & 63;
  int lrow = lane & 15, kq = lane >> 4;
  const unsigned short* ra = (const unsigned short*)ra_;
  const unsigned short* kv = (const unsigned short*)kv_;
  unsigned short* att = (unsigned short*)att_;

  // ---- phase A loads ----
  const unsigned short* rab = ra + ((size_t)(rb * 16 + h) * 12544 + win * 49) * 100;
  for (int i = tid; i < 4900; i += 256) P1[(i / 100) * 136 + i % 100] = rab[i];
  for (int i = tid; i < 49 * 28; i += 256) P1[(i / 28) * 136 + 100 + i % 28] = 0;
  const float* rv = refv + (size_t)(rb * 16 + h) * 3200;
  for (int i = tid; i < 3200; i += 256) { int r = i >> 5, d = i & 31; rvT[d * 136 + r] = f2bf(rv[i]); }
  for (int i = tid; i < 32 * 28; i += 256) rvT[(i / 28) * 136 + 100 + i % 28] = 0;
  const unsigned short* kvb = kv + (size_t)b_ * 49 * 1024;
  for (int i = tid; i < 1568; i += 256) { int m = i >> 5, d = i & 31; kb[m * 40 + d] = kvb[m * 1024 + h * 32 + d]; }
  for (int i = tid; i < 2401; i += 256) msk[(i / 49) * 56 + i % 49] = f2bf(mask[(size_t)win * 2401 + i]);
  for (int i = tid; i < 169; i += 256) rpb_s[i] = rpb_table[i * 16 + h];
  __syncthreads();

  // ---- softmax over 100 ref slots (rows 0..48, bf16 in place) ----
  if (tid < 196) {
    int n = tid >> 2, q = tid & 3;
    unsigned short* row = P1 + n * 136;
    float mx = -1e30f;
    for (int r = q * 25; r < q * 25 + 25; r++) mx = fmaxf(mx, bf2f(row[r]));
    mx = fmaxf(mx, __shfl_xor(mx, 1));
    mx = fmaxf(mx, __shfl_xor(mx, 2));
    float sm = 0.f;
    for (int r = q * 25; r < q * 25 + 25; r++) {
      float e = __expf(bf2f(row[r]) - mx); sm += e; row[r] = f2bf(e);
    }
    sm += __shfl_xor(sm, 1);
    sm += __shfl_xor(sm, 2);
    float inv = 1.f / sm;
    for (int r = q * 25; r < q * 25 + 25; r++) row[r] = f2bf(bf2f(row[r]) * inv);
  }
  __syncthreads();

  // ---- qnew = P1 @ rvT^T  (M=64, N=32, K=128) ----
  f32x4 acc1[2] = {};
#pragma unroll
  for (int ks = 0; ks < 4; ks++) {
    short8 a = *reinterpret_cast<const short8*>(&P1[(wave * 16 + lrow) * 136 + ks * 32 + kq * 8]);
#pragma unroll
    for (int dt = 0; dt < 2; dt++) {
      short8 b = *reinterpret_cast<const short8*>(&rvT[(dt * 16 + lrow) * 136 + ks * 32 + kq * 8]);
      acc1[dt] = __builtin_amdgcn_mfma_f32_16x16x32_bf16(a, b, acc1[dt], 0, 0, 0);
    }
  }
#pragma unroll
  for (int dt = 0; dt < 2; dt++)
#pragma unroll
    for (int r = 0; r < 4; r++) {
      int n = wave * 16 + kq * 4 + r;
      qn[n * 40 + dt * 16 + lrow] = f2bf(acc1[dt][r] * 0.17677669529663688f);
    }
  __syncthreads();

  // ---- phase B: stage v^T (P1/rvT dead) ----
  for (int i = tid; i < 1568; i += 256) { int m = i >> 5, d = i & 31; vT[d * 72 + m] = kvb[m * 1024 + 512 + h * 32 + d]; }
  for (int i = tid; i < 32 * 15; i += 256) vT[(i / 15) * 72 + 49 + i % 15] = 0;

  // ---- logits = qn @ kb^T (N=64, K=32), bias, register softmax ----
  short8 aq = *reinterpret_cast<const short8*>(&qn[(wave * 16 + lrow) * 40 + kq * 8]);
  f32x4 zero = {};
  float val[4][4];
#pragma unroll
  for (int mt = 0; mt < 4; mt++) {
    short8 bk = *reinterpret_cast<const short8*>(&kb[(mt * 16 + lrow) * 40 + kq * 8]);
    f32x4 lg = __builtin_amdgcn_mfma_f32_16x16x32_bf16(aq, bk, zero, 0, 0, 0);
    int m = mt * 16 + lrow;
    int i2 = m / 7, j2 = m % 7;
#pragma unroll
    for (int r = 0; r < 4; r++) {
      int n = wave * 16 + kq * 4 + r;
      float v;
      if (m < 49 && n < 49) {
        int i1 = n / 7, j1 = n % 7;
        v = lg[r] + rpb_s[(i1 - i2 + 6) * 13 + (j1 - j2 + 6)] + bf2f(msk[n * 56 + m]);
      } else v = -1e30f;
      val[mt][r] = v;
    }
  }
#pragma unroll
  for (int r = 0; r < 4; r++) {
    float mx = -1e30f;
#pragma unroll
    for (int mt = 0; mt < 4; mt++) mx = fmaxf(mx, val[mt][r]);
    mx = fmaxf(mx, __shfl_xor(mx, 1)); mx = fmaxf(mx, __shfl_xor(mx, 2));
    mx = fmaxf(mx, __shfl_xor(mx, 4)); mx = fmaxf(mx, __shfl_xor(mx, 8));
    float sm = 0.f, e[4];
#pragma unroll
    for (int mt = 0; mt < 4; mt++) { e[mt] = __expf(val[mt][r] - mx); sm += e[mt]; }
    sm += __shfl_xor(sm, 1); sm += __shfl_xor(sm, 2);
    sm += __shfl_xor(sm, 4); sm += __shfl_xor(sm, 8);
    float inv = 1.f / sm;
    int n = wave * 16 + kq * 4 + r;
#pragma unroll
    for (int mt = 0; mt < 4; mt++) P2[n * 72 + mt * 16 + lrow] = f2bf(e[mt] * inv);
  }
  __syncthreads();

  // ---- out = P2 @ vT^T (N=32, K=64) -> global bf16 ----
  f32x4 acc2[2] = {};
#pragma unroll
  for (int ks = 0; ks < 2; ks++) {
    short8 ap = *reinterpret_cast<const short8*>(&P2[(wave * 16 + lrow) * 72 + ks * 32 + kq * 8]);
#pragma unroll
    for (int dt = 0; dt < 2; dt++) {
      short8 bv = *reinterpret_cast<const short8*>(&vT[(dt * 16 + lrow) * 72 + ks * 32 + kq * 8]);
      acc2[dt] = __builtin_amdgcn_mfma_f32_16x16x32_bf16(ap, bv, acc2[dt], 0, 0, 0);
    }
  }
  unsigned short* ab = att + (size_t)b_ * 49 * 512 + h * 32;
#pragma unroll
  for (int dt = 0; dt < 2; dt++)
#pragma unroll
    for (int r = 0; r < 4; r++) {
      int n = wave * 16 + kq * 4 + r;
      if (n < 49) ab[n * 512 + dt * 16 + lrow] = f2bf(acc2[dt][r]);
    }
}

// ---------------- window-reverse gather + residual + LN2 ----------------
__global__ __launch_bounds__(256) void resid_ln2_kernel(
    const float* __restrict__ x, const __hip_bfloat16* __restrict__ proj_out,
    const float* __restrict__ w2, const float* __restrict__ b2,
    float* __restrict__ out, __hip_bfloat16* __restrict__ hout) {
  int blk = blockIdx.x;               // b*12544 + l
  int bb = blk / 12544, l = blk % 12544;
  int hh = l / 112, ww = l % 112;
  int hs = (hh + 109) % 112, wsx = (ww + 109) % 112;   // (h-3) mod 112
  int t = (bb * 256 + (hs / 7) * 16 + (wsx / 7)) * 49 + (hs % 7) * 7 + (wsx % 7);
  const float* xr = x + (size_t)blk * 512;
  const __hip_bfloat16* pr = proj_out + (size_t)t * 512;
  int tid = threadIdx.x;
  float v0 = xr[tid] + __bfloat162float(pr[tid]);
  float v1 = xr[tid + 256] + __bfloat162float(pr[tid + 256]);
  float* orow = out + (size_t)blk * 512;
  orow[tid] = v0;
  orow[tid + 256] = v1;
  float s = v0 + v1, s2 = v0 * v0 + v1 * v1;
  block_reduce2(s, s2);
  float mu = s * (1.f / 512.f);
  float rstd = rsqrtf(s2 * (1.f / 512.f) - mu * mu + 1e-5f);
  __hip_bfloat16* hrow = hout + (size_t)blk * 512;
  hrow[tid]       = __float2bfloat16((v0 - mu) * rstd * w2[tid] + b2[tid]);
  hrow[tid + 256] = __float2bfloat16((v1 - mu) * rstd * w2[tid + 256] + b2[tid + 256]);
}

// =======================================================================
extern "C" void kernel_launch(void* const* d_in, const int* in_sizes, int n_in,
                              void* d_out, int out_size, void* d_ws, size_t ws_size,
                              hipStream_t stream) {
  const float* x       = (const float*)d_in[0];
  const float* x_ref   = (const float*)d_in[1];
  const float* mask    = (const float*)d_in[2];
  const float* n1w     = (const float*)d_in[3];
  const float* n1b     = (const float*)d_in[4];
  const float* qkv_w   = (const float*)d_in[5];
  const float* qkv_b   = (const float*)d_in[6];
  const float* diff_mu = (const float*)d_in[7];
  const float* diff_ls = (const float*)d_in[8];
  const float* rpb     = (const float*)d_in[9];
  const float* ref_w   = (const float*)d_in[10];
  const float* ref_b   = (const float*)d_in[11];
  const float* conv_w  = (const float*)d_in[12];
  const float* conv_b  = (const float*)d_in[13];
  const float* proj_w  = (const float*)d_in[14];
  const float* proj_b  = (const float*)d_in[15];
  const float* n2w     = (const float*)d_in[16];
  const float* n2b     = (const float*)d_in[17];
  const float* fc1_w   = (const float*)d_in[18];
  const float* fc1_b   = (const float*)d_in[19];
  const float* fc2_w   = (const float*)d_in[20];
  const float* fc2_b   = (const float*)d_in[21];
  float* out = (float*)d_out;

  char* ws = (char*)d_ws;
  size_t off = 0;
  auto alloc = [&](size_t bytes) -> char* {
    char* p = ws + off;
    off += (bytes + 255) & ~(size_t)255;
    return p;
  };
  // ---- persistent small buffers ----
  __hip_bfloat16* wq_bf = (__hip_bfloat16*)alloc(1536ULL * 512 * 2);   // q rows 0..511, kv rows 512..1535
  __hip_bfloat16* wp_bf = (__hip_bfloat16*)alloc(512ULL * 512 * 2);
  __hip_bfloat16* w1_bf = (__hip_bfloat16*)alloc(2048ULL * 512 * 2);
  __hip_bfloat16* w2_bf = (__hip_bfloat16*)alloc(512ULL * 2048 * 2);
  float* refq  = (float*)alloc(2ULL * 16 * 100 * 32 * 4);
  float* refv  = (float*)alloc(2ULL * 16 * 100 * 32 * 4);
  float* psum  = (float*)alloc(2ULL * 1568 * 16 * 4);
  float* psumq = (float*)alloc(2ULL * 1568 * 16 * 4);
  float* stats = (float*)alloc(64 * 4);
  // ---- aliased regions ----
  char* regX  = alloc(25088ULL * 512 * 2);      // xw_bf -> att_bf            (25.7 MB)
  char* regQ  = alloc(25088ULL * 512 * 2);      // q_bf  -> h_bf              (25.7 MB)
  char* regRA = alloc(2ULL * 16 * 12544 * 100 * 2);  // ra    -> hg (per-chunk) (80.3 MB)
  char* regU  = alloc(2ULL * 16 * 12544 * 100 * 2);  // u -> kv_bf + proj_bf    (80.3 MB)

  __hip_bfloat16* xw_bf   = (__hip_bfloat16*)regX;
  __hip_bfloat16* att_bf  = (__hip_bfloat16*)regX;                      // after kv GEMM
  __hip_bfloat16* q_bf    = (__hip_bfloat16*)regQ;
  __hip_bfloat16* h_bf    = (__hip_bfloat16*)regQ;                      // after ra_kernel
  __hip_bfloat16* ra      = (__hip_bfloat16*)regRA;
  __hip_bfloat16* hg      = (__hip_bfloat16*)regRA;                     // after attn (51.4MB/chunk)
  __hip_bfloat16* u       = (__hip_bfloat16*)regU;
  __hip_bfloat16* kv_bf   = (__hip_bfloat16*)regU;                      // after conv rounds (51.4MB)
  __hip_bfloat16* proj_bf = (__hip_bfloat16*)(regU + 51380224);         // after attn (25.7MB)

  // 1. weights -> bf16
  f2b_kernel<<<3072, 256, 0, stream>>>(qkv_w, wq_bf, 786432);
  f2b_kernel<<<1024, 256, 0, stream>>>(proj_w, wp_bf, 262144);
  f2b_kernel<<<4096, 256, 0, stream>>>(fc1_w, w1_bf, 1048576);
  f2b_kernel<<<4096, 256, 0, stream>>>(fc2_w, w2_bf, 1048576);
  // 2. LN1 + shift + window partition
  ln1_window_kernel<<<25088, 256, 0, stream>>>(x, n1w, n1b, xw_bf);
  // 3. q GEMM (bias -> bf16)
  gemm_bt<1><<<dim3(196, 4), 256, 0, stream>>>(xw_bf, wq_bf, qkv_b, nullptr, q_bf,
                                               25088, 512, 512);
  // 4. reference tokens
  ref_kernel<<<200, 256, 0, stream>>>(x_ref, ref_w, ref_b, diff_mu, diff_ls, refq, refv);
  // 5. ra = q @ ref_q^T   (q region free afterwards)
  ra_kernel<<<8192, 256, 0, stream>>>(q_bf, refq, ra);
  // 6. conv diffusion x3 (MFMA implicit GEMM)
  for (int rd = 0; rd < 3; rd++) {
    conv_kernel<<<dim3(1568, 2), 256, 0, stream>>>(ra, conv_w, conv_b, u, psum, psumq);
    conv_stats_kernel<<<32, 256, 0, stream>>>(psum, psumq, stats);
    conv_apply_kernel<<<4096, 256, 0, stream>>>(ra, u, stats);
  }
  // 7. kv GEMM into dead u region (xw still live as A input)
  gemm_bt<1><<<dim3(196, 8), 256, 0, stream>>>(xw_bf, wq_bf + 512 * 512, qkv_b + 512,
                                               nullptr, kv_bf, 25088, 1024, 512);
  // 8. fused MFMA attention (xw dead -> att_bf)
  attn_kernel<<<8192, 256, 0, stream>>>(ra, refv, kv_bf, rpb, mask, att_bf);
  // 9. proj GEMM (bias -> bf16, into regU tail)
  gemm_bt<1><<<dim3(196, 4), 256, 0, stream>>>(att_bf, wp_bf, proj_b, nullptr, proj_bf,
                                               25088, 512, 512);
  // 10. window reverse + residual + LN2 (h_bf into dead q region)
  resid_ln2_kernel<<<25088, 256, 0, stream>>>(x, proj_bf, n2w, n2b, out, h_bf);
  // 11. MLP in two M-chunks; hg reuses dead ra region
  for (int ch = 0; ch < 2; ch++) {
    const __hip_bfloat16* hA = h_bf + (size_t)ch * 12544 * 512;
    gemm_bt<2><<<dim3(98, 16), 256, 0, stream>>>(hA, w1_bf, fc1_b, nullptr, hg,
                                                 12544, 2048, 512);
    gemm_bt<3><<<dim3(98, 4), 256, 0, stream>>>(hg, w2_bf, fc2_b,
                                                out + (size_t)ch * 12544 * 512, nullptr,
                                                12544, 512, 2048);
  }
}

// Round 5
// 1496.205 us; speedup vs baseline: 1.5152x; 1.0719x over previous
//
#include <hip/hip_runtime.h>
#include <hip/hip_bf16.h>

typedef __attribute__((ext_vector_type(8))) short short8;        // 8 bf16 = 4 VGPRs
typedef __attribute__((ext_vector_type(8))) unsigned short ushort8;
typedef __attribute__((ext_vector_type(4))) float f32x4;
typedef __attribute__((ext_vector_type(4))) unsigned int u32x4;
typedef __attribute__((ext_vector_type(2))) unsigned int u32x2;

#define DEV __device__ __forceinline__

DEV float gelu_f(float x) { return 0.5f * x * (1.f + erff(x * 0.70710678118654752440f)); }

DEV float bf2f(unsigned short s) {
  unsigned int t = ((unsigned int)s) << 16;
  float f; __builtin_memcpy(&f, &t, 4); return f;
}
DEV unsigned short f2bf(float f) {
  __hip_bfloat16 b = __float2bfloat16(f);
  unsigned short s; __builtin_memcpy(&s, &b, 2); return s;
}

// block-wide (256 thr) sum of two values; every thread gets the totals
DEV void block_reduce2(float& s, float& s2) {
  __shared__ float red[8];
  int tid = threadIdx.x;
#pragma unroll
  for (int o = 32; o > 0; o >>= 1) { s += __shfl_down(s, o); s2 += __shfl_down(s2, o); }
  if ((tid & 63) == 0) { red[tid >> 6] = s; red[4 + (tid >> 6)] = s2; }
  __syncthreads();
  s  = red[0] + red[1] + red[2] + red[3];
  s2 = red[4] + red[5] + red[6] + red[7];
}

// ---------------- weight fp32 -> bf16 ----------------
__global__ __launch_bounds__(256) void f2b_kernel(const float* __restrict__ in,
                                                  __hip_bfloat16* __restrict__ o, int n) {
  int i = blockIdx.x * 256 + threadIdx.x;
  if (i < n) o[i] = __float2bfloat16(in[i]);
}

// ---------------- mask -> bf16 padded [win][49][56] ----------------
__global__ __launch_bounds__(256) void maskb_kernel(const float* __restrict__ mask,
                                                    unsigned short* __restrict__ maskB) {
  int i = blockIdx.x * 256 + threadIdx.x;          // 256*49*56 = 702464 exactly
  int m = i % 56, rest = i / 56;
  int n = rest % 49, win = rest / 49;
  unsigned short v = 0;
  if (m < 49) v = f2bf(mask[((size_t)win * 49 + n) * 49 + m]);
  maskB[i] = v;
}

// ---------------- rpb -> bf16 padded [h][49][56] ----------------
__global__ __launch_bounds__(256) void rpbt_kernel(const float* __restrict__ rpb,
                                                   unsigned short* __restrict__ rpbT) {
  int i = blockIdx.x * 256 + threadIdx.x;          // 16*49*56 = 43904
  if (i >= 43904) return;
  int m = i % 56, rest = i / 56;
  int n = rest % 49, h = rest / 49;
  unsigned short v = 0;
  if (m < 49) {
    int rp = (n / 7 - m / 7 + 6) * 13 + (n % 7 - m % 7 + 6);
    v = f2bf(rpb[rp * 16 + h]);
  }
  rpbT[i] = v;
}

// ---------------- LN1 + cyclic shift + window partition -> bf16 ----------------
__global__ __launch_bounds__(256) void ln1_window_kernel(
    const float* __restrict__ x, const float* __restrict__ w, const float* __restrict__ b,
    __hip_bfloat16* __restrict__ xw) {
  int t = blockIdx.x;                 // 0..25087
  int b_ = t / 49, n = t % 49;
  int bb = b_ >> 8, win = b_ & 255;
  int wi = win >> 4, wj = win & 15;
  int ii = n / 7, jj = n % 7;
  int sh = (wi * 7 + ii + 3) % 112;
  int sw = (wj * 7 + jj + 3) % 112;
  const float* row = x + ((size_t)bb * 12544 + sh * 112 + sw) * 512;
  int tid = threadIdx.x;
  float v0 = row[tid], v1 = row[tid + 256];
  float s = v0 + v1, s2 = v0 * v0 + v1 * v1;
  block_reduce2(s, s2);
  float mu = s * (1.f / 512.f);
  float rstd = rsqrtf(s2 * (1.f / 512.f) - mu * mu + 1e-5f);
  __hip_bfloat16* orow = xw + (size_t)t * 512;
  orow[tid]       = __float2bfloat16((v0 - mu) * rstd * w[tid] + b[tid]);
  orow[tid + 256] = __float2bfloat16((v1 - mu) * rstd * w[tid + 256] + b[tid + 256]);
}

// ---------------- generic bf16 MFMA GEMM:  C = A(MxK) @ B(NxK)^T + bias ----------------
// EPI: 1 = bias -> bf16 store ; 2 = bias+gelu -> bf16 ; 3 = bias -> f32 +=
template <int EPI>
__global__ __launch_bounds__(256) void gemm_bt(
    const __hip_bfloat16* __restrict__ A, const __hip_bfloat16* __restrict__ B,
    const float* __restrict__ bias, float* __restrict__ outF,
    __hip_bfloat16* __restrict__ outB, int M, int N, int K) {
  __shared__ __align__(16) __hip_bfloat16 As[128][72];   // 64 data + 8 pad
  __shared__ __align__(16) __hip_bfloat16 Bs[128][72];
  int m0 = blockIdx.x * 128, n0 = blockIdx.y * 128;
  int tid = threadIdx.x;
  int wave = tid >> 6, lane = tid & 63;
  int wm = (wave & 1) * 64, wn = (wave >> 1) * 64;
  int lrow = lane & 15, kq = lane >> 4;
  f32x4 acc[4][4] = {};
  for (int k0 = 0; k0 < K; k0 += 64) {
#pragma unroll
    for (int i = 0; i < 4; i++) {
      int chunk = tid + i * 256;
      int row = chunk >> 3, c8 = chunk & 7;
      *reinterpret_cast<u32x4*>(&As[row][c8 * 8]) =
          *reinterpret_cast<const u32x4*>(&A[(size_t)(m0 + row) * K + k0 + c8 * 8]);
      *reinterpret_cast<u32x4*>(&Bs[row][c8 * 8]) =
          *reinterpret_cast<const u32x4*>(&B[(size_t)(n0 + row) * K + k0 + c8 * 8]);
    }
    __syncthreads();
#pragma unroll
    for (int ks = 0; ks < 2; ks++) {
      short8 af[4], bf[4];
#pragma unroll
      for (int t = 0; t < 4; t++) {
        af[t] = *reinterpret_cast<const short8*>(&As[wm + t * 16 + lrow][ks * 32 + kq * 8]);
        bf[t] = *reinterpret_cast<const short8*>(&Bs[wn + t * 16 + lrow][ks * 32 + kq * 8]);
      }
#pragma unroll
      for (int tm = 0; tm < 4; tm++)
#pragma unroll
        for (int tn = 0; tn < 4; tn++)
          acc[tm][tn] = __builtin_amdgcn_mfma_f32_16x16x32_bf16(af[tm], bf[tn], acc[tm][tn], 0, 0, 0);
    }
    __syncthreads();
  }
  // D: row=(lane>>4)*4+r, col=lane&15 (verified gfx950 C/D layout)
#pragma unroll
  for (int tm = 0; tm < 4; tm++) {
#pragma unroll
    for (int tn = 0; tn < 4; tn++) {
      int col = n0 + wn + tn * 16 + lrow;
      float bv = bias[col];
#pragma unroll
      for (int r = 0; r < 4; r++) {
        int row = m0 + wm + tm * 16 + kq * 4 + r;
        float v = acc[tm][tn][r] + bv;
        size_t o = (size_t)row * N + col;
        if (EPI == 1) outB[o] = __float2bfloat16(v);
        else if (EPI == 2) outB[o] = __float2bfloat16(gelu_f(v));
        else outF[o] += v;
      }
    }
  }
}

// ---------------- reference-token projection (tiny) ----------------
// writes refq fp32 [b][h][r][d] and refvT bf16 [b][h][d][r]
__global__ __launch_bounds__(256) void ref_kernel(
    const float* __restrict__ x_ref, const float* __restrict__ w, const float* __restrict__ bias,
    const float* __restrict__ diff_mu, const float* __restrict__ diff_ls,
    float* __restrict__ refq, unsigned short* __restrict__ refvT) {
  int blk = blockIdx.x;               // 0..199
  int b = blk / 100, r = blk % 100;
  __shared__ float xs[512];
  int tid = threadIdx.x;
  const float* xr = x_ref + (size_t)(b * 100 + r) * 512;
  xs[tid] = xr[tid];
  xs[tid + 256] = xr[tid + 256];
  __syncthreads();
#pragma unroll
  for (int cc = 0; cc < 4; cc++) {
    int c = cc * 256 + tid;
    const float* wr = w + (size_t)c * 512;
    float s = bias[c];
    for (int k = 0; k < 512; k++) s += xs[k] * wr[k];
    if (c < 512) {
      float v = diff_mu[c] + expf(diff_ls[c]) * s;
      int hh = c >> 5, d = c & 31;
      refq[((size_t)(b * 16 + hh) * 100 + r) * 32 + d] = v;
    } else {
      int c2 = c - 512, hh = c2 >> 5, d = c2 & 31;
      refvT[(((size_t)b * 16 + hh) * 32 + d) * 100 + r] = f2bf(s);
    }
  }
}

// ---------------- ra = q @ ref_q^T ; block per (b_, head) ; ra stored bf16 ----------------
__global__ __launch_bounds__(256) void ra_kernel(
    const __hip_bfloat16* __restrict__ q, const float* __restrict__ refq,
    __hip_bfloat16* __restrict__ ra) {
  int blk = blockIdx.x;               // 8192
  int b_ = blk >> 4, h = blk & 15;
  int rb = b_ >> 8, win = b_ & 255;
  __shared__ float q_s[49][33];
  __shared__ float rq_s[100][33];
  int tid = threadIdx.x;
  const __hip_bfloat16* qb = q + (size_t)b_ * 49 * 512 + h * 32;
  for (int i = tid; i < 1568; i += 256) {
    int n = i >> 5, d = i & 31;
    q_s[n][d] = __bfloat162float(qb[n * 512 + d]);
  }
  const float* rq = refq + (size_t)(rb * 16 + h) * 3200;
  for (int i = tid; i < 3200; i += 256) rq_s[i >> 5][i & 31] = rq[i];
  __syncthreads();
  __hip_bfloat16* ra_base = ra + ((size_t)(rb * 16 + h) * 12544 + win * 49) * 100;
  for (int i = tid; i < 4900; i += 256) {
    int n = i / 100, r = i % 100;
    float s = 0.f;
#pragma unroll
    for (int d = 0; d < 32; d++) s += q_s[n][d] * rq_s[r][d];
    ra_base[i] = __float2bfloat16(s);
  }
}

// ---------------- implicit-GEMM MFMA conv: 16ch 3x3 over (2,16,12544,100) ----------------
__global__ __launch_bounds__(256) void conv_kernel(
    const __hip_bfloat16* __restrict__ ra_, const float* __restrict__ cw, const float* __restrict__ cb,
    __hip_bfloat16* __restrict__ u_, float* __restrict__ psum, float* __restrict__ psumsq) {
  __shared__ __align__(16) unsigned short in_s[10 * 103 * 16];   // 32,960 B
  __shared__ __align__(16) unsigned short w_s[16 * 160];         //  5,120 B
  __shared__ float sred_s[4][16], sred_s2[4][16];
  const unsigned short* ra = (const unsigned short*)ra_;
  unsigned short* u = (unsigned short*)u_;
  int yt = blockIdx.x, bb = blockIdx.y;
  int y0 = yt * 8;
  int tid = threadIdx.x;
  int wave = tid >> 6, lane = tid & 63;
  int lrow = lane & 15, kq = lane >> 4;
  for (int i = tid; i < 2560; i += 256) {
    int co = i / 160, k = i % 160;
    unsigned short v = 0;
    if (k < 144) {
      int ci = k & 15, p = k >> 4;
      v = f2bf(cw[(co * 16 + ci) * 9 + p]);
    }
    w_s[i] = v;
  }
  for (int i = tid; i < 16480; i += 256) {
    int xl = i % 103, rem = i / 103;
    int yl = rem % 10, ci = rem / 10;
    int gy = y0 - 1 + yl, gx = xl - 1;
    unsigned short v = 0;
    if (gy >= 0 && gy < 12544 && gx >= 0 && gx < 100)
      v = ra[(((size_t)bb * 16 + ci) * 12544 + gy) * 100 + gx];
    in_s[(yl * 103 + xl) * 16 + ci] = v;
  }
  __syncthreads();

  short8 afr[5];
#pragma unroll
  for (int c = 0; c < 5; c++)
    afr[c] = *reinterpret_cast<const short8*>(&w_s[lrow * 160 + c * 32 + kq * 8]);
  int kqh = kq >> 1, ci0 = (kq & 1) * 8;
  int kyA[5], kxA[5];
#pragma unroll
  for (int c = 0; c < 5; c++) {
    int p = c * 2 + kqh; if (p > 8) p = 0;
    kyA[c] = p / 3; kxA[c] = p % 3;
  }
  float bias_r[4];
#pragma unroll
  for (int r = 0; r < 4; r++) bias_r[r] = cb[kq * 4 + r];
  float s_r[4] = {0.f, 0.f, 0.f, 0.f}, s2_r[4] = {0.f, 0.f, 0.f, 0.f};

#pragma unroll
  for (int rowi = 0; rowi < 2; rowi++) {
    int yl = wave + rowi * 4;
#pragma unroll
    for (int xg = 0; xg < 7; xg++) {
      int px = xg * 16 + lrow;
      int pxc = px < 100 ? px : 99;
      f32x4 acc = {};
#pragma unroll
      for (int c = 0; c < 5; c++) {
        short8 bfrag = *reinterpret_cast<const short8*>(
            &in_s[((yl + kyA[c]) * 103 + pxc + kxA[c]) * 16 + ci0]);
        acc = __builtin_amdgcn_mfma_f32_16x16x32_bf16(afr[c], bfrag, acc, 0, 0, 0);
      }
      int gy = y0 + yl;
      bool valid = px < 100;
#pragma unroll
      for (int r = 0; r < 4; r++) {
        float v = acc[r] + bias_r[r];
        if (valid) {
          u[(((size_t)bb * 16 + kq * 4 + r) * 12544 + gy) * 100 + px] = f2bf(v);
          s_r[r] += v; s2_r[r] += v * v;
        }
      }
    }
  }
#pragma unroll
  for (int o = 1; o < 16; o <<= 1)
#pragma unroll
    for (int r = 0; r < 4; r++) { s_r[r] += __shfl_xor(s_r[r], o); s2_r[r] += __shfl_xor(s2_r[r], o); }
  if (lrow == 0)
#pragma unroll
    for (int r = 0; r < 4; r++) { sred_s[wave][kq * 4 + r] = s_r[r]; sred_s2[wave][kq * 4 + r] = s2_r[r]; }
  __syncthreads();
  if (tid < 16) {
    float s  = sred_s[0][tid] + sred_s[1][tid] + sred_s[2][tid] + sred_s[3][tid];
    float s2 = sred_s2[0][tid] + sred_s2[1][tid] + sred_s2[2][tid] + sred_s2[3][tid];
    size_t pi = ((size_t)bb * 1568 + yt) * 16 + tid;
    psum[pi] = s; psumsq[pi] = s2;
  }
}

__global__ __launch_bounds__(256) void conv_stats_kernel(
    const float* __restrict__ psum, const float* __restrict__ psumsq, float* __restrict__ stats) {
  int g = blockIdx.x;                 // 32 = (b, co)
  int bb = g >> 4, co = g & 15;
  int tid = threadIdx.x;
  float s = 0.f, s2 = 0.f;
  for (int t = tid; t < 1568; t += 256) {
    size_t pi = ((size_t)bb * 1568 + t) * 16 + co;
    s += psum[pi];
    s2 += psumsq[pi];
  }
  block_reduce2(s, s2);
  if (tid == 0) {
    const float inv = 1.f / 1254400.f;
    float mu = s * inv;
    float var = s2 * inv - mu * mu;
    stats[g * 2] = mu;
    stats[g * 2 + 1] = rsqrtf(var + 1e-5f);
  }
}

__global__ __launch_bounds__(256) void conv_apply_kernel(
    __hip_bfloat16* __restrict__ ra, const __hip_bfloat16* __restrict__ u,
    const float* __restrict__ stats) {
  const int total8 = 5017600;         // 40,140,800 / 8
  int stride = gridDim.x * 256;
  for (int i = blockIdx.x * 256 + threadIdx.x; i < total8; i += stride) {
    int g = i / 156800;               // 1,254,400 / 8 per (b,ch) group
    float mu = stats[g * 2], rstd = stats[g * 2 + 1];
    ushort8 uu = reinterpret_cast<const ushort8*>(u)[i];
    ushort8 rr = reinterpret_cast<const ushort8*>(ra)[i];
    ushort8 oo;
#pragma unroll
    for (int j = 0; j < 8; j++) {
      float rv = bf2f(rr[j]) + gelu_f((bf2f(uu[j]) - mu) * rstd);
      oo[j] = f2bf(rv);
    }
    reinterpret_cast<ushort8*>(ra)[i] = oo;
  }
}

// ---------------- fused MFMA attention ----------------
// per block: (window b_, head h). LDS 36,352 B -> 4 blocks/CU.
//   [0     .. 17408)  P1  bf16 [64][136]   | phase B: P2 [64][72] @0, vT [32][72] @9216
//   [17408 .. 26112)  rvT bf16 [32][136]
//   [26112 .. 31232)  qn  bf16 [64][40]
//   [31232 .. 36352)  kb  bf16 [64][40]
__global__ __launch_bounds__(256) void attn_kernel(
    const __hip_bfloat16* __restrict__ ra_, const unsigned short* __restrict__ refvT,
    const __hip_bfloat16* __restrict__ kv_, const unsigned short* __restrict__ rpbT,
    const unsigned short* __restrict__ maskB, __hip_bfloat16* __restrict__ att_) {
  __shared__ __align__(16) char smem[36352];
  unsigned short* P1  = (unsigned short*)smem;              // stride 136
  unsigned short* rvT = (unsigned short*)(smem + 17408);    // stride 136
  unsigned short* P2  = (unsigned short*)smem;              // stride 72
  unsigned short* vT  = (unsigned short*)(smem + 9216);     // stride 72
  unsigned short* qn  = (unsigned short*)(smem + 26112);    // stride 40
  unsigned short* kb  = (unsigned short*)(smem + 31232);    // stride 40

  int blk = blockIdx.x;               // 8192
  int b_ = blk >> 4, h = blk & 15;
  int rb = b_ >> 8, win = b_ & 255;
  int tid = threadIdx.x;
  int wave = tid >> 6, lane = tid & 63;
  int lrow = lane & 15, kq = lane >> 4;
  const unsigned short* ra = (const unsigned short*)ra_;
  const unsigned short* kv = (const unsigned short*)kv_;
  unsigned short* att = (unsigned short*)att_;
  u32x2 zz = {};

  // ---- phase A staging (vectorized) ----
  const unsigned short* rab = ra + ((size_t)(rb * 16 + h) * 12544 + win * 49) * 100;
  for (int i = tid; i < 1225; i += 256) {          // P1 rows: 49 x 25 chunks of 4
    int n = i / 25, c = i % 25;
    *reinterpret_cast<u32x2*>(&P1[n * 136 + c * 4]) =
        *reinterpret_cast<const u32x2*>(&rab[n * 100 + c * 4]);
  }
  for (int i = tid; i < 343; i += 256) {           // P1 K-pad: 49 x 7 chunks
    int n = i / 7, c = i % 7;
    *reinterpret_cast<u32x2*>(&P1[n * 136 + 100 + c * 4]) = zz;
  }
  const unsigned short* rvtg = refvT + (size_t)(rb * 16 + h) * 3200;
  for (int i = tid; i < 800; i += 256) {           // rvT rows: 32 x 25 chunks
    int d = i / 25, c = i % 25;
    *reinterpret_cast<u32x2*>(&rvT[d * 136 + c * 4]) =
        *reinterpret_cast<const u32x2*>(&rvtg[d * 100 + c * 4]);
  }
  for (int i = tid; i < 224; i += 256) {           // rvT K-pad: 32 x 7
    int d = i / 7, c = i % 7;
    *reinterpret_cast<u32x2*>(&rvT[d * 136 + 100 + c * 4]) = zz;
  }
  const unsigned short* kvb = kv + (size_t)b_ * 49 * 1024;
  for (int i = tid; i < 196; i += 256) {           // K: 49 rows x 4 chunks of 8
    int m = i >> 2, c = i & 3;
    *reinterpret_cast<u32x4*>(&kb[m * 40 + c * 8]) =
        *reinterpret_cast<const u32x4*>(&kvb[m * 1024 + h * 32 + c * 8]);
  }
  __syncthreads();

  // ---- softmax over 100 ref slots (rows 0..48, bf16 in place) ----
  if (tid < 196) {
    int n = tid >> 2, q = tid & 3;
    unsigned short* row = P1 + n * 136;
    float mx = -1e30f;
    for (int r = q * 25; r < q * 25 + 25; r++) mx = fmaxf(mx, bf2f(row[r]));
    mx = fmaxf(mx, __shfl_xor(mx, 1));
    mx = fmaxf(mx, __shfl_xor(mx, 2));
    float sm = 0.f;
    for (int r = q * 25; r < q * 25 + 25; r++) {
      float e = __expf(bf2f(row[r]) - mx); sm += e; row[r] = f2bf(e);
    }
    sm += __shfl_xor(sm, 1);
    sm += __shfl_xor(sm, 2);
    float inv = 1.f / sm;
    for (int r = q * 25; r < q * 25 + 25; r++) row[r] = f2bf(bf2f(row[r]) * inv);
  }
  __syncthreads();

  // ---- qnew = P1 @ rvT^T  (M=64, N=32, K=128) ----
  f32x4 acc1[2] = {};
#pragma unroll
  for (int ks = 0; ks < 4; ks++) {
    short8 a = *reinterpret_cast<const short8*>(&P1[(wave * 16 + lrow) * 136 + ks * 32 + kq * 8]);
#pragma unroll
    for (int dt = 0; dt < 2; dt++) {
      short8 b = *reinterpret_cast<const short8*>(&rvT[(dt * 16 + lrow) * 136 + ks * 32 + kq * 8]);
      acc1[dt] = __builtin_amdgcn_mfma_f32_16x16x32_bf16(a, b, acc1[dt], 0, 0, 0);
    }
  }
#pragma unroll
  for (int dt = 0; dt < 2; dt++)
#pragma unroll
    for (int r = 0; r < 4; r++) {
      int n = wave * 16 + kq * 4 + r;
      qn[n * 40 + dt * 16 + lrow] = f2bf(acc1[dt][r] * 0.17677669529663688f);
    }
  __syncthreads();

  // ---- phase B: stage v^T via register transpose (P1/rvT dead) ----
  for (int i = tid; i < 196; i += 256) {
    int m = i >> 2, dg = (i & 3) * 8;
    ushort8 vv = *reinterpret_cast<const ushort8*>(&kvb[m * 1024 + 512 + h * 32 + dg]);
#pragma unroll
    for (int j = 0; j < 8; j++) vT[(dg + j) * 72 + m] = vv[j];
  }
  for (int i = tid; i < 480; i += 256) vT[(i / 15) * 72 + 49 + i % 15] = 0;

  // ---- logits = qn @ kb^T (N=64, K=32), +rpb+mask from global, register softmax ----
  const unsigned short* bt = maskB + (size_t)win * 2744;
  const unsigned short* rt = rpbT + (size_t)h * 2744;
  short8 aq = *reinterpret_cast<const short8*>(&qn[(wave * 16 + lrow) * 40 + kq * 8]);
  f32x4 zero = {};
  float val[4][4];
#pragma unroll
  for (int mt = 0; mt < 4; mt++) {
    short8 bk = *reinterpret_cast<const short8*>(&kb[(mt * 16 + lrow) * 40 + kq * 8]);
    f32x4 lg = __builtin_amdgcn_mfma_f32_16x16x32_bf16(aq, bk, zero, 0, 0, 0);
    int m = mt * 16 + lrow;
#pragma unroll
    for (int r = 0; r < 4; r++) {
      int n = wave * 16 + kq * 4 + r;
      float v;
      if (m < 49 && n < 49)
        v = lg[r] + bf2f(rt[n * 56 + m]) + bf2f(bt[n * 56 + m]);
      else v = -1e30f;
      val[mt][r] = v;
    }
  }
#pragma unroll
  for (int r = 0; r < 4; r++) {
    float mx = -1e30f;
#pragma unroll
    for (int mt = 0; mt < 4; mt++) mx = fmaxf(mx, val[mt][r]);
    mx = fmaxf(mx, __shfl_xor(mx, 1)); mx = fmaxf(mx, __shfl_xor(mx, 2));
    mx = fmaxf(mx, __shfl_xor(mx, 4)); mx = fmaxf(mx, __shfl_xor(mx, 8));
    float sm = 0.f, e[4];
#pragma unroll
    for (int mt = 0; mt < 4; mt++) { e[mt] = __expf(val[mt][r] - mx); sm += e[mt]; }
    sm += __shfl_xor(sm, 1); sm += __shfl_xor(sm, 2);
    sm += __shfl_xor(sm, 4); sm += __shfl_xor(sm, 8);
    float inv = 1.f / sm;
    int n = wave * 16 + kq * 4 + r;
#pragma unroll
    for (int mt = 0; mt < 4; mt++) P2[n * 72 + mt * 16 + lrow] = f2bf(e[mt] * inv);
  }
  __syncthreads();

  // ---- out = P2 @ vT^T (N=32, K=64) -> global bf16 ----
  f32x4 acc2[2] = {};
#pragma unroll
  for (int ks = 0; ks < 2; ks++) {
    short8 ap = *reinterpret_cast<const short8*>(&P2[(wave * 16 + lrow) * 72 + ks * 32 + kq * 8]);
#pragma unroll
    for (int dt = 0; dt < 2; dt++) {
      short8 bv = *reinterpret_cast<const short8*>(&vT[(dt * 16 + lrow) * 72 + ks * 32 + kq * 8]);
      acc2[dt] = __builtin_amdgcn_mfma_f32_16x16x32_bf16(ap, bv, acc2[dt], 0, 0, 0);
    }
  }
  unsigned short* ab = att + (size_t)b_ * 49 * 512 + h * 32;
#pragma unroll
  for (int dt = 0; dt < 2; dt++)
#pragma unroll
    for (int r = 0; r < 4; r++) {
      int n = wave * 16 + kq * 4 + r;
      if (n < 49) ab[n * 512 + dt * 16 + lrow] = f2bf(acc2[dt][r]);
    }
}

// ---------------- window-reverse gather + residual + LN2 ----------------
__global__ __launch_bounds__(256) void resid_ln2_kernel(
    const float* __restrict__ x, const __hip_bfloat16* __restrict__ proj_out,
    const float* __restrict__ w2, const float* __restrict__ b2,
    float* __restrict__ out, __hip_bfloat16* __restrict__ hout) {
  int blk = blockIdx.x;               // b*12544 + l
  int bb = blk / 12544, l = blk % 12544;
  int hh = l / 112, ww = l % 112;
  int hs = (hh + 109) % 112, wsx = (ww + 109) % 112;   // (h-3) mod 112
  int t = (bb * 256 + (hs / 7) * 16 + (wsx / 7)) * 49 + (hs % 7) * 7 + (wsx % 7);
  const float* xr = x + (size_t)blk * 512;
  const __hip_bfloat16* pr = proj_out + (size_t)t * 512;
  int tid = threadIdx.x;
  float v0 = xr[tid] + __bfloat162float(pr[tid]);
  float v1 = xr[tid + 256] + __bfloat162float(pr[tid + 256]);
  float* orow = out + (size_t)blk * 512;
  orow[tid] = v0;
  orow[tid + 256] = v1;
  float s = v0 + v1, s2 = v0 * v0 + v1 * v1;
  block_reduce2(s, s2);
  float mu = s * (1.f / 512.f);
  float rstd = rsqrtf(s2 * (1.f / 512.f) - mu * mu + 1e-5f);
  __hip_bfloat16* hrow = hout + (size_t)blk * 512;
  hrow[tid]       = __float2bfloat16((v0 - mu) * rstd * w2[tid] + b2[tid]);
  hrow[tid + 256] = __float2bfloat16((v1 - mu) * rstd * w2[tid + 256] + b2[tid + 256]);
}

// =======================================================================
extern "C" void kernel_launch(void* const* d_in, const int* in_sizes, int n_in,
                              void* d_out, int out_size, void* d_ws, size_t ws_size,
                              hipStream_t stream) {
  const float* x       = (const float*)d_in[0];
  const float* x_ref   = (const float*)d_in[1];
  const float* mask    = (const float*)d_in[2];
  const float* n1w     = (const float*)d_in[3];
  const float* n1b     = (const float*)d_in[4];
  const float* qkv_w   = (const float*)d_in[5];
  const float* qkv_b   = (const float*)d_in[6];
  const float* diff_mu = (const float*)d_in[7];
  const float* diff_ls = (const float*)d_in[8];
  const float* rpb     = (const float*)d_in[9];
  const float* ref_w   = (const float*)d_in[10];
  const float* ref_b   = (const float*)d_in[11];
  const float* conv_w  = (const float*)d_in[12];
  const float* conv_b  = (const float*)d_in[13];
  const float* proj_w  = (const float*)d_in[14];
  const float* proj_b  = (const float*)d_in[15];
  const float* n2w     = (const float*)d_in[16];
  const float* n2b     = (const float*)d_in[17];
  const float* fc1_w   = (const float*)d_in[18];
  const float* fc1_b   = (const float*)d_in[19];
  const float* fc2_w   = (const float*)d_in[20];
  const float* fc2_b   = (const float*)d_in[21];
  float* out = (float*)d_out;

  char* ws = (char*)d_ws;
  size_t off = 0;
  auto alloc = [&](size_t bytes) -> char* {
    char* p = ws + off;
    off += (bytes + 255) & ~(size_t)255;
    return p;
  };
  // ---- persistent small buffers ----
  __hip_bfloat16* wq_bf = (__hip_bfloat16*)alloc(1536ULL * 512 * 2);   // q rows 0..511, kv rows 512..1535
  __hip_bfloat16* wp_bf = (__hip_bfloat16*)alloc(512ULL * 512 * 2);
  __hip_bfloat16* w1_bf = (__hip_bfloat16*)alloc(2048ULL * 512 * 2);
  __hip_bfloat16* w2_bf = (__hip_bfloat16*)alloc(512ULL * 2048 * 2);
  float* refq  = (float*)alloc(2ULL * 16 * 100 * 32 * 4);
  unsigned short* refvT = (unsigned short*)alloc(2ULL * 16 * 32 * 100 * 2);
  unsigned short* maskB = (unsigned short*)alloc(256ULL * 49 * 56 * 2);
  unsigned short* rpbT  = (unsigned short*)alloc(16ULL * 49 * 56 * 2);
  float* psum  = (float*)alloc(2ULL * 1568 * 16 * 4);
  float* psumq = (float*)alloc(2ULL * 1568 * 16 * 4);
  float* stats = (float*)alloc(64 * 4);
  // ---- aliased regions ----
  char* regX  = alloc(25088ULL * 512 * 2);      // xw_bf -> att_bf            (25.7 MB)
  char* regQ  = alloc(25088ULL * 512 * 2);      // q_bf  -> h_bf              (25.7 MB)
  char* regRA = alloc(2ULL * 16 * 12544 * 100 * 2);  // ra    -> hg (per-chunk) (80.3 MB)
  char* regU  = alloc(2ULL * 16 * 12544 * 100 * 2);  // u -> kv_bf + proj_bf    (80.3 MB)

  __hip_bfloat16* xw_bf   = (__hip_bfloat16*)regX;
  __hip_bfloat16* att_bf  = (__hip_bfloat16*)regX;                      // after kv GEMM
  __hip_bfloat16* q_bf    = (__hip_bfloat16*)regQ;
  __hip_bfloat16* h_bf    = (__hip_bfloat16*)regQ;                      // after ra_kernel
  __hip_bfloat16* ra      = (__hip_bfloat16*)regRA;
  __hip_bfloat16* hg      = (__hip_bfloat16*)regRA;                     // after attn (51.4MB/chunk)
  __hip_bfloat16* u       = (__hip_bfloat16*)regU;
  __hip_bfloat16* kv_bf   = (__hip_bfloat16*)regU;                      // after conv rounds (51.4MB)
  __hip_bfloat16* proj_bf = (__hip_bfloat16*)(regU + 51380224);         // after attn (25.7MB)

  // 1. weights -> bf16 ; bias tables
  f2b_kernel<<<3072, 256, 0, stream>>>(qkv_w, wq_bf, 786432);
  f2b_kernel<<<1024, 256, 0, stream>>>(proj_w, wp_bf, 262144);
  f2b_kernel<<<4096, 256, 0, stream>>>(fc1_w, w1_bf, 1048576);
  f2b_kernel<<<4096, 256, 0, stream>>>(fc2_w, w2_bf, 1048576);
  maskb_kernel<<<2744, 256, 0, stream>>>(mask, maskB);
  rpbt_kernel<<<172, 256, 0, stream>>>(rpb, rpbT);
  // 2. LN1 + shift + window partition
  ln1_window_kernel<<<25088, 256, 0, stream>>>(x, n1w, n1b, xw_bf);
  // 3. q GEMM (bias -> bf16)
  gemm_bt<1><<<dim3(196, 4), 256, 0, stream>>>(xw_bf, wq_bf, qkv_b, nullptr, q_bf,
                                               25088, 512, 512);
  // 4. reference tokens
  ref_kernel<<<200, 256, 0, stream>>>(x_ref, ref_w, ref_b, diff_mu, diff_ls, refq, refvT);
  // 5. ra = q @ ref_q^T   (q region free afterwards)
  ra_kernel<<<8192, 256, 0, stream>>>(q_bf, refq, ra);
  // 6. conv diffusion x3 (MFMA implicit GEMM)
  for (int rd = 0; rd < 3; rd++) {
    conv_kernel<<<dim3(1568, 2), 256, 0, stream>>>(ra, conv_w, conv_b, u, psum, psumq);
    conv_stats_kernel<<<32, 256, 0, stream>>>(psum, psumq, stats);
    conv_apply_kernel<<<4096, 256, 0, stream>>>(ra, u, stats);
  }
  // 7. kv GEMM into dead u region (xw still live as A input)
  gemm_bt<1><<<dim3(196, 8), 256, 0, stream>>>(xw_bf, wq_bf + 512 * 512, qkv_b + 512,
                                               nullptr, kv_bf, 25088, 1024, 512);
  // 8. fused MFMA attention (xw dead -> att_bf)
  attn_kernel<<<8192, 256, 0, stream>>>(ra, refvT, kv_bf, rpbT, maskB, att_bf);
  // 9. proj GEMM (bias -> bf16, into regU tail)
  gemm_bt<1><<<dim3(196, 4), 256, 0, stream>>>(att_bf, wp_bf, proj_b, nullptr, proj_bf,
                                               25088, 512, 512);
  // 10. window reverse + residual + LN2 (h_bf into dead q region)
  resid_ln2_kernel<<<25088, 256, 0, stream>>>(x, proj_bf, n2w, n2b, out, h_bf);
  // 11. MLP in two M-chunks; hg reuses dead ra region
  for (int ch = 0; ch < 2; ch++) {
    const __hip_bfloat16* hA = h_bf + (size_t)ch * 12544 * 512;
    gemm_bt<2><<<dim3(98, 16), 256, 0, stream>>>(hA, w1_bf, fc1_b, nullptr, hg,
                                                 12544, 2048, 512);
    gemm_bt<3><<<dim3(98, 4), 256, 0, stream>>>(hg, w2_bf, fc2_b,
                                                out + (size_t)ch * 12544 * 512, nullptr,
                                                12544, 512, 2048);
  }
}

// Round 6
// 1373.539 us; speedup vs baseline: 1.6505x; 1.0893x over previous
//
#include <hip/hip_runtime.h>
#include <hip/hip_bf16.h>

typedef __attribute__((ext_vector_type(8))) short short8;        // 8 bf16 = 4 VGPRs
typedef __attribute__((ext_vector_type(8))) unsigned short ushort8;
typedef __attribute__((ext_vector_type(4))) float f32x4;
typedef __attribute__((ext_vector_type(4))) unsigned int u32x4;
typedef __attribute__((ext_vector_type(2))) unsigned int u32x2;

#define DEV __device__ __forceinline__

DEV float gelu_f(float x) { return 0.5f * x * (1.f + erff(x * 0.70710678118654752440f)); }

DEV float bf2f(unsigned short s) {
  unsigned int t = ((unsigned int)s) << 16;
  float f; __builtin_memcpy(&f, &t, 4); return f;
}
DEV unsigned short f2bf(float f) {
  __hip_bfloat16 b = __float2bfloat16(f);
  unsigned short s; __builtin_memcpy(&s, &b, 2); return s;
}

// block-wide (256 thr) sum of two values; every thread gets the totals
DEV void block_reduce2(float& s, float& s2) {
  __shared__ float red[8];
  int tid = threadIdx.x;
#pragma unroll
  for (int o = 32; o > 0; o >>= 1) { s += __shfl_down(s, o); s2 += __shfl_down(s2, o); }
  if ((tid & 63) == 0) { red[tid >> 6] = s; red[4 + (tid >> 6)] = s2; }
  __syncthreads();
  s  = red[0] + red[1] + red[2] + red[3];
  s2 = red[4] + red[5] + red[6] + red[7];
}

// ---------------- weight fp32 -> bf16 ----------------
__global__ __launch_bounds__(256) void f2b_kernel(const float* __restrict__ in,
                                                  __hip_bfloat16* __restrict__ o, int n) {
  int i = blockIdx.x * 256 + threadIdx.x;
  if (i < n) o[i] = __float2bfloat16(in[i]);
}

// ---------------- mask -> bf16 padded [win][49][56] ----------------
__global__ __launch_bounds__(256) void maskb_kernel(const float* __restrict__ mask,
                                                    unsigned short* __restrict__ maskB) {
  int i = blockIdx.x * 256 + threadIdx.x;          // 256*49*56 = 702464 exactly
  int m = i % 56, rest = i / 56;
  int n = rest % 49, win = rest / 49;
  unsigned short v = 0;
  if (m < 49) v = f2bf(mask[((size_t)win * 49 + n) * 49 + m]);
  maskB[i] = v;
}

// ---------------- rpb -> bf16 padded [h][49][56] ----------------
__global__ __launch_bounds__(256) void rpbt_kernel(const float* __restrict__ rpb,
                                                   unsigned short* __restrict__ rpbT) {
  int i = blockIdx.x * 256 + threadIdx.x;          // 16*49*56 = 43904
  if (i >= 43904) return;
  int m = i % 56, rest = i / 56;
  int n = rest % 49, h = rest / 49;
  unsigned short v = 0;
  if (m < 49) {
    int rp = (n / 7 - m / 7 + 6) * 13 + (n % 7 - m % 7 + 6);
    v = f2bf(rpb[rp * 16 + h]);
  }
  rpbT[i] = v;
}

// ---------------- LN1 + cyclic shift + window partition -> bf16 ----------------
__global__ __launch_bounds__(256) void ln1_window_kernel(
    const float* __restrict__ x, const float* __restrict__ w, const float* __restrict__ b,
    __hip_bfloat16* __restrict__ xw) {
  int t = blockIdx.x;                 // 0..25087
  int b_ = t / 49, n = t % 49;
  int bb = b_ >> 8, win = b_ & 255;
  int wi = win >> 4, wj = win & 15;
  int ii = n / 7, jj = n % 7;
  int sh = (wi * 7 + ii + 3) % 112;
  int sw = (wj * 7 + jj + 3) % 112;
  const float* row = x + ((size_t)bb * 12544 + sh * 112 + sw) * 512;
  int tid = threadIdx.x;
  float v0 = row[tid], v1 = row[tid + 256];
  float s = v0 + v1, s2 = v0 * v0 + v1 * v1;
  block_reduce2(s, s2);
  float mu = s * (1.f / 512.f);
  float rstd = rsqrtf(s2 * (1.f / 512.f) - mu * mu + 1e-5f);
  __hip_bfloat16* orow = xw + (size_t)t * 512;
  orow[tid]       = __float2bfloat16((v0 - mu) * rstd * w[tid] + b[tid]);
  orow[tid + 256] = __float2bfloat16((v1 - mu) * rstd * w[tid + 256] + b[tid + 256]);
}

// ---------------- generic bf16 MFMA GEMM:  C = A(MxK) @ B(NxK)^T + bias ----------------
// EPI: 1 = bias -> bf16 store ; 2 = bias+gelu -> bf16 ; 3 = bias -> f32 +=
template <int EPI>
__global__ __launch_bounds__(256) void gemm_bt(
    const __hip_bfloat16* __restrict__ A, const __hip_bfloat16* __restrict__ B,
    const float* __restrict__ bias, float* __restrict__ outF,
    __hip_bfloat16* __restrict__ outB, int M, int N, int K) {
  __shared__ __align__(16) __hip_bfloat16 As[128][72];   // 64 data + 8 pad
  __shared__ __align__(16) __hip_bfloat16 Bs[128][72];
  int m0 = blockIdx.x * 128, n0 = blockIdx.y * 128;
  int tid = threadIdx.x;
  int wave = tid >> 6, lane = tid & 63;
  int wm = (wave & 1) * 64, wn = (wave >> 1) * 64;
  int lrow = lane & 15, kq = lane >> 4;
  f32x4 acc[4][4] = {};
  for (int k0 = 0; k0 < K; k0 += 64) {
#pragma unroll
    for (int i = 0; i < 4; i++) {
      int chunk = tid + i * 256;
      int row = chunk >> 3, c8 = chunk & 7;
      *reinterpret_cast<u32x4*>(&As[row][c8 * 8]) =
          *reinterpret_cast<const u32x4*>(&A[(size_t)(m0 + row) * K + k0 + c8 * 8]);
      *reinterpret_cast<u32x4*>(&Bs[row][c8 * 8]) =
          *reinterpret_cast<const u32x4*>(&B[(size_t)(n0 + row) * K + k0 + c8 * 8]);
    }
    __syncthreads();
#pragma unroll
    for (int ks = 0; ks < 2; ks++) {
      short8 af[4], bf[4];
#pragma unroll
      for (int t = 0; t < 4; t++) {
        af[t] = *reinterpret_cast<const short8*>(&As[wm + t * 16 + lrow][ks * 32 + kq * 8]);
        bf[t] = *reinterpret_cast<const short8*>(&Bs[wn + t * 16 + lrow][ks * 32 + kq * 8]);
      }
#pragma unroll
      for (int tm = 0; tm < 4; tm++)
#pragma unroll
        for (int tn = 0; tn < 4; tn++)
          acc[tm][tn] = __builtin_amdgcn_mfma_f32_16x16x32_bf16(af[tm], bf[tn], acc[tm][tn], 0, 0, 0);
    }
    __syncthreads();
  }
  // D: row=(lane>>4)*4+r, col=lane&15 (verified gfx950 C/D layout)
#pragma unroll
  for (int tm = 0; tm < 4; tm++) {
#pragma unroll
    for (int tn = 0; tn < 4; tn++) {
      int col = n0 + wn + tn * 16 + lrow;
      float bv = bias[col];
#pragma unroll
      for (int r = 0; r < 4; r++) {
        int row = m0 + wm + tm * 16 + kq * 4 + r;
        float v = acc[tm][tn][r] + bv;
        size_t o = (size_t)row * N + col;
        if (EPI == 1) outB[o] = __float2bfloat16(v);
        else if (EPI == 2) outB[o] = __float2bfloat16(gelu_f(v));
        else outF[o] += v;
      }
    }
  }
}

// ---------------- reference-token projection (tiny) ----------------
// writes refq bf16 [b][h][r][32] and refvT bf16 [b][h][d][r]
__global__ __launch_bounds__(256) void ref_kernel(
    const float* __restrict__ x_ref, const float* __restrict__ w, const float* __restrict__ bias,
    const float* __restrict__ diff_mu, const float* __restrict__ diff_ls,
    unsigned short* __restrict__ refq, unsigned short* __restrict__ refvT) {
  int blk = blockIdx.x;               // 0..199
  int b = blk / 100, r = blk % 100;
  __shared__ float xs[512];
  int tid = threadIdx.x;
  const float* xr = x_ref + (size_t)(b * 100 + r) * 512;
  xs[tid] = xr[tid];
  xs[tid + 256] = xr[tid + 256];
  __syncthreads();
#pragma unroll
  for (int cc = 0; cc < 4; cc++) {
    int c = cc * 256 + tid;
    const float* wr = w + (size_t)c * 512;
    float s = bias[c];
    for (int k = 0; k < 512; k++) s += xs[k] * wr[k];
    if (c < 512) {
      float v = diff_mu[c] + expf(diff_ls[c]) * s;
      int hh = c >> 5, d = c & 31;
      refq[((size_t)(b * 16 + hh) * 100 + r) * 32 + d] = f2bf(v);
    } else {
      int c2 = c - 512, hh = c2 >> 5, d = c2 & 31;
      refvT[(((size_t)b * 16 + hh) * 32 + d) * 100 + r] = f2bf(s);
    }
  }
}

// ---------------- ra = q @ ref_q^T ; MFMA ; block per (b_, head) ----------------
// M=49 (pad 64, wave = M-tile), N=100 (pad 112, 7 tiles), K=32 (exact).
__global__ __launch_bounds__(256) void ra_kernel(
    const __hip_bfloat16* __restrict__ q, const unsigned short* __restrict__ refq,
    __hip_bfloat16* __restrict__ ra) {
  __shared__ __align__(16) unsigned short q_s[64 * 40];    //  5,120 B (stride 40: conflict-free)
  __shared__ __align__(16) unsigned short rq_s[112 * 40];  //  8,960 B
  int blk = blockIdx.x;               // 8192
  int b_ = blk >> 4, h = blk & 15;
  int rb = b_ >> 8, win = b_ & 255;
  int tid = threadIdx.x;
  int wave = tid >> 6, lane = tid & 63;
  int lrow = lane & 15, kq = lane >> 4;
  u32x4 z4 = {};
  const unsigned short* qb = (const unsigned short*)q + (size_t)b_ * 49 * 512 + h * 32;
  for (int i = tid; i < 196; i += 256) {           // q: 49 rows x 4 chunks of 8
    int n = i >> 2, c = i & 3;
    *reinterpret_cast<u32x4*>(&q_s[n * 40 + c * 8]) =
        *reinterpret_cast<const u32x4*>(&qb[n * 512 + c * 8]);
  }
  for (int i = tid; i < 60; i += 256) {            // q M-pad rows 49..63
    int n = 49 + (i >> 2), c = i & 3;
    *reinterpret_cast<u32x4*>(&q_s[n * 40 + c * 8]) = z4;
  }
  const unsigned short* rqg = refq + (size_t)(rb * 16 + h) * 3200;
  for (int i = tid; i < 400; i += 256) {           // refq: 100 rows x 4 chunks
    int r = i >> 2, c = i & 3;
    *reinterpret_cast<u32x4*>(&rq_s[r * 40 + c * 8]) =
        *reinterpret_cast<const u32x4*>(&rqg[r * 32 + c * 8]);
  }
  for (int i = tid; i < 48; i += 256) {            // refq N-pad rows 100..111
    int r = 100 + (i >> 2), c = i & 3;
    *reinterpret_cast<u32x4*>(&rq_s[r * 40 + c * 8]) = z4;
  }
  __syncthreads();
  short8 a = *reinterpret_cast<const short8*>(&q_s[(wave * 16 + lrow) * 40 + kq * 8]);
  unsigned short* ra_base = (unsigned short*)ra + ((size_t)(rb * 16 + h) * 12544 + win * 49) * 100;
  f32x4 zero = {};
#pragma unroll
  for (int nt = 0; nt < 7; nt++) {
    short8 b = *reinterpret_cast<const short8*>(&rq_s[(nt * 16 + lrow) * 40 + kq * 8]);
    f32x4 c = __builtin_amdgcn_mfma_f32_16x16x32_bf16(a, b, zero, 0, 0, 0);
    int col = nt * 16 + lrow;
#pragma unroll
    for (int r = 0; r < 4; r++) {
      int n = wave * 16 + kq * 4 + r;
      if (n < 49 && col < 100) ra_base[n * 100 + col] = f2bf(c[r]);
    }
  }
}

// ---------------- implicit-GEMM MFMA conv: 16ch 3x3 over (2,16,12544,100) ----------------
__global__ __launch_bounds__(256) void conv_kernel(
    const __hip_bfloat16* __restrict__ ra_, const float* __restrict__ cw, const float* __restrict__ cb,
    __hip_bfloat16* __restrict__ u_, float* __restrict__ psum, float* __restrict__ psumsq) {
  __shared__ __align__(16) unsigned short in_s[10 * 103 * 16];   // 32,960 B
  __shared__ __align__(16) unsigned short w_s[16 * 160];         //  5,120 B
  __shared__ float sred_s[4][16], sred_s2[4][16];
  const unsigned short* ra = (const unsigned short*)ra_;
  unsigned short* u = (unsigned short*)u_;
  int yt = blockIdx.x, bb = blockIdx.y;
  int y0 = yt * 8;
  int tid = threadIdx.x;
  int wave = tid >> 6, lane = tid & 63;
  int lrow = lane & 15, kq = lane >> 4;
  for (int i = tid; i < 2560; i += 256) {
    int co = i / 160, k = i % 160;
    unsigned short v = 0;
    if (k < 144) {
      int ci = k & 15, p = k >> 4;
      v = f2bf(cw[(co * 16 + ci) * 9 + p]);
    }
    w_s[i] = v;
  }
  for (int i = tid; i < 16480; i += 256) {
    int xl = i % 103, rem = i / 103;
    int yl = rem % 10, ci = rem / 10;
    int gy = y0 - 1 + yl, gx = xl - 1;
    unsigned short v = 0;
    if (gy >= 0 && gy < 12544 && gx >= 0 && gx < 100)
      v = ra[(((size_t)bb * 16 + ci) * 12544 + gy) * 100 + gx];
    in_s[(yl * 103 + xl) * 16 + ci] = v;
  }
  __syncthreads();

  short8 afr[5];
#pragma unroll
  for (int c = 0; c < 5; c++)
    afr[c] = *reinterpret_cast<const short8*>(&w_s[lrow * 160 + c * 32 + kq * 8]);
  int kqh = kq >> 1, ci0 = (kq & 1) * 8;
  int kyA[5], kxA[5];
#pragma unroll
  for (int c = 0; c < 5; c++) {
    int p = c * 2 + kqh; if (p > 8) p = 0;
    kyA[c] = p / 3; kxA[c] = p % 3;
  }
  float bias_r[4];
#pragma unroll
  for (int r = 0; r < 4; r++) bias_r[r] = cb[kq * 4 + r];
  float s_r[4] = {0.f, 0.f, 0.f, 0.f}, s2_r[4] = {0.f, 0.f, 0.f, 0.f};

#pragma unroll
  for (int rowi = 0; rowi < 2; rowi++) {
    int yl = wave + rowi * 4;
#pragma unroll
    for (int xg = 0; xg < 7; xg++) {
      int px = xg * 16 + lrow;
      int pxc = px < 100 ? px : 99;
      f32x4 acc = {};
#pragma unroll
      for (int c = 0; c < 5; c++) {
        short8 bfrag = *reinterpret_cast<const short8*>(
            &in_s[((yl + kyA[c]) * 103 + pxc + kxA[c]) * 16 + ci0]);
        acc = __builtin_amdgcn_mfma_f32_16x16x32_bf16(afr[c], bfrag, acc, 0, 0, 0);
      }
      int gy = y0 + yl;
      bool valid = px < 100;
#pragma unroll
      for (int r = 0; r < 4; r++) {
        float v = acc[r] + bias_r[r];
        if (valid) {
          u[(((size_t)bb * 16 + kq * 4 + r) * 12544 + gy) * 100 + px] = f2bf(v);
          s_r[r] += v; s2_r[r] += v * v;
        }
      }
    }
  }
#pragma unroll
  for (int o = 1; o < 16; o <<= 1)
#pragma unroll
    for (int r = 0; r < 4; r++) { s_r[r] += __shfl_xor(s_r[r], o); s2_r[r] += __shfl_xor(s2_r[r], o); }
  if (lrow == 0)
#pragma unroll
    for (int r = 0; r < 4; r++) { sred_s[wave][kq * 4 + r] = s_r[r]; sred_s2[wave][kq * 4 + r] = s2_r[r]; }
  __syncthreads();
  if (tid < 16) {
    float s  = sred_s[0][tid] + sred_s[1][tid] + sred_s[2][tid] + sred_s[3][tid];
    float s2 = sred_s2[0][tid] + sred_s2[1][tid] + sred_s2[2][tid] + sred_s2[3][tid];
    size_t pi = ((size_t)bb * 1568 + yt) * 16 + tid;
    psum[pi] = s; psumsq[pi] = s2;
  }
}

__global__ __launch_bounds__(256) void conv_stats_kernel(
    const float* __restrict__ psum, const float* __restrict__ psumsq, float* __restrict__ stats) {
  int g = blockIdx.x;                 // 32 = (b, co)
  int bb = g >> 4, co = g & 15;
  int tid = threadIdx.x;
  float s = 0.f, s2 = 0.f;
  for (int t = tid; t < 1568; t += 256) {
    size_t pi = ((size_t)bb * 1568 + t) * 16 + co;
    s += psum[pi];
    s2 += psumsq[pi];
  }
  block_reduce2(s, s2);
  if (tid == 0) {
    const float inv = 1.f / 1254400.f;
    float mu = s * inv;
    float var = s2 * inv - mu * mu;
    stats[g * 2] = mu;
    stats[g * 2 + 1] = rsqrtf(var + 1e-5f);
  }
}

__global__ __launch_bounds__(256) void conv_apply_kernel(
    __hip_bfloat16* __restrict__ ra, const __hip_bfloat16* __restrict__ u,
    const float* __restrict__ stats) {
  const int total8 = 5017600;         // 40,140,800 / 8
  int stride = gridDim.x * 256;
  for (int i = blockIdx.x * 256 + threadIdx.x; i < total8; i += stride) {
    int g = i / 156800;               // 1,254,400 / 8 per (b,ch) group
    float mu = stats[g * 2], rstd = stats[g * 2 + 1];
    ushort8 uu = reinterpret_cast<const ushort8*>(u)[i];
    ushort8 rr = reinterpret_cast<const ushort8*>(ra)[i];
    ushort8 oo;
#pragma unroll
    for (int j = 0; j < 8; j++) {
      float rv = bf2f(rr[j]) + gelu_f((bf2f(uu[j]) - mu) * rstd);
      oo[j] = f2bf(rv);
    }
    reinterpret_cast<ushort8*>(ra)[i] = oo;
  }
}

// ---------------- fused MFMA attention ----------------
__global__ __launch_bounds__(256) void attn_kernel(
    const __hip_bfloat16* __restrict__ ra_, const unsigned short* __restrict__ refvT,
    const __hip_bfloat16* __restrict__ kv_, const unsigned short* __restrict__ rpbT,
    const unsigned short* __restrict__ maskB, __hip_bfloat16* __restrict__ att_) {
  __shared__ __align__(16) char smem[36352];
  unsigned short* P1  = (unsigned short*)smem;              // stride 136
  unsigned short* rvT = (unsigned short*)(smem + 17408);    // stride 136
  unsigned short* P2  = (unsigned short*)smem;              // stride 72
  unsigned short* vT  = (unsigned short*)(smem + 9216);     // stride 72
  unsigned short* qn  = (unsigned short*)(smem + 26112);    // stride 40
  unsigned short* kb  = (unsigned short*)(smem + 31232);    // stride 40

  int blk = blockIdx.x;               // 8192
  int b_ = blk >> 4, h = blk & 15;
  int rb = b_ >> 8, win = b_ & 255;
  int tid = threadIdx.x;
  int wave = tid >> 6, lane = tid & 63;
  int lrow = lane & 15, kq = lane >> 4;
  const unsigned short* ra = (const unsigned short*)ra_;
  const unsigned short* kv = (const unsigned short*)kv_;
  unsigned short* att = (unsigned short*)att_;
  u32x2 zz = {};

  // ---- phase A staging (vectorized) ----
  const unsigned short* rab = ra + ((size_t)(rb * 16 + h) * 12544 + win * 49) * 100;
  for (int i = tid; i < 1225; i += 256) {
    int n = i / 25, c = i % 25;
    *reinterpret_cast<u32x2*>(&P1[n * 136 + c * 4]) =
        *reinterpret_cast<const u32x2*>(&rab[n * 100 + c * 4]);
  }
  for (int i = tid; i < 343; i += 256) {
    int n = i / 7, c = i % 7;
    *reinterpret_cast<u32x2*>(&P1[n * 136 + 100 + c * 4]) = zz;
  }
  const unsigned short* rvtg = refvT + (size_t)(rb * 16 + h) * 3200;
  for (int i = tid; i < 800; i += 256) {
    int d = i / 25, c = i % 25;
    *reinterpret_cast<u32x2*>(&rvT[d * 136 + c * 4]) =
        *reinterpret_cast<const u32x2*>(&rvtg[d * 100 + c * 4]);
  }
  for (int i = tid; i < 224; i += 256) {
    int d = i / 7, c = i % 7;
    *reinterpret_cast<u32x2*>(&rvT[d * 136 + 100 + c * 4]) = zz;
  }
  const unsigned short* kvb = kv + (size_t)b_ * 49 * 1024;
  for (int i = tid; i < 196; i += 256) {
    int m = i >> 2, c = i & 3;
    *reinterpret_cast<u32x4*>(&kb[m * 40 + c * 8]) =
        *reinterpret_cast<const u32x4*>(&kvb[m * 1024 + h * 32 + c * 8]);
  }
  __syncthreads();

  // ---- softmax over 100 ref slots ----
  if (tid < 196) {
    int n = tid >> 2, q = tid & 3;
    unsigned short* row = P1 + n * 136;
    float mx = -1e30f;
    for (int r = q * 25; r < q * 25 + 25; r++) mx = fmaxf(mx, bf2f(row[r]));
    mx = fmaxf(mx, __shfl_xor(mx, 1));
    mx = fmaxf(mx, __shfl_xor(mx, 2));
    float sm = 0.f;
    for (int r = q * 25; r < q * 25 + 25; r++) {
      float e = __expf(bf2f(row[r]) - mx); sm += e; row[r] = f2bf(e);
    }
    sm += __shfl_xor(sm, 1);
    sm += __shfl_xor(sm, 2);
    float inv = 1.f / sm;
    for (int r = q * 25; r < q * 25 + 25; r++) row[r] = f2bf(bf2f(row[r]) * inv);
  }
  __syncthreads();

  // ---- qnew = P1 @ rvT^T  (M=64, N=32, K=128) ----
  f32x4 acc1[2] = {};
#pragma unroll
  for (int ks = 0; ks < 4; ks++) {
    short8 a = *reinterpret_cast<const short8*>(&P1[(wave * 16 + lrow) * 136 + ks * 32 + kq * 8]);
#pragma unroll
    for (int dt = 0; dt < 2; dt++) {
      short8 b = *reinterpret_cast<const short8*>(&rvT[(dt * 16 + lrow) * 136 + ks * 32 + kq * 8]);
      acc1[dt] = __builtin_amdgcn_mfma_f32_16x16x32_bf16(a, b, acc1[dt], 0, 0, 0);
    }
  }
#pragma unroll
  for (int dt = 0; dt < 2; dt++)
#pragma unroll
    for (int r = 0; r < 4; r++) {
      int n = wave * 16 + kq * 4 + r;
      qn[n * 40 + dt * 16 + lrow] = f2bf(acc1[dt][r] * 0.17677669529663688f);
    }
  __syncthreads();

  // ---- phase B: stage v^T via register transpose ----
  for (int i = tid; i < 196; i += 256) {
    int m = i >> 2, dg = (i & 3) * 8;
    ushort8 vv = *reinterpret_cast<const ushort8*>(&kvb[m * 1024 + 512 + h * 32 + dg]);
#pragma unroll
    for (int j = 0; j < 8; j++) vT[(dg + j) * 72 + m] = vv[j];
  }
  for (int i = tid; i < 480; i += 256) vT[(i / 15) * 72 + 49 + i % 15] = 0;

  // ---- logits = qn @ kb^T (N=64, K=32), +rpb+mask, register softmax ----
  const unsigned short* bt = maskB + (size_t)win * 2744;
  const unsigned short* rt = rpbT + (size_t)h * 2744;
  short8 aq = *reinterpret_cast<const short8*>(&qn[(wave * 16 + lrow) * 40 + kq * 8]);
  f32x4 zero = {};
  float val[4][4];
#pragma unroll
  for (int mt = 0; mt < 4; mt++) {
    short8 bk = *reinterpret_cast<const short8*>(&kb[(mt * 16 + lrow) * 40 + kq * 8]);
    f32x4 lg = __builtin_amdgcn_mfma_f32_16x16x32_bf16(aq, bk, zero, 0, 0, 0);
    int m = mt * 16 + lrow;
#pragma unroll
    for (int r = 0; r < 4; r++) {
      int n = wave * 16 + kq * 4 + r;
      float v;
      if (m < 49 && n < 49)
        v = lg[r] + bf2f(rt[n * 56 + m]) + bf2f(bt[n * 56 + m]);
      else v = -1e30f;
      val[mt][r] = v;
    }
  }
#pragma unroll
  for (int r = 0; r < 4; r++) {
    float mx = -1e30f;
#pragma unroll
    for (int mt = 0; mt < 4; mt++) mx = fmaxf(mx, val[mt][r]);
    mx = fmaxf(mx, __shfl_xor(mx, 1)); mx = fmaxf(mx, __shfl_xor(mx, 2));
    mx = fmaxf(mx, __shfl_xor(mx, 4)); mx = fmaxf(mx, __shfl_xor(mx, 8));
    float sm = 0.f, e[4];
#pragma unroll
    for (int mt = 0; mt < 4; mt++) { e[mt] = __expf(val[mt][r] - mx); sm += e[mt]; }
    sm += __shfl_xor(sm, 1); sm += __shfl_xor(sm, 2);
    sm += __shfl_xor(sm, 4); sm += __shfl_xor(sm, 8);
    float inv = 1.f / sm;
    int n = wave * 16 + kq * 4 + r;
#pragma unroll
    for (int mt = 0; mt < 4; mt++) P2[n * 72 + mt * 16 + lrow] = f2bf(e[mt] * inv);
  }
  __syncthreads();

  // ---- out = P2 @ vT^T (N=32, K=64) -> global bf16 ----
  f32x4 acc2[2] = {};
#pragma unroll
  for (int ks = 0; ks < 2; ks++) {
    short8 ap = *reinterpret_cast<const short8*>(&P2[(wave * 16 + lrow) * 72 + ks * 32 + kq * 8]);
#pragma unroll
    for (int dt = 0; dt < 2; dt++) {
      short8 bv = *reinterpret_cast<const short8*>(&vT[(dt * 16 + lrow) * 72 + ks * 32 + kq * 8]);
      acc2[dt] = __builtin_amdgcn_mfma_f32_16x16x32_bf16(ap, bv, acc2[dt], 0, 0, 0);
    }
  }
  unsigned short* ab = att + (size_t)b_ * 49 * 512 + h * 32;
#pragma unroll
  for (int dt = 0; dt < 2; dt++)
#pragma unroll
    for (int r = 0; r < 4; r++) {
      int n = wave * 16 + kq * 4 + r;
      if (n < 49) ab[n * 512 + dt * 16 + lrow] = f2bf(acc2[dt][r]);
    }
}

// ---------------- window-reverse gather + residual + LN2 ----------------
__global__ __launch_bounds__(256) void resid_ln2_kernel(
    const float* __restrict__ x, const __hip_bfloat16* __restrict__ proj_out,
    const float* __restrict__ w2, const float* __restrict__ b2,
    float* __restrict__ out, __hip_bfloat16* __restrict__ hout) {
  int blk = blockIdx.x;               // b*12544 + l
  int bb = blk / 12544, l = blk % 12544;
  int hh = l / 112, ww = l % 112;
  int hs = (hh + 109) % 112, wsx = (ww + 109) % 112;   // (h-3) mod 112
  int t = (bb * 256 + (hs / 7) * 16 + (wsx / 7)) * 49 + (hs % 7) * 7 + (wsx % 7);
  const float* xr = x + (size_t)blk * 512;
  const __hip_bfloat16* pr = proj_out + (size_t)t * 512;
  int tid = threadIdx.x;
  float v0 = xr[tid] + __bfloat162float(pr[tid]);
  float v1 = xr[tid + 256] + __bfloat162float(pr[tid + 256]);
  float* orow = out + (size_t)blk * 512;
  orow[tid] = v0;
  orow[tid + 256] = v1;
  float s = v0 + v1, s2 = v0 * v0 + v1 * v1;
  block_reduce2(s, s2);
  float mu = s * (1.f / 512.f);
  float rstd = rsqrtf(s2 * (1.f / 512.f) - mu * mu + 1e-5f);
  __hip_bfloat16* hrow = hout + (size_t)blk * 512;
  hrow[tid]       = __float2bfloat16((v0 - mu) * rstd * w2[tid] + b2[tid]);
  hrow[tid + 256] = __float2bfloat16((v1 - mu) * rstd * w2[tid + 256] + b2[tid + 256]);
}

// =======================================================================
extern "C" void kernel_launch(void* const* d_in, const int* in_sizes, int n_in,
                              void* d_out, int out_size, void* d_ws, size_t ws_size,
                              hipStream_t stream) {
  const float* x       = (const float*)d_in[0];
  const float* x_ref   = (const float*)d_in[1];
  const float* mask    = (const float*)d_in[2];
  const float* n1w     = (const float*)d_in[3];
  const float* n1b     = (const float*)d_in[4];
  const float* qkv_w   = (const float*)d_in[5];
  const float* qkv_b   = (const float*)d_in[6];
  const float* diff_mu = (const float*)d_in[7];
  const float* diff_ls = (const float*)d_in[8];
  const float* rpb     = (const float*)d_in[9];
  const float* ref_w   = (const float*)d_in[10];
  const float* ref_b   = (const float*)d_in[11];
  const float* conv_w  = (const float*)d_in[12];
  const float* conv_b  = (const float*)d_in[13];
  const float* proj_w  = (const float*)d_in[14];
  const float* proj_b  = (const float*)d_in[15];
  const float* n2w     = (const float*)d_in[16];
  const float* n2b     = (const float*)d_in[17];
  const float* fc1_w   = (const float*)d_in[18];
  const float* fc1_b   = (const float*)d_in[19];
  const float* fc2_w   = (const float*)d_in[20];
  const float* fc2_b   = (const float*)d_in[21];
  float* out = (float*)d_out;

  char* ws = (char*)d_ws;
  size_t off = 0;
  auto alloc = [&](size_t bytes) -> char* {
    char* p = ws + off;
    off += (bytes + 255) & ~(size_t)255;
    return p;
  };
  // ---- persistent small buffers ----
  __hip_bfloat16* wq_bf = (__hip_bfloat16*)alloc(1536ULL * 512 * 2);   // q rows 0..511, kv rows 512..1535
  __hip_bfloat16* wp_bf = (__hip_bfloat16*)alloc(512ULL * 512 * 2);
  __hip_bfloat16* w1_bf = (__hip_bfloat16*)alloc(2048ULL * 512 * 2);
  __hip_bfloat16* w2_bf = (__hip_bfloat16*)alloc(512ULL * 2048 * 2);
  unsigned short* refq  = (unsigned short*)alloc(2ULL * 16 * 100 * 32 * 2);
  unsigned short* refvT = (unsigned short*)alloc(2ULL * 16 * 32 * 100 * 2);
  unsigned short* maskB = (unsigned short*)alloc(256ULL * 49 * 56 * 2);
  unsigned short* rpbT  = (unsigned short*)alloc(16ULL * 49 * 56 * 2);
  float* psum  = (float*)alloc(2ULL * 1568 * 16 * 4);
  float* psumq = (float*)alloc(2ULL * 1568 * 16 * 4);
  float* stats = (float*)alloc(64 * 4);
  // ---- aliased regions ----
  char* regX  = alloc(25088ULL * 512 * 2);      // xw_bf -> att_bf            (25.7 MB)
  char* regQ  = alloc(25088ULL * 512 * 2);      // q_bf  -> h_bf              (25.7 MB)
  char* regRA = alloc(2ULL * 16 * 12544 * 100 * 2);  // ra    -> hg (per-chunk) (80.3 MB)
  char* regU  = alloc(2ULL * 16 * 12544 * 100 * 2);  // u -> kv_bf + proj_bf    (80.3 MB)

  __hip_bfloat16* xw_bf   = (__hip_bfloat16*)regX;
  __hip_bfloat16* att_bf  = (__hip_bfloat16*)regX;                      // after kv GEMM
  __hip_bfloat16* q_bf    = (__hip_bfloat16*)regQ;
  __hip_bfloat16* h_bf    = (__hip_bfloat16*)regQ;                      // after ra_kernel
  __hip_bfloat16* ra      = (__hip_bfloat16*)regRA;
  __hip_bfloat16* hg      = (__hip_bfloat16*)regRA;                     // after attn (51.4MB/chunk)
  __hip_bfloat16* u       = (__hip_bfloat16*)regU;
  __hip_bfloat16* kv_bf   = (__hip_bfloat16*)regU;                      // after conv rounds (51.4MB)
  __hip_bfloat16* proj_bf = (__hip_bfloat16*)(regU + 51380224);         // after attn (25.7MB)

  // 1. weights -> bf16 ; bias tables
  f2b_kernel<<<3072, 256, 0, stream>>>(qkv_w, wq_bf, 786432);
  f2b_kernel<<<1024, 256, 0, stream>>>(proj_w, wp_bf, 262144);
  f2b_kernel<<<4096, 256, 0, stream>>>(fc1_w, w1_bf, 1048576);
  f2b_kernel<<<4096, 256, 0, stream>>>(fc2_w, w2_bf, 1048576);
  maskb_kernel<<<2744, 256, 0, stream>>>(mask, maskB);
  rpbt_kernel<<<172, 256, 0, stream>>>(rpb, rpbT);
  // 2. LN1 + shift + window partition
  ln1_window_kernel<<<25088, 256, 0, stream>>>(x, n1w, n1b, xw_bf);
  // 3. q GEMM (bias -> bf16)
  gemm_bt<1><<<dim3(196, 4), 256, 0, stream>>>(xw_bf, wq_bf, qkv_b, nullptr, q_bf,
                                               25088, 512, 512);
  // 4. reference tokens
  ref_kernel<<<200, 256, 0, stream>>>(x_ref, ref_w, ref_b, diff_mu, diff_ls, refq, refvT);
  // 5. ra = q @ ref_q^T (MFMA)
  ra_kernel<<<8192, 256, 0, stream>>>(q_bf, refq, ra);
  // 6. conv diffusion x3 (MFMA implicit GEMM)
  for (int rd = 0; rd < 3; rd++) {
    conv_kernel<<<dim3(1568, 2), 256, 0, stream>>>(ra, conv_w, conv_b, u, psum, psumq);
    conv_stats_kernel<<<32, 256, 0, stream>>>(psum, psumq, stats);
    conv_apply_kernel<<<4096, 256, 0, stream>>>(ra, u, stats);
  }
  // 7. kv GEMM into dead u region (xw still live as A input)
  gemm_bt<1><<<dim3(196, 8), 256, 0, stream>>>(xw_bf, wq_bf + 512 * 512, qkv_b + 512,
                                               nullptr, kv_bf, 25088, 1024, 512);
  // 8. fused MFMA attention (xw dead -> att_bf)
  attn_kernel<<<8192, 256, 0, stream>>>(ra, refvT, kv_bf, rpbT, maskB, att_bf);
  // 9. proj GEMM (bias -> bf16, into regU tail)
  gemm_bt<1><<<dim3(196, 4), 256, 0, stream>>>(att_bf, wp_bf, proj_b, nullptr, proj_bf,
                                               25088, 512, 512);
  // 10. window reverse + residual + LN2 (h_bf into dead q region)
  resid_ln2_kernel<<<25088, 256, 0, stream>>>(x, proj_bf, n2w, n2b, out, h_bf);
  // 11. MLP in two M-chunks; hg reuses dead ra region
  for (int ch = 0; ch < 2; ch++) {
    const __hip_bfloat16* hA = h_bf + (size_t)ch * 12544 * 512;
    gemm_bt<2><<<dim3(98, 16), 256, 0, stream>>>(hA, w1_bf, fc1_b, nullptr, hg,
                                                 12544, 2048, 512);
    gemm_bt<3><<<dim3(98, 4), 256, 0, stream>>>(hg, w2_bf, fc2_b,
                                                out + (size_t)ch * 12544 * 512, nullptr,
                                                12544, 512, 2048);
  }
}

// Round 7
// 1264.523 us; speedup vs baseline: 1.7928x; 1.0862x over previous
//
#include <hip/hip_runtime.h>
#include <hip/hip_bf16.h>

typedef __attribute__((ext_vector_type(8))) short short8;        // 8 bf16 = 4 VGPRs
typedef __attribute__((ext_vector_type(8))) unsigned short ushort8;
typedef __attribute__((ext_vector_type(4))) float f32x4;
typedef __attribute__((ext_vector_type(4))) unsigned int u32x4;
typedef __attribute__((ext_vector_type(2))) unsigned int u32x2;

#define DEV __device__ __forceinline__

DEV float gelu_f(float x) { return 0.5f * x * (1.f + erff(x * 0.70710678118654752440f)); }

DEV float bf2f(unsigned short s) {
  unsigned int t = ((unsigned int)s) << 16;
  float f; __builtin_memcpy(&f, &t, 4); return f;
}
DEV unsigned short f2bf(float f) {
  __hip_bfloat16 b = __float2bfloat16(f);
  unsigned short s; __builtin_memcpy(&s, &b, 2); return s;
}

// async global->LDS 16B/lane (dest = wave-uniform base + lane*16)
DEV void async_copy16(void* lds, const void* g) {
  __builtin_amdgcn_global_load_lds(
      (const __attribute__((address_space(1))) unsigned int*)g,
      (__attribute__((address_space(3))) unsigned int*)lds, 16, 0, 0);
}

// block-wide (256 thr) sum of two values; every thread gets the totals
DEV void block_reduce2(float& s, float& s2) {
  __shared__ float red[8];
  int tid = threadIdx.x;
#pragma unroll
  for (int o = 32; o > 0; o >>= 1) { s += __shfl_down(s, o); s2 += __shfl_down(s2, o); }
  if ((tid & 63) == 0) { red[tid >> 6] = s; red[4 + (tid >> 6)] = s2; }
  __syncthreads();
  s  = red[0] + red[1] + red[2] + red[3];
  s2 = red[4] + red[5] + red[6] + red[7];
}

// ---------------- weight fp32 -> bf16 ----------------
__global__ __launch_bounds__(256) void f2b_kernel(const float* __restrict__ in,
                                                  __hip_bfloat16* __restrict__ o, int n) {
  int i = blockIdx.x * 256 + threadIdx.x;
  if (i < n) o[i] = __float2bfloat16(in[i]);
}

// ---------------- mask -> bf16 padded [win][49][56] ----------------
__global__ __launch_bounds__(256) void maskb_kernel(const float* __restrict__ mask,
                                                    unsigned short* __restrict__ maskB) {
  int i = blockIdx.x * 256 + threadIdx.x;          // 256*49*56 = 702464 exactly
  int m = i % 56, rest = i / 56;
  int n = rest % 49, win = rest / 49;
  unsigned short v = 0;
  if (m < 49) v = f2bf(mask[((size_t)win * 49 + n) * 49 + m]);
  maskB[i] = v;
}

// ---------------- rpb -> bf16 padded [h][49][56] ----------------
__global__ __launch_bounds__(256) void rpbt_kernel(const float* __restrict__ rpb,
                                                   unsigned short* __restrict__ rpbT) {
  int i = blockIdx.x * 256 + threadIdx.x;          // 16*49*56 = 43904
  if (i >= 43904) return;
  int m = i % 56, rest = i / 56;
  int n = rest % 49, h = rest / 49;
  unsigned short v = 0;
  if (m < 49) {
    int rp = (n / 7 - m / 7 + 6) * 13 + (n % 7 - m % 7 + 6);
    v = f2bf(rpb[rp * 16 + h]);
  }
  rpbT[i] = v;
}

// ---------------- LN1 + cyclic shift + window partition -> bf16 ----------------
__global__ __launch_bounds__(256) void ln1_window_kernel(
    const float* __restrict__ x, const float* __restrict__ w, const float* __restrict__ b,
    __hip_bfloat16* __restrict__ xw) {
  int t = blockIdx.x;                 // 0..25087
  int b_ = t / 49, n = t % 49;
  int bb = b_ >> 8, win = b_ & 255;
  int wi = win >> 4, wj = win & 15;
  int ii = n / 7, jj = n % 7;
  int sh = (wi * 7 + ii + 3) % 112;
  int sw = (wj * 7 + jj + 3) % 112;
  const float* row = x + ((size_t)bb * 12544 + sh * 112 + sw) * 512;
  int tid = threadIdx.x;
  float v0 = row[tid], v1 = row[tid + 256];
  float s = v0 + v1, s2 = v0 * v0 + v1 * v1;
  block_reduce2(s, s2);
  float mu = s * (1.f / 512.f);
  float rstd = rsqrtf(s2 * (1.f / 512.f) - mu * mu + 1e-5f);
  __hip_bfloat16* orow = xw + (size_t)t * 512;
  orow[tid]       = __float2bfloat16((v0 - mu) * rstd * w[tid] + b[tid]);
  orow[tid + 256] = __float2bfloat16((v1 - mu) * rstd * w[tid + 256] + b[tid + 256]);
}

// ---------------- bf16 MFMA GEMM (global_load_lds staging): C = A @ B^T + bias ----------------
// EPI: 1 = bias -> bf16 store ; 2 = bias+gelu -> bf16 ; 3 = bias -> f32 +=
// Requires: M,N multiples of 128; K multiple of 64 (all call sites satisfy).
template <int EPI>
__global__ __launch_bounds__(256) void gemm_bt(
    const __hip_bfloat16* __restrict__ A, const __hip_bfloat16* __restrict__ B,
    const float* __restrict__ bias, float* __restrict__ outF,
    __hip_bfloat16* __restrict__ outB, int M, int N, int K) {
  __shared__ __align__(16) __hip_bfloat16 As[128 * 64];   // unpadded (global_load_lds layout)
  __shared__ __align__(16) __hip_bfloat16 Bs[128 * 64];
  int m0 = blockIdx.x * 128, n0 = blockIdx.y * 128;
  int tid = threadIdx.x;
  int wave = tid >> 6, lane = tid & 63;
  int wm = (wave & 1) * 64, wn = (wave >> 1) * 64;
  int lrow = lane & 15, kq = lane >> 4;
  int srow = lane >> 3, scol = (lane & 7) * 8;     // staging: 8 rows x 64 cols per wave-inst
  f32x4 acc[4][4] = {};
  for (int k0 = 0; k0 < K; k0 += 64) {
    int rb = wave * 32;
#pragma unroll
    for (int i = 0; i < 4; i++) {
      int row = rb + i * 8 + srow;
      async_copy16(&As[(rb + i * 8) * 64], &A[(size_t)(m0 + row) * K + k0 + scol]);
      async_copy16(&Bs[(rb + i * 8) * 64], &B[(size_t)(n0 + row) * K + k0 + scol]);
    }
    __syncthreads();
#pragma unroll
    for (int ks = 0; ks < 2; ks++) {
      short8 af[4], bf[4];
#pragma unroll
      for (int t = 0; t < 4; t++) {
        af[t] = *reinterpret_cast<const short8*>(&As[(wm + t * 16 + lrow) * 64 + ks * 32 + kq * 8]);
        bf[t] = *reinterpret_cast<const short8*>(&Bs[(wn + t * 16 + lrow) * 64 + ks * 32 + kq * 8]);
      }
#pragma unroll
      for (int tm = 0; tm < 4; tm++)
#pragma unroll
        for (int tn = 0; tn < 4; tn++)
          acc[tm][tn] = __builtin_amdgcn_mfma_f32_16x16x32_bf16(af[tm], bf[tn], acc[tm][tn], 0, 0, 0);
    }
    __syncthreads();
  }
  // D: row=(lane>>4)*4+r, col=lane&15 (verified gfx950 C/D layout)
#pragma unroll
  for (int tm = 0; tm < 4; tm++) {
#pragma unroll
    for (int tn = 0; tn < 4; tn++) {
      int col = n0 + wn + tn * 16 + lrow;
      float bv = bias[col];
#pragma unroll
      for (int r = 0; r < 4; r++) {
        int row = m0 + wm + tm * 16 + kq * 4 + r;
        float v = acc[tm][tn][r] + bv;
        size_t o = (size_t)row * N + col;
        if (EPI == 1) outB[o] = __float2bfloat16(v);
        else if (EPI == 2) outB[o] = __float2bfloat16(gelu_f(v));
        else outF[o] += v;
      }
    }
  }
}

// ---------------- reference-token projection (tiny) ----------------
// writes refq bf16 [b][h][r][32] and refvT bf16 [b][h][d][r]
__global__ __launch_bounds__(256) void ref_kernel(
    const float* __restrict__ x_ref, const float* __restrict__ w, const float* __restrict__ bias,
    const float* __restrict__ diff_mu, const float* __restrict__ diff_ls,
    unsigned short* __restrict__ refq, unsigned short* __restrict__ refvT) {
  int blk = blockIdx.x;               // 0..199
  int b = blk / 100, r = blk % 100;
  __shared__ float xs[512];
  int tid = threadIdx.x;
  const float* xr = x_ref + (size_t)(b * 100 + r) * 512;
  xs[tid] = xr[tid];
  xs[tid + 256] = xr[tid + 256];
  __syncthreads();
#pragma unroll
  for (int cc = 0; cc < 4; cc++) {
    int c = cc * 256 + tid;
    const float* wr = w + (size_t)c * 512;
    float s = bias[c];
    for (int k = 0; k < 512; k++) s += xs[k] * wr[k];
    if (c < 512) {
      float v = diff_mu[c] + expf(diff_ls[c]) * s;
      int hh = c >> 5, d = c & 31;
      refq[((size_t)(b * 16 + hh) * 100 + r) * 32 + d] = f2bf(v);
    } else {
      int c2 = c - 512, hh = c2 >> 5, d = c2 & 31;
      refvT[(((size_t)b * 16 + hh) * 32 + d) * 100 + r] = f2bf(s);
    }
  }
}

// ---------------- ra = q @ ref_q^T ; MFMA ; block per (b_, head) ----------------
__global__ __launch_bounds__(256) void ra_kernel(
    const __hip_bfloat16* __restrict__ q, const unsigned short* __restrict__ refq,
    __hip_bfloat16* __restrict__ ra) {
  __shared__ __align__(16) unsigned short q_s[64 * 40];
  __shared__ __align__(16) unsigned short rq_s[112 * 40];
  int blk = blockIdx.x;               // 8192
  int b_ = blk >> 4, h = blk & 15;
  int rb = b_ >> 8, win = b_ & 255;
  int tid = threadIdx.x;
  int wave = tid >> 6, lane = tid & 63;
  int lrow = lane & 15, kq = lane >> 4;
  u32x4 z4 = {};
  const unsigned short* qb = (const unsigned short*)q + (size_t)b_ * 49 * 512 + h * 32;
  for (int i = tid; i < 196; i += 256) {
    int n = i >> 2, c = i & 3;
    *reinterpret_cast<u32x4*>(&q_s[n * 40 + c * 8]) =
        *reinterpret_cast<const u32x4*>(&qb[n * 512 + c * 8]);
  }
  for (int i = tid; i < 60; i += 256) {
    int n = 49 + (i >> 2), c = i & 3;
    *reinterpret_cast<u32x4*>(&q_s[n * 40 + c * 8]) = z4;
  }
  const unsigned short* rqg = refq + (size_t)(rb * 16 + h) * 3200;
  for (int i = tid; i < 400; i += 256) {
    int r = i >> 2, c = i & 3;
    *reinterpret_cast<u32x4*>(&rq_s[r * 40 + c * 8]) =
        *reinterpret_cast<const u32x4*>(&rqg[r * 32 + c * 8]);
  }
  for (int i = tid; i < 48; i += 256) {
    int r = 100 + (i >> 2), c = i & 3;
    *reinterpret_cast<u32x4*>(&rq_s[r * 40 + c * 8]) = z4;
  }
  __syncthreads();
  short8 a = *reinterpret_cast<const short8*>(&q_s[(wave * 16 + lrow) * 40 + kq * 8]);
  unsigned short* ra_base = (unsigned short*)ra + ((size_t)(rb * 16 + h) * 12544 + win * 49) * 100;
  f32x4 zero = {};
#pragma unroll
  for (int nt = 0; nt < 7; nt++) {
    short8 b = *reinterpret_cast<const short8*>(&rq_s[(nt * 16 + lrow) * 40 + kq * 8]);
    f32x4 c = __builtin_amdgcn_mfma_f32_16x16x32_bf16(a, b, zero, 0, 0, 0);
    int col = nt * 16 + lrow;
#pragma unroll
    for (int r = 0; r < 4; r++) {
      int n = wave * 16 + kq * 4 + r;
      if (n < 49 && col < 100) ra_base[n * 100 + col] = f2bf(c[r]);
    }
  }
}

// ---------------- implicit-GEMM MFMA conv v3: stride-24 LDS, role-based staging ----------------
// pixel stride 24 ushort = 48 B -> bank stride 12 -> 2-way aliasing (free).
__global__ __launch_bounds__(256) void conv_kernel(
    const __hip_bfloat16* __restrict__ ra_, const float* __restrict__ cw, const float* __restrict__ cb,
    __hip_bfloat16* __restrict__ u_, float* __restrict__ psum, float* __restrict__ psumsq) {
  __shared__ __align__(16) unsigned short in_s[10 * 103 * 24];   // 49,440 B
  __shared__ __align__(16) unsigned short w_s[16 * 160];         //  5,120 B
  __shared__ float sred_s[4][16], sred_s2[4][16];
  const unsigned short* ra = (const unsigned short*)ra_;
  unsigned short* u = (unsigned short*)u_;
  int yt = blockIdx.x, bb = blockIdx.y;
  int y0 = yt * 8;
  int tid = threadIdx.x;
  int wave = tid >> 6, lane = tid & 63;
  int lrow = lane & 15, kq = lane >> 4;
  // weights: w_s[co*160 + tap*16 + ci], zeros for k>=144
  for (int i = tid; i < 2560; i += 256) {
    int co = i / 160, k = i % 160;
    unsigned short v = 0;
    if (k < 144) {
      int ci = k & 15, p = k >> 4;
      v = f2bf(cw[(co * 16 + ci) * 9 + p]);
    }
    w_s[i] = v;
  }
  // halo columns xl in {0,101,102} are always zero (gx=-1,100,101 all OOB)
  for (int i = tid; i < 480; i += 256) {
    int ci = i & 15, rem = i >> 4;       // rem 0..29
    int yl = rem / 3, xs = rem % 3;
    int xl = (xs == 0) ? 0 : (100 + xs); // 0,101,102
    in_s[(yl * 103 + xl) * 24 + ci] = 0;
  }
  // interior: thread t<160 owns (ci, yl); 25 x u32x2 loads, scalar LDS scatter
  if (tid < 160) {
    int ci = tid / 10, yl = tid % 10;
    int gy = y0 - 1 + yl;
    bool rv = (gy >= 0 && gy < 12544);
    const unsigned short* rp = ra + (((size_t)bb * 16 + ci) * 12544 + (rv ? gy : 0)) * 100;
    unsigned short* lp = &in_s[(yl * 103 + 1) * 24 + ci];
#pragma unroll 5
    for (int c = 0; c < 25; c++) {
      u32x2 d = {0u, 0u};
      if (rv) d = *reinterpret_cast<const u32x2*>(&rp[c * 4]);
      lp[(c * 4 + 0) * 24] = (unsigned short)(d[0] & 0xffff);
      lp[(c * 4 + 1) * 24] = (unsigned short)(d[0] >> 16);
      lp[(c * 4 + 2) * 24] = (unsigned short)(d[1] & 0xffff);
      lp[(c * 4 + 3) * 24] = (unsigned short)(d[1] >> 16);
    }
  }
  __syncthreads();

  short8 afr[5];
#pragma unroll
  for (int c = 0; c < 5; c++)
    afr[c] = *reinterpret_cast<const short8*>(&w_s[lrow * 160 + c * 32 + kq * 8]);
  int kqh = kq >> 1, ci0 = (kq & 1) * 8;
  int kyA[5], kxA[5];
#pragma unroll
  for (int c = 0; c < 5; c++) {
    int p = c * 2 + kqh; if (p > 8) p = 0;   // zero-padded k-chunk: safe addr, A=0
    kyA[c] = p / 3; kxA[c] = p % 3;
  }
  float bias_r[4];
#pragma unroll
  for (int r = 0; r < 4; r++) bias_r[r] = cb[kq * 4 + r];
  float s_r[4] = {0.f, 0.f, 0.f, 0.f}, s2_r[4] = {0.f, 0.f, 0.f, 0.f};

#pragma unroll
  for (int rowi = 0; rowi < 2; rowi++) {
    int yl = wave + rowi * 4;
#pragma unroll
    for (int xg = 0; xg < 7; xg++) {
      int px = xg * 16 + lrow;
      int pxc = px < 100 ? px : 99;
      f32x4 acc = {};
#pragma unroll
      for (int c = 0; c < 5; c++) {
        short8 bfrag = *reinterpret_cast<const short8*>(
            &in_s[((yl + kyA[c]) * 103 + pxc + kxA[c]) * 24 + ci0]);
        acc = __builtin_amdgcn_mfma_f32_16x16x32_bf16(afr[c], bfrag, acc, 0, 0, 0);
      }
      int gy = y0 + yl;
      bool valid = px < 100;
#pragma unroll
      for (int r = 0; r < 4; r++) {
        float v = acc[r] + bias_r[r];
        if (valid) {
          u[(((size_t)bb * 16 + kq * 4 + r) * 12544 + gy) * 100 + px] = f2bf(v);
          s_r[r] += v; s2_r[r] += v * v;
        }
      }
    }
  }
#pragma unroll
  for (int o = 1; o < 16; o <<= 1)
#pragma unroll
    for (int r = 0; r < 4; r++) { s_r[r] += __shfl_xor(s_r[r], o); s2_r[r] += __shfl_xor(s2_r[r], o); }
  if (lrow == 0)
#pragma unroll
    for (int r = 0; r < 4; r++) { sred_s[wave][kq * 4 + r] = s_r[r]; sred_s2[wave][kq * 4 + r] = s2_r[r]; }
  __syncthreads();
  if (tid < 16) {
    float s  = sred_s[0][tid] + sred_s[1][tid] + sred_s[2][tid] + sred_s[3][tid];
    float s2 = sred_s2[0][tid] + sred_s2[1][tid] + sred_s2[2][tid] + sred_s2[3][tid];
    size_t pi = ((size_t)bb * 1568 + yt) * 16 + tid;
    psum[pi] = s; psumsq[pi] = s2;
  }
}

__global__ __launch_bounds__(256) void conv_stats_kernel(
    const float* __restrict__ psum, const float* __restrict__ psumsq, float* __restrict__ stats) {
  int g = blockIdx.x;                 // 32 = (b, co)
  int bb = g >> 4, co = g & 15;
  int tid = threadIdx.x;
  float s = 0.f, s2 = 0.f;
  for (int t = tid; t < 1568; t += 256) {
    size_t pi = ((size_t)bb * 1568 + t) * 16 + co;
    s += psum[pi];
    s2 += psumsq[pi];
  }
  block_reduce2(s, s2);
  if (tid == 0) {
    const float inv = 1.f / 1254400.f;
    float mu = s * inv;
    float var = s2 * inv - mu * mu;
    stats[g * 2] = mu;
    stats[g * 2 + 1] = rsqrtf(var + 1e-5f);
  }
}

__global__ __launch_bounds__(256) void conv_apply_kernel(
    __hip_bfloat16* __restrict__ ra, const __hip_bfloat16* __restrict__ u,
    const float* __restrict__ stats) {
  const int total8 = 5017600;         // 40,140,800 / 8
  int stride = gridDim.x * 256;
  for (int i = blockIdx.x * 256 + threadIdx.x; i < total8; i += stride) {
    int g = i / 156800;               // 1,254,400 / 8 per (b,ch) group
    float mu = stats[g * 2], rstd = stats[g * 2 + 1];
    ushort8 uu = reinterpret_cast<const ushort8*>(u)[i];
    ushort8 rr = reinterpret_cast<const ushort8*>(ra)[i];
    ushort8 oo;
#pragma unroll
    for (int j = 0; j < 8; j++) {
      float rv = bf2f(rr[j]) + gelu_f((bf2f(uu[j]) - mu) * rstd);
      oo[j] = f2bf(rv);
    }
    reinterpret_cast<ushort8*>(ra)[i] = oo;
  }
}

// ---------------- fused MFMA attention ----------------
__global__ __launch_bounds__(256) void attn_kernel(
    const __hip_bfloat16* __restrict__ ra_, const unsigned short* __restrict__ refvT,
    const __hip_bfloat16* __restrict__ kv_, const unsigned short* __restrict__ rpbT,
    const unsigned short* __restrict__ maskB, __hip_bfloat16* __restrict__ att_) {
  __shared__ __align__(16) char smem[36352];
  unsigned short* P1  = (unsigned short*)smem;              // stride 136
  unsigned short* rvT = (unsigned short*)(smem + 17408);    // stride 136
  unsigned short* P2  = (unsigned short*)smem;              // stride 72
  unsigned short* vT  = (unsigned short*)(smem + 9216);     // stride 72
  unsigned short* qn  = (unsigned short*)(smem + 26112);    // stride 40
  unsigned short* kb  = (unsigned short*)(smem + 31232);    // stride 40

  int blk = blockIdx.x;               // 8192
  int b_ = blk >> 4, h = blk & 15;
  int rb = b_ >> 8, win = b_ & 255;
  int tid = threadIdx.x;
  int wave = tid >> 6, lane = tid & 63;
  int lrow = lane & 15, kq = lane >> 4;
  const unsigned short* ra = (const unsigned short*)ra_;
  const unsigned short* kv = (const unsigned short*)kv_;
  unsigned short* att = (unsigned short*)att_;
  u32x2 zz = {};

  const unsigned short* rab = ra + ((size_t)(rb * 16 + h) * 12544 + win * 49) * 100;
  for (int i = tid; i < 1225; i += 256) {
    int n = i / 25, c = i % 25;
    *reinterpret_cast<u32x2*>(&P1[n * 136 + c * 4]) =
        *reinterpret_cast<const u32x2*>(&rab[n * 100 + c * 4]);
  }
  for (int i = tid; i < 343; i += 256) {
    int n = i / 7, c = i % 7;
    *reinterpret_cast<u32x2*>(&P1[n * 136 + 100 + c * 4]) = zz;
  }
  const unsigned short* rvtg = refvT + (size_t)(rb * 16 + h) * 3200;
  for (int i = tid; i < 800; i += 256) {
    int d = i / 25, c = i % 25;
    *reinterpret_cast<u32x2*>(&rvT[d * 136 + c * 4]) =
        *reinterpret_cast<const u32x2*>(&rvtg[d * 100 + c * 4]);
  }
  for (int i = tid; i < 224; i += 256) {
    int d = i / 7, c = i % 7;
    *reinterpret_cast<u32x2*>(&rvT[d * 136 + 100 + c * 4]) = zz;
  }
  const unsigned short* kvb = kv + (size_t)b_ * 49 * 1024;
  for (int i = tid; i < 196; i += 256) {
    int m = i >> 2, c = i & 3;
    *reinterpret_cast<u32x4*>(&kb[m * 40 + c * 8]) =
        *reinterpret_cast<const u32x4*>(&kvb[m * 1024 + h * 32 + c * 8]);
  }
  __syncthreads();

  if (tid < 196) {
    int n = tid >> 2, q = tid & 3;
    unsigned short* row = P1 + n * 136;
    float mx = -1e30f;
    for (int r = q * 25; r < q * 25 + 25; r++) mx = fmaxf(mx, bf2f(row[r]));
    mx = fmaxf(mx, __shfl_xor(mx, 1));
    mx = fmaxf(mx, __shfl_xor(mx, 2));
    float sm = 0.f;
    for (int r = q * 25; r < q * 25 + 25; r++) {
      float e = __expf(bf2f(row[r]) - mx); sm += e; row[r] = f2bf(e);
    }
    sm += __shfl_xor(sm, 1);
    sm += __shfl_xor(sm, 2);
    float inv = 1.f / sm;
    for (int r = q * 25; r < q * 25 + 25; r++) row[r] = f2bf(bf2f(row[r]) * inv);
  }
  __syncthreads();

  f32x4 acc1[2] = {};
#pragma unroll
  for (int ks = 0; ks < 4; ks++) {
    short8 a = *reinterpret_cast<const short8*>(&P1[(wave * 16 + lrow) * 136 + ks * 32 + kq * 8]);
#pragma unroll
    for (int dt = 0; dt < 2; dt++) {
      short8 b = *reinterpret_cast<const short8*>(&rvT[(dt * 16 + lrow) * 136 + ks * 32 + kq * 8]);
      acc1[dt] = __builtin_amdgcn_mfma_f32_16x16x32_bf16(a, b, acc1[dt], 0, 0, 0);
    }
  }
#pragma unroll
  for (int dt = 0; dt < 2; dt++)
#pragma unroll
    for (int r = 0; r < 4; r++) {
      int n = wave * 16 + kq * 4 + r;
      qn[n * 40 + dt * 16 + lrow] = f2bf(acc1[dt][r] * 0.17677669529663688f);
    }
  __syncthreads();

  for (int i = tid; i < 196; i += 256) {
    int m = i >> 2, dg = (i & 3) * 8;
    ushort8 vv = *reinterpret_cast<const ushort8*>(&kvb[m * 1024 + 512 + h * 32 + dg]);
#pragma unroll
    for (int j = 0; j < 8; j++) vT[(dg + j) * 72 + m] = vv[j];
  }
  for (int i = tid; i < 480; i += 256) vT[(i / 15) * 72 + 49 + i % 15] = 0;

  const unsigned short* bt = maskB + (size_t)win * 2744;
  const unsigned short* rt = rpbT + (size_t)h * 2744;
  short8 aq = *reinterpret_cast<const short8*>(&qn[(wave * 16 + lrow) * 40 + kq * 8]);
  f32x4 zero = {};
  float val[4][4];
#pragma unroll
  for (int mt = 0; mt < 4; mt++) {
    short8 bk = *reinterpret_cast<const short8*>(&kb[(mt * 16 + lrow) * 40 + kq * 8]);
    f32x4 lg = __builtin_amdgcn_mfma_f32_16x16x32_bf16(aq, bk, zero, 0, 0, 0);
    int m = mt * 16 + lrow;
#pragma unroll
    for (int r = 0; r < 4; r++) {
      int n = wave * 16 + kq * 4 + r;
      float v;
      if (m < 49 && n < 49)
        v = lg[r] + bf2f(rt[n * 56 + m]) + bf2f(bt[n * 56 + m]);
      else v = -1e30f;
      val[mt][r] = v;
    }
  }
#pragma unroll
  for (int r = 0; r < 4; r++) {
    float mx = -1e30f;
#pragma unroll
    for (int mt = 0; mt < 4; mt++) mx = fmaxf(mx, val[mt][r]);
    mx = fmaxf(mx, __shfl_xor(mx, 1)); mx = fmaxf(mx, __shfl_xor(mx, 2));
    mx = fmaxf(mx, __shfl_xor(mx, 4)); mx = fmaxf(mx, __shfl_xor(mx, 8));
    float sm = 0.f, e[4];
#pragma unroll
    for (int mt = 0; mt < 4; mt++) { e[mt] = __expf(val[mt][r] - mx); sm += e[mt]; }
    sm += __shfl_xor(sm, 1); sm += __shfl_xor(sm, 2);
    sm += __shfl_xor(sm, 4); sm += __shfl_xor(sm, 8);
    float inv = 1.f / sm;
    int n = wave * 16 + kq * 4 + r;
#pragma unroll
    for (int mt = 0; mt < 4; mt++) P2[n * 72 + mt * 16 + lrow] = f2bf(e[mt] * inv);
  }
  __syncthreads();

  f32x4 acc2[2] = {};
#pragma unroll
  for (int ks = 0; ks < 2; ks++) {
    short8 ap = *reinterpret_cast<const short8*>(&P2[(wave * 16 + lrow) * 72 + ks * 32 + kq * 8]);
#pragma unroll
    for (int dt = 0; dt < 2; dt++) {
      short8 bv = *reinterpret_cast<const short8*>(&vT[(dt * 16 + lrow) * 72 + ks * 32 + kq * 8]);
      acc2[dt] = __builtin_amdgcn_mfma_f32_16x16x32_bf16(ap, bv, acc2[dt], 0, 0, 0);
    }
  }
  unsigned short* ab = att + (size_t)b_ * 49 * 512 + h * 32;
#pragma unroll
  for (int dt = 0; dt < 2; dt++)
#pragma unroll
    for (int r = 0; r < 4; r++) {
      int n = wave * 16 + kq * 4 + r;
      if (n < 49) ab[n * 512 + dt * 16 + lrow] = f2bf(acc2[dt][r]);
    }
}

// ---------------- window-reverse gather + residual + LN2 ----------------
__global__ __launch_bounds__(256) void resid_ln2_kernel(
    const float* __restrict__ x, const __hip_bfloat16* __restrict__ proj_out,
    const float* __restrict__ w2, const float* __restrict__ b2,
    float* __restrict__ out, __hip_bfloat16* __restrict__ hout) {
  int blk = blockIdx.x;               // b*12544 + l
  int bb = blk / 12544, l = blk % 12544;
  int hh = l / 112, ww = l % 112;
  int hs = (hh + 109) % 112, wsx = (ww + 109) % 112;   // (h-3) mod 112
  int t = (bb * 256 + (hs / 7) * 16 + (wsx / 7)) * 49 + (hs % 7) * 7 + (wsx % 7);
  const float* xr = x + (size_t)blk * 512;
  const __hip_bfloat16* pr = proj_out + (size_t)t * 512;
  int tid = threadIdx.x;
  float v0 = xr[tid] + __bfloat162float(pr[tid]);
  float v1 = xr[tid + 256] + __bfloat162float(pr[tid + 256]);
  float* orow = out + (size_t)blk * 512;
  orow[tid] = v0;
  orow[tid + 256] = v1;
  float s = v0 + v1, s2 = v0 * v0 + v1 * v1;
  block_reduce2(s, s2);
  float mu = s * (1.f / 512.f);
  float rstd = rsqrtf(s2 * (1.f / 512.f) - mu * mu + 1e-5f);
  __hip_bfloat16* hrow = hout + (size_t)blk * 512;
  hrow[tid]       = __float2bfloat16((v0 - mu) * rstd * w2[tid] + b2[tid]);
  hrow[tid + 256] = __float2bfloat16((v1 - mu) * rstd * w2[tid + 256] + b2[tid + 256]);
}

// =======================================================================
extern "C" void kernel_launch(void* const* d_in, const int* in_sizes, int n_in,
                              void* d_out, int out_size, void* d_ws, size_t ws_size,
                              hipStream_t stream) {
  const float* x       = (const float*)d_in[0];
  const float* x_ref   = (const float*)d_in[1];
  const float* mask    = (const float*)d_in[2];
  const float* n1w     = (const float*)d_in[3];
  const float* n1b     = (const float*)d_in[4];
  const float* qkv_w   = (const float*)d_in[5];
  const float* qkv_b   = (const float*)d_in[6];
  const float* diff_mu = (const float*)d_in[7];
  const float* diff_ls = (const float*)d_in[8];
  const float* rpb     = (const float*)d_in[9];
  const float* ref_w   = (const float*)d_in[10];
  const float* ref_b   = (const float*)d_in[11];
  const float* conv_w  = (const float*)d_in[12];
  const float* conv_b  = (const float*)d_in[13];
  const float* proj_w  = (const float*)d_in[14];
  const float* proj_b  = (const float*)d_in[15];
  const float* n2w     = (const float*)d_in[16];
  const float* n2b     = (const float*)d_in[17];
  const float* fc1_w   = (const float*)d_in[18];
  const float* fc1_b   = (const float*)d_in[19];
  const float* fc2_w   = (const float*)d_in[20];
  const float* fc2_b   = (const float*)d_in[21];
  float* out = (float*)d_out;

  char* ws = (char*)d_ws;
  size_t off = 0;
  auto alloc = [&](size_t bytes) -> char* {
    char* p = ws + off;
    off += (bytes + 255) & ~(size_t)255;
    return p;
  };
  // ---- persistent small buffers ----
  __hip_bfloat16* wq_bf = (__hip_bfloat16*)alloc(1536ULL * 512 * 2);   // q rows 0..511, kv rows 512..1535
  __hip_bfloat16* wp_bf = (__hip_bfloat16*)alloc(512ULL * 512 * 2);
  __hip_bfloat16* w1_bf = (__hip_bfloat16*)alloc(2048ULL * 512 * 2);
  __hip_bfloat16* w2_bf = (__hip_bfloat16*)alloc(512ULL * 2048 * 2);
  unsigned short* refq  = (unsigned short*)alloc(2ULL * 16 * 100 * 32 * 2);
  unsigned short* refvT = (unsigned short*)alloc(2ULL * 16 * 32 * 100 * 2);
  unsigned short* maskB = (unsigned short*)alloc(256ULL * 49 * 56 * 2);
  unsigned short* rpbT  = (unsigned short*)alloc(16ULL * 49 * 56 * 2);
  float* psum  = (float*)alloc(2ULL * 1568 * 16 * 4);
  float* psumq = (float*)alloc(2ULL * 1568 * 16 * 4);
  float* stats = (float*)alloc(64 * 4);
  // ---- aliased regions ----
  char* regX  = alloc(25088ULL * 512 * 2);      // xw_bf -> att_bf            (25.7 MB)
  char* regQ  = alloc(25088ULL * 512 * 2);      // q_bf  -> h_bf              (25.7 MB)
  char* regRA = alloc(2ULL * 16 * 12544 * 100 * 2);  // ra    -> hg (per-chunk) (80.3 MB)
  char* regU  = alloc(2ULL * 16 * 12544 * 100 * 2);  // u -> kv_bf + proj_bf    (80.3 MB)

  __hip_bfloat16* xw_bf   = (__hip_bfloat16*)regX;
  __hip_bfloat16* att_bf  = (__hip_bfloat16*)regX;                      // after kv GEMM
  __hip_bfloat16* q_bf    = (__hip_bfloat16*)regQ;
  __hip_bfloat16* h_bf    = (__hip_bfloat16*)regQ;                      // after ra_kernel
  __hip_bfloat16* ra      = (__hip_bfloat16*)regRA;
  __hip_bfloat16* hg      = (__hip_bfloat16*)regRA;                     // after attn (51.4MB/chunk)
  __hip_bfloat16* u       = (__hip_bfloat16*)regU;
  __hip_bfloat16* kv_bf   = (__hip_bfloat16*)regU;                      // after conv rounds (51.4MB)
  __hip_bfloat16* proj_bf = (__hip_bfloat16*)(regU + 51380224);         // after attn (25.7MB)

  // 1. weights -> bf16 ; bias tables
  f2b_kernel<<<3072, 256, 0, stream>>>(qkv_w, wq_bf, 786432);
  f2b_kernel<<<1024, 256, 0, stream>>>(proj_w, wp_bf, 262144);
  f2b_kernel<<<4096, 256, 0, stream>>>(fc1_w, w1_bf, 1048576);
  f2b_kernel<<<4096, 256, 0, stream>>>(fc2_w, w2_bf, 1048576);
  maskb_kernel<<<2744, 256, 0, stream>>>(mask, maskB);
  rpbt_kernel<<<172, 256, 0, stream>>>(rpb, rpbT);
  // 2. LN1 + shift + window partition
  ln1_window_kernel<<<25088, 256, 0, stream>>>(x, n1w, n1b, xw_bf);
  // 3. q GEMM (bias -> bf16)
  gemm_bt<1><<<dim3(196, 4), 256, 0, stream>>>(xw_bf, wq_bf, qkv_b, nullptr, q_bf,
                                               25088, 512, 512);
  // 4. reference tokens
  ref_kernel<<<200, 256, 0, stream>>>(x_ref, ref_w, ref_b, diff_mu, diff_ls, refq, refvT);
  // 5. ra = q @ ref_q^T (MFMA)
  ra_kernel<<<8192, 256, 0, stream>>>(q_bf, refq, ra);
  // 6. conv diffusion x3 (MFMA implicit GEMM)
  for (int rd = 0; rd < 3; rd++) {
    conv_kernel<<<dim3(1568, 2), 256, 0, stream>>>(ra, conv_w, conv_b, u, psum, psumq);
    conv_stats_kernel<<<32, 256, 0, stream>>>(psum, psumq, stats);
    conv_apply_kernel<<<4096, 256, 0, stream>>>(ra, u, stats);
  }
  // 7. kv GEMM into dead u region (xw still live as A input)
  gemm_bt<1><<<dim3(196, 8), 256, 0, stream>>>(xw_bf, wq_bf + 512 * 512, qkv_b + 512,
                                               nullptr, kv_bf, 25088, 1024, 512);
  // 8. fused MFMA attention (xw dead -> att_bf)
  attn_kernel<<<8192, 256, 0, stream>>>(ra, refvT, kv_bf, rpbT, maskB, att_bf);
  // 9. proj GEMM (bias -> bf16, into regU tail)
  gemm_bt<1><<<dim3(196, 4), 256, 0, stream>>>(att_bf, wp_bf, proj_b, nullptr, proj_bf,
                                               25088, 512, 512);
  // 10. window reverse + residual + LN2 (h_bf into dead q region)
  resid_ln2_kernel<<<25088, 256, 0, stream>>>(x, proj_bf, n2w, n2b, out, h_bf);
  // 11. MLP in two M-chunks; hg reuses dead ra region
  for (int ch = 0; ch < 2; ch++) {
    const __hip_bfloat16* hA = h_bf + (size_t)ch * 12544 * 512;
    gemm_bt<2><<<dim3(98, 16), 256, 0, stream>>>(hA, w1_bf, fc1_b, nullptr, hg,
                                                 12544, 2048, 512);
    gemm_bt<3><<<dim3(98, 4), 256, 0, stream>>>(hg, w2_bf, fc2_b,
                                                out + (size_t)ch * 12544 * 512, nullptr,
                                                12544, 512, 2048);
  }
}

// Round 8
// 1187.219 us; speedup vs baseline: 1.9095x; 1.0651x over previous
//
#include <hip/hip_runtime.h>
#include <hip/hip_bf16.h>

typedef __attribute__((ext_vector_type(8))) short short8;        // 8 bf16 = 4 VGPRs
typedef __attribute__((ext_vector_type(8))) unsigned short ushort8;
typedef __attribute__((ext_vector_type(4))) float f32x4;
typedef __attribute__((ext_vector_type(4))) unsigned int u32x4;
typedef __attribute__((ext_vector_type(2))) unsigned int u32x2;

#define DEV __device__ __forceinline__

DEV float gelu_f(float x) { return 0.5f * x * (1.f + erff(x * 0.70710678118654752440f)); }

DEV float bf2f(unsigned short s) {
  unsigned int t = ((unsigned int)s) << 16;
  float f; __builtin_memcpy(&f, &t, 4); return f;
}
DEV unsigned short f2bf(float f) {
  __hip_bfloat16 b = __float2bfloat16(f);
  unsigned short s; __builtin_memcpy(&s, &b, 2); return s;
}

// async global->LDS 16B/lane (dest = wave-uniform base + lane*16)
DEV void async_copy16(void* lds, const void* g) {
  __builtin_amdgcn_global_load_lds(
      (const __attribute__((address_space(1))) unsigned int*)g,
      (__attribute__((address_space(3))) unsigned int*)lds, 16, 0, 0);
}

// block-wide (256 thr) sum of two values; every thread gets the totals
DEV void block_reduce2(float& s, float& s2) {
  __shared__ float red[8];
  int tid = threadIdx.x;
#pragma unroll
  for (int o = 32; o > 0; o >>= 1) { s += __shfl_down(s, o); s2 += __shfl_down(s2, o); }
  if ((tid & 63) == 0) { red[tid >> 6] = s; red[4 + (tid >> 6)] = s2; }
  __syncthreads();
  s  = red[0] + red[1] + red[2] + red[3];
  s2 = red[4] + red[5] + red[6] + red[7];
}

// ---------------- weight fp32 -> bf16 ----------------
__global__ __launch_bounds__(256) void f2b_kernel(const float* __restrict__ in,
                                                  __hip_bfloat16* __restrict__ o, int n) {
  int i = blockIdx.x * 256 + threadIdx.x;
  if (i < n) o[i] = __float2bfloat16(in[i]);
}

// ---------------- mask -> bf16 padded [win][49][56] ----------------
__global__ __launch_bounds__(256) void maskb_kernel(const float* __restrict__ mask,
                                                    unsigned short* __restrict__ maskB) {
  int i = blockIdx.x * 256 + threadIdx.x;          // 256*49*56 = 702464 exactly
  int m = i % 56, rest = i / 56;
  int n = rest % 49, win = rest / 49;
  unsigned short v = 0;
  if (m < 49) v = f2bf(mask[((size_t)win * 49 + n) * 49 + m]);
  maskB[i] = v;
}

// ---------------- rpb -> bf16 padded [h][49][56] ----------------
__global__ __launch_bounds__(256) void rpbt_kernel(const float* __restrict__ rpb,
                                                   unsigned short* __restrict__ rpbT) {
  int i = blockIdx.x * 256 + threadIdx.x;          // 16*49*56 = 43904
  if (i >= 43904) return;
  int m = i % 56, rest = i / 56;
  int n = rest % 49, h = rest / 49;
  unsigned short v = 0;
  if (m < 49) {
    int rp = (n / 7 - m / 7 + 6) * 13 + (n % 7 - m % 7 + 6);
    v = f2bf(rpb[rp * 16 + h]);
  }
  rpbT[i] = v;
}

// ---------------- LN1 + cyclic shift + window partition -> bf16 ----------------
__global__ __launch_bounds__(256) void ln1_window_kernel(
    const float* __restrict__ x, const float* __restrict__ w, const float* __restrict__ b,
    __hip_bfloat16* __restrict__ xw) {
  int t = blockIdx.x;                 // 0..25087
  int b_ = t / 49, n = t % 49;
  int bb = b_ >> 8, win = b_ & 255;
  int wi = win >> 4, wj = win & 15;
  int ii = n / 7, jj = n % 7;
  int sh = (wi * 7 + ii + 3) % 112;
  int sw = (wj * 7 + jj + 3) % 112;
  const float* row = x + ((size_t)bb * 12544 + sh * 112 + sw) * 512;
  int tid = threadIdx.x;
  float v0 = row[tid], v1 = row[tid + 256];
  float s = v0 + v1, s2 = v0 * v0 + v1 * v1;
  block_reduce2(s, s2);
  float mu = s * (1.f / 512.f);
  float rstd = rsqrtf(s2 * (1.f / 512.f) - mu * mu + 1e-5f);
  __hip_bfloat16* orow = xw + (size_t)t * 512;
  orow[tid]       = __float2bfloat16((v0 - mu) * rstd * w[tid] + b[tid]);
  orow[tid + 256] = __float2bfloat16((v1 - mu) * rstd * w[tid + 256] + b[tid + 256]);
}

// ---------------- bf16 MFMA GEMM (global_load_lds staging): C = A @ B^T + bias ----------------
// EPI: 1 = bias -> bf16 store ; 2 = bias+gelu -> bf16 ; 3 = bias -> f32 +=
template <int EPI>
__global__ __launch_bounds__(256) void gemm_bt(
    const __hip_bfloat16* __restrict__ A, const __hip_bfloat16* __restrict__ B,
    const float* __restrict__ bias, float* __restrict__ outF,
    __hip_bfloat16* __restrict__ outB, int M, int N, int K) {
  __shared__ __align__(16) __hip_bfloat16 As[128 * 64];   // unpadded (global_load_lds layout)
  __shared__ __align__(16) __hip_bfloat16 Bs[128 * 64];
  int m0 = blockIdx.x * 128, n0 = blockIdx.y * 128;
  int tid = threadIdx.x;
  int wave = tid >> 6, lane = tid & 63;
  int wm = (wave & 1) * 64, wn = (wave >> 1) * 64;
  int lrow = lane & 15, kq = lane >> 4;
  int srow = lane >> 3, scol = (lane & 7) * 8;     // staging: 8 rows x 64 cols per wave-inst
  f32x4 acc[4][4] = {};
  for (int k0 = 0; k0 < K; k0 += 64) {
    int rb = wave * 32;
#pragma unroll
    for (int i = 0; i < 4; i++) {
      int row = rb + i * 8 + srow;
      async_copy16(&As[(rb + i * 8) * 64], &A[(size_t)(m0 + row) * K + k0 + scol]);
      async_copy16(&Bs[(rb + i * 8) * 64], &B[(size_t)(n0 + row) * K + k0 + scol]);
    }
    __syncthreads();
#pragma unroll
    for (int ks = 0; ks < 2; ks++) {
      short8 af[4], bf[4];
#pragma unroll
      for (int t = 0; t < 4; t++) {
        af[t] = *reinterpret_cast<const short8*>(&As[(wm + t * 16 + lrow) * 64 + ks * 32 + kq * 8]);
        bf[t] = *reinterpret_cast<const short8*>(&Bs[(wn + t * 16 + lrow) * 64 + ks * 32 + kq * 8]);
      }
#pragma unroll
      for (int tm = 0; tm < 4; tm++)
#pragma unroll
        for (int tn = 0; tn < 4; tn++)
          acc[tm][tn] = __builtin_amdgcn_mfma_f32_16x16x32_bf16(af[tm], bf[tn], acc[tm][tn], 0, 0, 0);
    }
    __syncthreads();
  }
  // D: row=(lane>>4)*4+r, col=lane&15 (verified gfx950 C/D layout)
#pragma unroll
  for (int tm = 0; tm < 4; tm++) {
#pragma unroll
    for (int tn = 0; tn < 4; tn++) {
      int col = n0 + wn + tn * 16 + lrow;
      float bv = bias[col];
#pragma unroll
      for (int r = 0; r < 4; r++) {
        int row = m0 + wm + tm * 16 + kq * 4 + r;
        float v = acc[tm][tn][r] + bv;
        size_t o = (size_t)row * N + col;
        if (EPI == 1) outB[o] = __float2bfloat16(v);
        else if (EPI == 2) outB[o] = __float2bfloat16(gelu_f(v));
        else outF[o] += v;
      }
    }
  }
}

// ---------------- reference-token projection (tiny) ----------------
// writes refq bf16 [b][h][r][32] and refvT bf16 [b][h][d][r]
__global__ __launch_bounds__(256) void ref_kernel(
    const float* __restrict__ x_ref, const float* __restrict__ w, const float* __restrict__ bias,
    const float* __restrict__ diff_mu, const float* __restrict__ diff_ls,
    unsigned short* __restrict__ refq, unsigned short* __restrict__ refvT) {
  int blk = blockIdx.x;               // 0..199
  int b = blk / 100, r = blk % 100;
  __shared__ float xs[512];
  int tid = threadIdx.x;
  const float* xr = x_ref + (size_t)(b * 100 + r) * 512;
  xs[tid] = xr[tid];
  xs[tid + 256] = xr[tid + 256];
  __syncthreads();
#pragma unroll
  for (int cc = 0; cc < 4; cc++) {
    int c = cc * 256 + tid;
    const float* wr = w + (size_t)c * 512;
    float s = bias[c];
    for (int k = 0; k < 512; k++) s += xs[k] * wr[k];
    if (c < 512) {
      float v = diff_mu[c] + expf(diff_ls[c]) * s;
      int hh = c >> 5, d = c & 31;
      refq[((size_t)(b * 16 + hh) * 100 + r) * 32 + d] = f2bf(v);
    } else {
      int c2 = c - 512, hh = c2 >> 5, d = c2 & 31;
      refvT[(((size_t)b * 16 + hh) * 32 + d) * 100 + r] = f2bf(s);
    }
  }
}

// ---------------- ra = q @ ref_q^T ; MFMA ; block per (b_, head) ----------------
__global__ __launch_bounds__(256) void ra_kernel(
    const __hip_bfloat16* __restrict__ q, const unsigned short* __restrict__ refq,
    __hip_bfloat16* __restrict__ ra) {
  __shared__ __align__(16) unsigned short q_s[64 * 40];
  __shared__ __align__(16) unsigned short rq_s[112 * 40];
  int blk = blockIdx.x;               // 8192
  int b_ = blk >> 4, h = blk & 15;
  int rb = b_ >> 8, win = b_ & 255;
  int tid = threadIdx.x;
  int wave = tid >> 6, lane = tid & 63;
  int lrow = lane & 15, kq = lane >> 4;
  u32x4 z4 = {};
  const unsigned short* qb = (const unsigned short*)q + (size_t)b_ * 49 * 512 + h * 32;
  for (int i = tid; i < 196; i += 256) {
    int n = i >> 2, c = i & 3;
    *reinterpret_cast<u32x4*>(&q_s[n * 40 + c * 8]) =
        *reinterpret_cast<const u32x4*>(&qb[n * 512 + c * 8]);
  }
  for (int i = tid; i < 60; i += 256) {
    int n = 49 + (i >> 2), c = i & 3;
    *reinterpret_cast<u32x4*>(&q_s[n * 40 + c * 8]) = z4;
  }
  const unsigned short* rqg = refq + (size_t)(rb * 16 + h) * 3200;
  for (int i = tid; i < 400; i += 256) {
    int r = i >> 2, c = i & 3;
    *reinterpret_cast<u32x4*>(&rq_s[r * 40 + c * 8]) =
        *reinterpret_cast<const u32x4*>(&rqg[r * 32 + c * 8]);
  }
  for (int i = tid; i < 48; i += 256) {
    int r = 100 + (i >> 2), c = i & 3;
    *reinterpret_cast<u32x4*>(&rq_s[r * 40 + c * 8]) = z4;
  }
  __syncthreads();
  short8 a = *reinterpret_cast<const short8*>(&q_s[(wave * 16 + lrow) * 40 + kq * 8]);
  unsigned short* ra_base = (unsigned short*)ra + ((size_t)(rb * 16 + h) * 12544 + win * 49) * 100;
  f32x4 zero = {};
#pragma unroll
  for (int nt = 0; nt < 7; nt++) {
    short8 b = *reinterpret_cast<const short8*>(&rq_s[(nt * 16 + lrow) * 40 + kq * 8]);
    f32x4 c = __builtin_amdgcn_mfma_f32_16x16x32_bf16(a, b, zero, 0, 0, 0);
    int col = nt * 16 + lrow;
#pragma unroll
    for (int r = 0; r < 4; r++) {
      int n = wave * 16 + kq * 4 + r;
      if (n < 49 && col < 100) ra_base[n * 100 + col] = f2bf(c[r]);
    }
  }
}

// ---------------- implicit-GEMM MFMA conv v4: 4-row tiles, 4 blocks/CU ----------------
// pixel stride 24 ushort = 48 B -> bank stride 12 -> 2-way aliasing (free).
__global__ __launch_bounds__(256) void conv_kernel(
    const __hip_bfloat16* __restrict__ ra_, const float* __restrict__ cw, const float* __restrict__ cb,
    __hip_bfloat16* __restrict__ u_, float* __restrict__ psum, float* __restrict__ psumsq) {
  __shared__ __align__(16) unsigned short in_s[6 * 103 * 24];    // 29,664 B
  __shared__ __align__(16) unsigned short w_s[16 * 160];         //  5,120 B
  __shared__ float sred_s[4][16], sred_s2[4][16];
  const unsigned short* ra = (const unsigned short*)ra_;
  unsigned short* u = (unsigned short*)u_;
  int yt = blockIdx.x, bb = blockIdx.y;
  int y0 = yt * 4;
  int tid = threadIdx.x;
  int wave = tid >> 6, lane = tid & 63;
  int lrow = lane & 15, kq = lane >> 4;
  // weights: w_s[co*160 + tap*16 + ci], zeros for k>=144
  for (int i = tid; i < 2560; i += 256) {
    int co = i / 160, k = i % 160;
    unsigned short v = 0;
    if (k < 144) {
      int ci = k & 15, p = k >> 4;
      v = f2bf(cw[(co * 16 + ci) * 9 + p]);
    }
    w_s[i] = v;
  }
  // halo columns xl in {0,101,102} are always zero: 6 yl x 3 x 16 ci
  for (int i = tid; i < 288; i += 256) {
    int ci = i & 15, rem = i >> 4;       // rem 0..17
    int yl = rem / 3, xs = rem % 3;
    int xl = (xs == 0) ? 0 : (100 + xs);
    in_s[(yl * 103 + xl) * 24 + ci] = 0;
  }
  // interior: 192 threads; thread = (ci, yl, x-parity); ~12 independent u32x2 loads each
  if (tid < 192) {
    int unit = tid >> 1, par = tid & 1;
    int ci = unit / 6, yl = unit % 6;
    int gy = y0 - 1 + yl;
    bool rv = (gy >= 0 && gy < 12544);
    const unsigned short* rp = ra + (((size_t)bb * 16 + ci) * 12544 + (rv ? gy : 0)) * 100;
    unsigned short* lp = &in_s[(yl * 103 + 1) * 24 + ci];
#pragma unroll 4
    for (int c = par; c < 25; c += 2) {
      u32x2 d = {0u, 0u};
      if (rv) d = *reinterpret_cast<const u32x2*>(&rp[c * 4]);
      lp[(c * 4 + 0) * 24] = (unsigned short)(d[0] & 0xffff);
      lp[(c * 4 + 1) * 24] = (unsigned short)(d[0] >> 16);
      lp[(c * 4 + 2) * 24] = (unsigned short)(d[1] & 0xffff);
      lp[(c * 4 + 3) * 24] = (unsigned short)(d[1] >> 16);
    }
  }
  __syncthreads();

  short8 afr[5];
#pragma unroll
  for (int c = 0; c < 5; c++)
    afr[c] = *reinterpret_cast<const short8*>(&w_s[lrow * 160 + c * 32 + kq * 8]);
  int kqh = kq >> 1, ci0 = (kq & 1) * 8;
  int kyA[5], kxA[5];
#pragma unroll
  for (int c = 0; c < 5; c++) {
    int p = c * 2 + kqh; if (p > 8) p = 0;   // zero-padded k-chunk: safe addr, A=0
    kyA[c] = p / 3; kxA[c] = p % 3;
  }
  float bias_r[4];
#pragma unroll
  for (int r = 0; r < 4; r++) bias_r[r] = cb[kq * 4 + r];
  float s_r[4] = {0.f, 0.f, 0.f, 0.f}, s2_r[4] = {0.f, 0.f, 0.f, 0.f};

  int yl = wave;                        // output row 0..3
  int gy = y0 + yl;
#pragma unroll
  for (int xg = 0; xg < 7; xg++) {
    int px = xg * 16 + lrow;
    int pxc = px < 100 ? px : 99;
    f32x4 acc = {};
#pragma unroll
    for (int c = 0; c < 5; c++) {
      short8 bfrag = *reinterpret_cast<const short8*>(
          &in_s[((yl + kyA[c]) * 103 + pxc + kxA[c]) * 24 + ci0]);
      acc = __builtin_amdgcn_mfma_f32_16x16x32_bf16(afr[c], bfrag, acc, 0, 0, 0);
    }
    bool valid = px < 100;
#pragma unroll
    for (int r = 0; r < 4; r++) {
      float v = acc[r] + bias_r[r];
      if (valid) {
        u[(((size_t)bb * 16 + kq * 4 + r) * 12544 + gy) * 100 + px] = f2bf(v);
        s_r[r] += v; s2_r[r] += v * v;
      }
    }
  }
#pragma unroll
  for (int o = 1; o < 16; o <<= 1)
#pragma unroll
    for (int r = 0; r < 4; r++) { s_r[r] += __shfl_xor(s_r[r], o); s2_r[r] += __shfl_xor(s2_r[r], o); }
  if (lrow == 0)
#pragma unroll
    for (int r = 0; r < 4; r++) { sred_s[wave][kq * 4 + r] = s_r[r]; sred_s2[wave][kq * 4 + r] = s2_r[r]; }
  __syncthreads();
  if (tid < 16) {
    float s  = sred_s[0][tid] + sred_s[1][tid] + sred_s[2][tid] + sred_s[3][tid];
    float s2 = sred_s2[0][tid] + sred_s2[1][tid] + sred_s2[2][tid] + sred_s2[3][tid];
    size_t pi = ((size_t)bb * 3136 + yt) * 16 + tid;
    psum[pi] = s; psumsq[pi] = s2;
  }
}

__global__ __launch_bounds__(256) void conv_stats_kernel(
    const float* __restrict__ psum, const float* __restrict__ psumsq, float* __restrict__ stats) {
  int g = blockIdx.x;                 // 32 = (b, co)
  int bb = g >> 4, co = g & 15;
  int tid = threadIdx.x;
  float s = 0.f, s2 = 0.f;
  for (int t = tid; t < 3136; t += 256) {
    size_t pi = ((size_t)bb * 3136 + t) * 16 + co;
    s += psum[pi];
    s2 += psumsq[pi];
  }
  block_reduce2(s, s2);
  if (tid == 0) {
    const float inv = 1.f / 1254400.f;
    float mu = s * inv;
    float var = s2 * inv - mu * mu;
    stats[g * 2] = mu;
    stats[g * 2 + 1] = rsqrtf(var + 1e-5f);
  }
}

__global__ __launch_bounds__(256) void conv_apply_kernel(
    __hip_bfloat16* __restrict__ ra, const __hip_bfloat16* __restrict__ u,
    const float* __restrict__ stats) {
  const int total8 = 5017600;         // 40,140,800 / 8
  int stride = gridDim.x * 256;
  for (int i = blockIdx.x * 256 + threadIdx.x; i < total8; i += stride) {
    int g = i / 156800;               // 1,254,400 / 8 per (b,ch) group
    float mu = stats[g * 2], rstd = stats[g * 2 + 1];
    ushort8 uu = reinterpret_cast<const ushort8*>(u)[i];
    ushort8 rr = reinterpret_cast<const ushort8*>(ra)[i];
    ushort8 oo;
#pragma unroll
    for (int j = 0; j < 8; j++) {
      float rv = bf2f(rr[j]) + gelu_f((bf2f(uu[j]) - mu) * rstd);
      oo[j] = f2bf(rv);
    }
    reinterpret_cast<ushort8*>(ra)[i] = oo;
  }
}

// ---------------- fused MFMA attention ----------------
__global__ __launch_bounds__(256) void attn_kernel(
    const __hip_bfloat16* __restrict__ ra_, const unsigned short* __restrict__ refvT,
    const __hip_bfloat16* __restrict__ kv_, const unsigned short* __restrict__ rpbT,
    const unsigned short* __restrict__ maskB, __hip_bfloat16* __restrict__ att_) {
  __shared__ __align__(16) char smem[36352];
  unsigned short* P1  = (unsigned short*)smem;              // stride 136
  unsigned short* rvT = (unsigned short*)(smem + 17408);    // stride 136
  unsigned short* P2  = (unsigned short*)smem;              // stride 72
  unsigned short* vT  = (unsigned short*)(smem + 9216);     // stride 72
  unsigned short* qn  = (unsigned short*)(smem + 26112);    // stride 40
  unsigned short* kb  = (unsigned short*)(smem + 31232);    // stride 40

  int blk = blockIdx.x;               // 8192
  int b_ = blk >> 4, h = blk & 15;
  int rb = b_ >> 8, win = b_ & 255;
  int tid = threadIdx.x;
  int wave = tid >> 6, lane = tid & 63;
  int lrow = lane & 15, kq = lane >> 4;
  const unsigned short* ra = (const unsigned short*)ra_;
  const unsigned short* kv = (const unsigned short*)kv_;
  unsigned short* att = (unsigned short*)att_;
  u32x2 zz = {};

  const unsigned short* rab = ra + ((size_t)(rb * 16 + h) * 12544 + win * 49) * 100;
  for (int i = tid; i < 1225; i += 256) {
    int n = i / 25, c = i % 25;
    *reinterpret_cast<u32x2*>(&P1[n * 136 + c * 4]) =
        *reinterpret_cast<const u32x2*>(&rab[n * 100 + c * 4]);
  }
  for (int i = tid; i < 343; i += 256) {
    int n = i / 7, c = i % 7;
    *reinterpret_cast<u32x2*>(&P1[n * 136 + 100 + c * 4]) = zz;
  }
  const unsigned short* rvtg = refvT + (size_t)(rb * 16 + h) * 3200;
  for (int i = tid; i < 800; i += 256) {
    int d = i / 25, c = i % 25;
    *reinterpret_cast<u32x2*>(&rvT[d * 136 + c * 4]) =
        *reinterpret_cast<const u32x2*>(&rvtg[d * 100 + c * 4]);
  }
  for (int i = tid; i < 224; i += 256) {
    int d = i / 7, c = i % 7;
    *reinterpret_cast<u32x2*>(&rvT[d * 136 + 100 + c * 4]) = zz;
  }
  const unsigned short* kvb = kv + (size_t)b_ * 49 * 1024;
  for (int i = tid; i < 196; i += 256) {
    int m = i >> 2, c = i & 3;
    *reinterpret_cast<u32x4*>(&kb[m * 40 + c * 8]) =
        *reinterpret_cast<const u32x4*>(&kvb[m * 1024 + h * 32 + c * 8]);
  }
  __syncthreads();

  if (tid < 196) {
    int n = tid >> 2, q = tid & 3;
    unsigned short* row = P1 + n * 136;
    float mx = -1e30f;
    for (int r = q * 25; r < q * 25 + 25; r++) mx = fmaxf(mx, bf2f(row[r]));
    mx = fmaxf(mx, __shfl_xor(mx, 1));
    mx = fmaxf(mx, __shfl_xor(mx, 2));
    float sm = 0.f;
    for (int r = q * 25; r < q * 25 + 25; r++) {
      float e = __expf(bf2f(row[r]) - mx); sm += e; row[r] = f2bf(e);
    }
    sm += __shfl_xor(sm, 1);
    sm += __shfl_xor(sm, 2);
    float inv = 1.f / sm;
    for (int r = q * 25; r < q * 25 + 25; r++) row[r] = f2bf(bf2f(row[r]) * inv);
  }
  __syncthreads();

  f32x4 acc1[2] = {};
#pragma unroll
  for (int ks = 0; ks < 4; ks++) {
    short8 a = *reinterpret_cast<const short8*>(&P1[(wave * 16 + lrow) * 136 + ks * 32 + kq * 8]);
#pragma unroll
    for (int dt = 0; dt < 2; dt++) {
      short8 b = *reinterpret_cast<const short8*>(&rvT[(dt * 16 + lrow) * 136 + ks * 32 + kq * 8]);
      acc1[dt] = __builtin_amdgcn_mfma_f32_16x16x32_bf16(a, b, acc1[dt], 0, 0, 0);
    }
  }
#pragma unroll
  for (int dt = 0; dt < 2; dt++)
#pragma unroll
    for (int r = 0; r < 4; r++) {
      int n = wave * 16 + kq * 4 + r;
      qn[n * 40 + dt * 16 + lrow] = f2bf(acc1[dt][r] * 0.17677669529663688f);
    }
  __syncthreads();

  for (int i = tid; i < 196; i += 256) {
    int m = i >> 2, dg = (i & 3) * 8;
    ushort8 vv = *reinterpret_cast<const ushort8*>(&kvb[m * 1024 + 512 + h * 32 + dg]);
#pragma unroll
    for (int j = 0; j < 8; j++) vT[(dg + j) * 72 + m] = vv[j];
  }
  for (int i = tid; i < 480; i += 256) vT[(i / 15) * 72 + 49 + i % 15] = 0;

  const unsigned short* bt = maskB + (size_t)win * 2744;
  const unsigned short* rt = rpbT + (size_t)h * 2744;
  short8 aq = *reinterpret_cast<const short8*>(&qn[(wave * 16 + lrow) * 40 + kq * 8]);
  f32x4 zero = {};
  float val[4][4];
#pragma unroll
  for (int mt = 0; mt < 4; mt++) {
    short8 bk = *reinterpret_cast<const short8*>(&kb[(mt * 16 + lrow) * 40 + kq * 8]);
    f32x4 lg = __builtin_amdgcn_mfma_f32_16x16x32_bf16(aq, bk, zero, 0, 0, 0);
    int m = mt * 16 + lrow;
#pragma unroll
    for (int r = 0; r < 4; r++) {
      int n = wave * 16 + kq * 4 + r;
      float v;
      if (m < 49 && n < 49)
        v = lg[r] + bf2f(rt[n * 56 + m]) + bf2f(bt[n * 56 + m]);
      else v = -1e30f;
      val[mt][r] = v;
    }
  }
#pragma unroll
  for (int r = 0; r < 4; r++) {
    float mx = -1e30f;
#pragma unroll
    for (int mt = 0; mt < 4; mt++) mx = fmaxf(mx, val[mt][r]);
    mx = fmaxf(mx, __shfl_xor(mx, 1)); mx = fmaxf(mx, __shfl_xor(mx, 2));
    mx = fmaxf(mx, __shfl_xor(mx, 4)); mx = fmaxf(mx, __shfl_xor(mx, 8));
    float sm = 0.f, e[4];
#pragma unroll
    for (int mt = 0; mt < 4; mt++) { e[mt] = __expf(val[mt][r] - mx); sm += e[mt]; }
    sm += __shfl_xor(sm, 1); sm += __shfl_xor(sm, 2);
    sm += __shfl_xor(sm, 4); sm += __shfl_xor(sm, 8);
    float inv = 1.f / sm;
    int n = wave * 16 + kq * 4 + r;
#pragma unroll
    for (int mt = 0; mt < 4; mt++) P2[n * 72 + mt * 16 + lrow] = f2bf(e[mt] * inv);
  }
  __syncthreads();

  f32x4 acc2[2] = {};
#pragma unroll
  for (int ks = 0; ks < 2; ks++) {
    short8 ap = *reinterpret_cast<const short8*>(&P2[(wave * 16 + lrow) * 72 + ks * 32 + kq * 8]);
#pragma unroll
    for (int dt = 0; dt < 2; dt++) {
      short8 bv = *reinterpret_cast<const short8*>(&vT[(dt * 16 + lrow) * 72 + ks * 32 + kq * 8]);
      acc2[dt] = __builtin_amdgcn_mfma_f32_16x16x32_bf16(ap, bv, acc2[dt], 0, 0, 0);
    }
  }
  unsigned short* ab = att + (size_t)b_ * 49 * 512 + h * 32;
#pragma unroll
  for (int dt = 0; dt < 2; dt++)
#pragma unroll
    for (int r = 0; r < 4; r++) {
      int n = wave * 16 + kq * 4 + r;
      if (n < 49) ab[n * 512 + dt * 16 + lrow] = f2bf(acc2[dt][r]);
    }
}

// ---------------- window-reverse gather + residual + LN2 ----------------
__global__ __launch_bounds__(256) void resid_ln2_kernel(
    const float* __restrict__ x, const __hip_bfloat16* __restrict__ proj_out,
    const float* __restrict__ w2, const float* __restrict__ b2,
    float* __restrict__ out, __hip_bfloat16* __restrict__ hout) {
  int blk = blockIdx.x;               // b*12544 + l
  int bb = blk / 12544, l = blk % 12544;
  int hh = l / 112, ww = l % 112;
  int hs = (hh + 109) % 112, wsx = (ww + 109) % 112;   // (h-3) mod 112
  int t = (bb * 256 + (hs / 7) * 16 + (wsx / 7)) * 49 + (hs % 7) * 7 + (wsx % 7);
  const float* xr = x + (size_t)blk * 512;
  const __hip_bfloat16* pr = proj_out + (size_t)t * 512;
  int tid = threadIdx.x;
  float v0 = xr[tid] + __bfloat162float(pr[tid]);
  float v1 = xr[tid + 256] + __bfloat162float(pr[tid + 256]);
  float* orow = out + (size_t)blk * 512;
  orow[tid] = v0;
  orow[tid + 256] = v1;
  float s = v0 + v1, s2 = v0 * v0 + v1 * v1;
  block_reduce2(s, s2);
  float mu = s * (1.f / 512.f);
  float rstd = rsqrtf(s2 * (1.f / 512.f) - mu * mu + 1e-5f);
  __hip_bfloat16* hrow = hout + (size_t)blk * 512;
  hrow[tid]       = __float2bfloat16((v0 - mu) * rstd * w2[tid] + b2[tid]);
  hrow[tid + 256] = __float2bfloat16((v1 - mu) * rstd * w2[tid + 256] + b2[tid + 256]);
}

// =======================================================================
extern "C" void kernel_launch(void* const* d_in, const int* in_sizes, int n_in,
                              void* d_out, int out_size, void* d_ws, size_t ws_size,
                              hipStream_t stream) {
  const float* x       = (const float*)d_in[0];
  const float* x_ref   = (const float*)d_in[1];
  const float* mask    = (const float*)d_in[2];
  const float* n1w     = (const float*)d_in[3];
  const float* n1b     = (const float*)d_in[4];
  const float* qkv_w   = (const float*)d_in[5];
  const float* qkv_b   = (const float*)d_in[6];
  const float* diff_mu = (const float*)d_in[7];
  const float* diff_ls = (const float*)d_in[8];
  const float* rpb     = (const float*)d_in[9];
  const float* ref_w   = (const float*)d_in[10];
  const float* ref_b   = (const float*)d_in[11];
  const float* conv_w  = (const float*)d_in[12];
  const float* conv_b  = (const float*)d_in[13];
  const float* proj_w  = (const float*)d_in[14];
  const float* proj_b  = (const float*)d_in[15];
  const float* n2w     = (const float*)d_in[16];
  const float* n2b     = (const float*)d_in[17];
  const float* fc1_w   = (const float*)d_in[18];
  const float* fc1_b   = (const float*)d_in[19];
  const float* fc2_w   = (const float*)d_in[20];
  const float* fc2_b   = (const float*)d_in[21];
  float* out = (float*)d_out;

  char* ws = (char*)d_ws;
  size_t off = 0;
  auto alloc = [&](size_t bytes) -> char* {
    char* p = ws + off;
    off += (bytes + 255) & ~(size_t)255;
    return p;
  };
  // ---- persistent small buffers ----
  __hip_bfloat16* wq_bf = (__hip_bfloat16*)alloc(1536ULL * 512 * 2);   // q rows 0..511, kv rows 512..1535
  __hip_bfloat16* wp_bf = (__hip_bfloat16*)alloc(512ULL * 512 * 2);
  __hip_bfloat16* w1_bf = (__hip_bfloat16*)alloc(2048ULL * 512 * 2);
  __hip_bfloat16* w2_bf = (__hip_bfloat16*)alloc(512ULL * 2048 * 2);
  unsigned short* refq  = (unsigned short*)alloc(2ULL * 16 * 100 * 32 * 2);
  unsigned short* refvT = (unsigned short*)alloc(2ULL * 16 * 32 * 100 * 2);
  unsigned short* maskB = (unsigned short*)alloc(256ULL * 49 * 56 * 2);
  unsigned short* rpbT  = (unsigned short*)alloc(16ULL * 49 * 56 * 2);
  float* psum  = (float*)alloc(2ULL * 3136 * 16 * 4);
  float* psumq = (float*)alloc(2ULL * 3136 * 16 * 4);
  float* stats = (float*)alloc(64 * 4);
  // ---- aliased regions ----
  char* regX  = alloc(25088ULL * 512 * 2);      // xw_bf -> att_bf            (25.7 MB)
  char* regQ  = alloc(25088ULL * 512 * 2);      // q_bf  -> h_bf              (25.7 MB)
  char* regRA = alloc(2ULL * 16 * 12544 * 100 * 2);  // ra    -> hg (per-chunk) (80.3 MB)
  char* regU  = alloc(2ULL * 16 * 12544 * 100 * 2);  // u -> kv_bf + proj_bf    (80.3 MB)

  __hip_bfloat16* xw_bf   = (__hip_bfloat16*)regX;
  __hip_bfloat16* att_bf  = (__hip_bfloat16*)regX;                      // after kv GEMM
  __hip_bfloat16* q_bf    = (__hip_bfloat16*)regQ;
  __hip_bfloat16* h_bf    = (__hip_bfloat16*)regQ;                      // after ra_kernel
  __hip_bfloat16* ra      = (__hip_bfloat16*)regRA;
  __hip_bfloat16* hg      = (__hip_bfloat16*)regRA;                     // after attn (51.4MB/chunk)
  __hip_bfloat16* u       = (__hip_bfloat16*)regU;
  __hip_bfloat16* kv_bf   = (__hip_bfloat16*)regU;                      // after conv rounds (51.4MB)
  __hip_bfloat16* proj_bf = (__hip_bfloat16*)(regU + 51380224);         // after attn (25.7MB)

  // 1. weights -> bf16 ; bias tables
  f2b_kernel<<<3072, 256, 0, stream>>>(qkv_w, wq_bf, 786432);
  f2b_kernel<<<1024, 256, 0, stream>>>(proj_w, wp_bf, 262144);
  f2b_kernel<<<4096, 256, 0, stream>>>(fc1_w, w1_bf, 1048576);
  f2b_kernel<<<4096, 256, 0, stream>>>(fc2_w, w2_bf, 1048576);
  maskb_kernel<<<2744, 256, 0, stream>>>(mask, maskB);
  rpbt_kernel<<<172, 256, 0, stream>>>(rpb, rpbT);
  // 2. LN1 + shift + window partition
  ln1_window_kernel<<<25088, 256, 0, stream>>>(x, n1w, n1b, xw_bf);
  // 3. q GEMM (bias -> bf16)
  gemm_bt<1><<<dim3(196, 4), 256, 0, stream>>>(xw_bf, wq_bf, qkv_b, nullptr, q_bf,
                                               25088, 512, 512);
  // 4. reference tokens
  ref_kernel<<<200, 256, 0, stream>>>(x_ref, ref_w, ref_b, diff_mu, diff_ls, refq, refvT);
  // 5. ra = q @ ref_q^T (MFMA)
  ra_kernel<<<8192, 256, 0, stream>>>(q_bf, refq, ra);
  // 6. conv diffusion x3 (MFMA implicit GEMM, 4-row tiles)
  for (int rd = 0; rd < 3; rd++) {
    conv_kernel<<<dim3(3136, 2), 256, 0, stream>>>(ra, conv_w, conv_b, u, psum, psumq);
    conv_stats_kernel<<<32, 256, 0, stream>>>(psum, psumq, stats);
    conv_apply_kernel<<<4096, 256, 0, stream>>>(ra, u, stats);
  }
  // 7. kv GEMM into dead u region (xw still live as A input)
  gemm_bt<1><<<dim3(196, 8), 256, 0, stream>>>(xw_bf, wq_bf + 512 * 512, qkv_b + 512,
                                               nullptr, kv_bf, 25088, 1024, 512);
  // 8. fused MFMA attention (xw dead -> att_bf)
  attn_kernel<<<8192, 256, 0, stream>>>(ra, refvT, kv_bf, rpbT, maskB, att_bf);
  // 9. proj GEMM (bias -> bf16, into regU tail)
  gemm_bt<1><<<dim3(196, 4), 256, 0, stream>>>(att_bf, wp_bf, proj_b, nullptr, proj_bf,
                                               25088, 512, 512);
  // 10. window reverse + residual + LN2 (h_bf into dead q region)
  resid_ln2_kernel<<<25088, 256, 0, stream>>>(x, proj_bf, n2w, n2b, out, h_bf);
  // 11. MLP in two M-chunks; hg reuses dead ra region
  for (int ch = 0; ch < 2; ch++) {
    const __hip_bfloat16* hA = h_bf + (size_t)ch * 12544 * 512;
    gemm_bt<2><<<dim3(98, 16), 256, 0, stream>>>(hA, w1_bf, fc1_b, nullptr, hg,
                                                 12544, 2048, 512);
    gemm_bt<3><<<dim3(98, 4), 256, 0, stream>>>(hg, w2_bf, fc2_b,
                                                out + (size_t)ch * 12544 * 512, nullptr,
                                                12544, 512, 2048);
  }
}

// Round 9
// 1184.615 us; speedup vs baseline: 1.9137x; 1.0022x over previous
//
#include <hip/hip_runtime.h>
#include <hip/hip_bf16.h>

typedef __attribute__((ext_vector_type(8))) short short8;        // 8 bf16 = 4 VGPRs
typedef __attribute__((ext_vector_type(8))) unsigned short ushort8;
typedef __attribute__((ext_vector_type(4))) float f32x4;
typedef __attribute__((ext_vector_type(4))) unsigned int u32x4;
typedef __attribute__((ext_vector_type(2))) unsigned int u32x2;

#define DEV __device__ __forceinline__

DEV float gelu_f(float x) { return 0.5f * x * (1.f + erff(x * 0.70710678118654752440f)); }

DEV float bf2f(unsigned short s) {
  unsigned int t = ((unsigned int)s) << 16;
  float f; __builtin_memcpy(&f, &t, 4); return f;
}
DEV unsigned short f2bf(float f) {
  __hip_bfloat16 b = __float2bfloat16(f);
  unsigned short s; __builtin_memcpy(&s, &b, 2); return s;
}

// async global->LDS 16B/lane (dest = wave-uniform base + lane*16)
DEV void async_copy16(void* lds, const void* g) {
  __builtin_amdgcn_global_load_lds(
      (const __attribute__((address_space(1))) unsigned int*)g,
      (__attribute__((address_space(3))) unsigned int*)lds, 16, 0, 0);
}

// block-wide (256 thr) sum of two values; every thread gets the totals
DEV void block_reduce2(float& s, float& s2) {
  __shared__ float red[8];
  int tid = threadIdx.x;
#pragma unroll
  for (int o = 32; o > 0; o >>= 1) { s += __shfl_down(s, o); s2 += __shfl_down(s2, o); }
  if ((tid & 63) == 0) { red[tid >> 6] = s; red[4 + (tid >> 6)] = s2; }
  __syncthreads();
  s  = red[0] + red[1] + red[2] + red[3];
  s2 = red[4] + red[5] + red[6] + red[7];
}

// ---------------- weight fp32 -> bf16 ----------------
__global__ __launch_bounds__(256) void f2b_kernel(const float* __restrict__ in,
                                                  __hip_bfloat16* __restrict__ o, int n) {
  int i = blockIdx.x * 256 + threadIdx.x;
  if (i < n) o[i] = __float2bfloat16(in[i]);
}

// ---------------- mask -> bf16 padded [win][49][56] ----------------
__global__ __launch_bounds__(256) void maskb_kernel(const float* __restrict__ mask,
                                                    unsigned short* __restrict__ maskB) {
  int i = blockIdx.x * 256 + threadIdx.x;          // 256*49*56 = 702464 exactly
  int m = i % 56, rest = i / 56;
  int n = rest % 49, win = rest / 49;
  unsigned short v = 0;
  if (m < 49) v = f2bf(mask[((size_t)win * 49 + n) * 49 + m]);
  maskB[i] = v;
}

// ---------------- rpb -> bf16 padded [h][49][56] ----------------
__global__ __launch_bounds__(256) void rpbt_kernel(const float* __restrict__ rpb,
                                                   unsigned short* __restrict__ rpbT) {
  int i = blockIdx.x * 256 + threadIdx.x;          // 16*49*56 = 43904
  if (i >= 43904) return;
  int m = i % 56, rest = i / 56;
  int n = rest % 49, h = rest / 49;
  unsigned short v = 0;
  if (m < 49) {
    int rp = (n / 7 - m / 7 + 6) * 13 + (n % 7 - m % 7 + 6);
    v = f2bf(rpb[rp * 16 + h]);
  }
  rpbT[i] = v;
}

// ---------------- LN1 + cyclic shift + window partition -> bf16 ----------------
__global__ __launch_bounds__(256) void ln1_window_kernel(
    const float* __restrict__ x, const float* __restrict__ w, const float* __restrict__ b,
    __hip_bfloat16* __restrict__ xw) {
  int t = blockIdx.x;                 // 0..25087
  int b_ = t / 49, n = t % 49;
  int bb = b_ >> 8, win = b_ & 255;
  int wi = win >> 4, wj = win & 15;
  int ii = n / 7, jj = n % 7;
  int sh = (wi * 7 + ii + 3) % 112;
  int sw = (wj * 7 + jj + 3) % 112;
  const float* row = x + ((size_t)bb * 12544 + sh * 112 + sw) * 512;
  int tid = threadIdx.x;
  float v0 = row[tid], v1 = row[tid + 256];
  float s = v0 + v1, s2 = v0 * v0 + v1 * v1;
  block_reduce2(s, s2);
  float mu = s * (1.f / 512.f);
  float rstd = rsqrtf(s2 * (1.f / 512.f) - mu * mu + 1e-5f);
  __hip_bfloat16* orow = xw + (size_t)t * 512;
  orow[tid]       = __float2bfloat16((v0 - mu) * rstd * w[tid] + b[tid]);
  orow[tid + 256] = __float2bfloat16((v1 - mu) * rstd * w[tid + 256] + b[tid + 256]);
}

// ---------------- bf16 MFMA GEMM (global_load_lds staging): C = A @ B^T + bias ----------------
// EPI: 1 = bias -> bf16 store ; 2 = bias+gelu -> bf16 ; 3 = bias -> f32 +=
template <int EPI>
__global__ __launch_bounds__(256) void gemm_bt(
    const __hip_bfloat16* __restrict__ A, const __hip_bfloat16* __restrict__ B,
    const float* __restrict__ bias, float* __restrict__ outF,
    __hip_bfloat16* __restrict__ outB, int M, int N, int K) {
  __shared__ __align__(16) __hip_bfloat16 As[128 * 64];   // unpadded (global_load_lds layout)
  __shared__ __align__(16) __hip_bfloat16 Bs[128 * 64];
  int m0 = blockIdx.x * 128, n0 = blockIdx.y * 128;
  int tid = threadIdx.x;
  int wave = tid >> 6, lane = tid & 63;
  int wm = (wave & 1) * 64, wn = (wave >> 1) * 64;
  int lrow = lane & 15, kq = lane >> 4;
  int srow = lane >> 3, scol = (lane & 7) * 8;     // staging: 8 rows x 64 cols per wave-inst
  f32x4 acc[4][4] = {};
  for (int k0 = 0; k0 < K; k0 += 64) {
    int rb = wave * 32;
#pragma unroll
    for (int i = 0; i < 4; i++) {
      int row = rb + i * 8 + srow;
      async_copy16(&As[(rb + i * 8) * 64], &A[(size_t)(m0 + row) * K + k0 + scol]);
      async_copy16(&Bs[(rb + i * 8) * 64], &B[(size_t)(n0 + row) * K + k0 + scol]);
    }
    __syncthreads();
#pragma unroll
    for (int ks = 0; ks < 2; ks++) {
      short8 af[4], bf[4];
#pragma unroll
      for (int t = 0; t < 4; t++) {
        af[t] = *reinterpret_cast<const short8*>(&As[(wm + t * 16 + lrow) * 64 + ks * 32 + kq * 8]);
        bf[t] = *reinterpret_cast<const short8*>(&Bs[(wn + t * 16 + lrow) * 64 + ks * 32 + kq * 8]);
      }
#pragma unroll
      for (int tm = 0; tm < 4; tm++)
#pragma unroll
        for (int tn = 0; tn < 4; tn++)
          acc[tm][tn] = __builtin_amdgcn_mfma_f32_16x16x32_bf16(af[tm], bf[tn], acc[tm][tn], 0, 0, 0);
    }
    __syncthreads();
  }
  // D: row=(lane>>4)*4+r, col=lane&15 (verified gfx950 C/D layout)
#pragma unroll
  for (int tm = 0; tm < 4; tm++) {
#pragma unroll
    for (int tn = 0; tn < 4; tn++) {
      int col = n0 + wn + tn * 16 + lrow;
      float bv = bias[col];
#pragma unroll
      for (int r = 0; r < 4; r++) {
        int row = m0 + wm + tm * 16 + kq * 4 + r;
        float v = acc[tm][tn][r] + bv;
        size_t o = (size_t)row * N + col;
        if (EPI == 1) outB[o] = __float2bfloat16(v);
        else if (EPI == 2) outB[o] = __float2bfloat16(gelu_f(v));
        else outF[o] += v;
      }
    }
  }
}

// ---------------- reference-token projection (tiny) ----------------
__global__ __launch_bounds__(256) void ref_kernel(
    const float* __restrict__ x_ref, const float* __restrict__ w, const float* __restrict__ bias,
    const float* __restrict__ diff_mu, const float* __restrict__ diff_ls,
    unsigned short* __restrict__ refq, unsigned short* __restrict__ refvT) {
  int blk = blockIdx.x;               // 0..199
  int b = blk / 100, r = blk % 100;
  __shared__ float xs[512];
  int tid = threadIdx.x;
  const float* xr = x_ref + (size_t)(b * 100 + r) * 512;
  xs[tid] = xr[tid];
  xs[tid + 256] = xr[tid + 256];
  __syncthreads();
#pragma unroll
  for (int cc = 0; cc < 4; cc++) {
    int c = cc * 256 + tid;
    const float* wr = w + (size_t)c * 512;
    float s = bias[c];
    for (int k = 0; k < 512; k++) s += xs[k] * wr[k];
    if (c < 512) {
      float v = diff_mu[c] + expf(diff_ls[c]) * s;
      int hh = c >> 5, d = c & 31;
      refq[((size_t)(b * 16 + hh) * 100 + r) * 32 + d] = f2bf(v);
    } else {
      int c2 = c - 512, hh = c2 >> 5, d = c2 & 31;
      refvT[(((size_t)b * 16 + hh) * 32 + d) * 100 + r] = f2bf(s);
    }
  }
}

// ---------------- ra = q @ ref_q^T ; MFMA ; block per (b_, head) ----------------
__global__ __launch_bounds__(256) void ra_kernel(
    const __hip_bfloat16* __restrict__ q, const unsigned short* __restrict__ refq,
    __hip_bfloat16* __restrict__ ra) {
  __shared__ __align__(16) unsigned short q_s[64 * 40];
  __shared__ __align__(16) unsigned short rq_s[112 * 40];
  int blk = blockIdx.x;               // 8192
  int b_ = blk >> 4, h = blk & 15;
  int rb = b_ >> 8, win = b_ & 255;
  int tid = threadIdx.x;
  int wave = tid >> 6, lane = tid & 63;
  int lrow = lane & 15, kq = lane >> 4;
  u32x4 z4 = {};
  const unsigned short* qb = (const unsigned short*)q + (size_t)b_ * 49 * 512 + h * 32;
  for (int i = tid; i < 196; i += 256) {
    int n = i >> 2, c = i & 3;
    *reinterpret_cast<u32x4*>(&q_s[n * 40 + c * 8]) =
        *reinterpret_cast<const u32x4*>(&qb[n * 512 + c * 8]);
  }
  for (int i = tid; i < 60; i += 256) {
    int n = 49 + (i >> 2), c = i & 3;
    *reinterpret_cast<u32x4*>(&q_s[n * 40 + c * 8]) = z4;
  }
  const unsigned short* rqg = refq + (size_t)(rb * 16 + h) * 3200;
  for (int i = tid; i < 400; i += 256) {
    int r = i >> 2, c = i & 3;
    *reinterpret_cast<u32x4*>(&rq_s[r * 40 + c * 8]) =
        *reinterpret_cast<const u32x4*>(&rqg[r * 32 + c * 8]);
  }
  for (int i = tid; i < 48; i += 256) {
    int r = 100 + (i >> 2), c = i & 3;
    *reinterpret_cast<u32x4*>(&rq_s[r * 40 + c * 8]) = z4;
  }
  __syncthreads();
  short8 a = *reinterpret_cast<const short8*>(&q_s[(wave * 16 + lrow) * 40 + kq * 8]);
  unsigned short* ra_base = (unsigned short*)ra + ((size_t)(rb * 16 + h) * 12544 + win * 49) * 100;
  f32x4 zero = {};
#pragma unroll
  for (int nt = 0; nt < 7; nt++) {
    short8 b = *reinterpret_cast<const short8*>(&rq_s[(nt * 16 + lrow) * 40 + kq * 8]);
    f32x4 c = __builtin_amdgcn_mfma_f32_16x16x32_bf16(a, b, zero, 0, 0, 0);
    int col = nt * 16 + lrow;
#pragma unroll
    for (int r = 0; r < 4; r++) {
      int n = wave * 16 + kq * 4 + r;
      if (n < 49 && col < 100) ra_base[n * 100 + col] = f2bf(c[r]);
    }
  }
}

// ---------------- implicit-GEMM MFMA conv v4: 4-row tiles, 4 blocks/CU ----------------
__global__ __launch_bounds__(256) void conv_kernel(
    const __hip_bfloat16* __restrict__ ra_, const float* __restrict__ cw, const float* __restrict__ cb,
    __hip_bfloat16* __restrict__ u_, float* __restrict__ psum, float* __restrict__ psumsq) {
  __shared__ __align__(16) unsigned short in_s[6 * 103 * 24];    // 29,664 B
  __shared__ __align__(16) unsigned short w_s[16 * 160];         //  5,120 B
  __shared__ float sred_s[4][16], sred_s2[4][16];
  const unsigned short* ra = (const unsigned short*)ra_;
  unsigned short* u = (unsigned short*)u_;
  int yt = blockIdx.x, bb = blockIdx.y;
  int y0 = yt * 4;
  int tid = threadIdx.x;
  int wave = tid >> 6, lane = tid & 63;
  int lrow = lane & 15, kq = lane >> 4;
  for (int i = tid; i < 2560; i += 256) {
    int co = i / 160, k = i % 160;
    unsigned short v = 0;
    if (k < 144) {
      int ci = k & 15, p = k >> 4;
      v = f2bf(cw[(co * 16 + ci) * 9 + p]);
    }
    w_s[i] = v;
  }
  for (int i = tid; i < 288; i += 256) {
    int ci = i & 15, rem = i >> 4;
    int yl = rem / 3, xs = rem % 3;
    int xl = (xs == 0) ? 0 : (100 + xs);
    in_s[(yl * 103 + xl) * 24 + ci] = 0;
  }
  if (tid < 192) {
    int unit = tid >> 1, par = tid & 1;
    int ci = unit / 6, yl = unit % 6;
    int gy = y0 - 1 + yl;
    bool rv = (gy >= 0 && gy < 12544);
    const unsigned short* rp = ra + (((size_t)bb * 16 + ci) * 12544 + (rv ? gy : 0)) * 100;
    unsigned short* lp = &in_s[(yl * 103 + 1) * 24 + ci];
#pragma unroll 4
    for (int c = par; c < 25; c += 2) {
      u32x2 d = {0u, 0u};
      if (rv) d = *reinterpret_cast<const u32x2*>(&rp[c * 4]);
      lp[(c * 4 + 0) * 24] = (unsigned short)(d[0] & 0xffff);
      lp[(c * 4 + 1) * 24] = (unsigned short)(d[0] >> 16);
      lp[(c * 4 + 2) * 24] = (unsigned short)(d[1] & 0xffff);
      lp[(c * 4 + 3) * 24] = (unsigned short)(d[1] >> 16);
    }
  }
  __syncthreads();

  short8 afr[5];
#pragma unroll
  for (int c = 0; c < 5; c++)
    afr[c] = *reinterpret_cast<const short8*>(&w_s[lrow * 160 + c * 32 + kq * 8]);
  int kqh = kq >> 1, ci0 = (kq & 1) * 8;
  int kyA[5], kxA[5];
#pragma unroll
  for (int c = 0; c < 5; c++) {
    int p = c * 2 + kqh; if (p > 8) p = 0;
    kyA[c] = p / 3; kxA[c] = p % 3;
  }
  float bias_r[4];
#pragma unroll
  for (int r = 0; r < 4; r++) bias_r[r] = cb[kq * 4 + r];
  float s_r[4] = {0.f, 0.f, 0.f, 0.f}, s2_r[4] = {0.f, 0.f, 0.f, 0.f};

  int yl = wave;
  int gy = y0 + yl;
#pragma unroll
  for (int xg = 0; xg < 7; xg++) {
    int px = xg * 16 + lrow;
    int pxc = px < 100 ? px : 99;
    f32x4 acc = {};
#pragma unroll
    for (int c = 0; c < 5; c++) {
      short8 bfrag = *reinterpret_cast<const short8*>(
          &in_s[((yl + kyA[c]) * 103 + pxc + kxA[c]) * 24 + ci0]);
      acc = __builtin_amdgcn_mfma_f32_16x16x32_bf16(afr[c], bfrag, acc, 0, 0, 0);
    }
    bool valid = px < 100;
#pragma unroll
    for (int r = 0; r < 4; r++) {
      float v = acc[r] + bias_r[r];
      if (valid) {
        u[(((size_t)bb * 16 + kq * 4 + r) * 12544 + gy) * 100 + px] = f2bf(v);
        s_r[r] += v; s2_r[r] += v * v;
      }
    }
  }
#pragma unroll
  for (int o = 1; o < 16; o <<= 1)
#pragma unroll
    for (int r = 0; r < 4; r++) { s_r[r] += __shfl_xor(s_r[r], o); s2_r[r] += __shfl_xor(s2_r[r], o); }
  if (lrow == 0)
#pragma unroll
    for (int r = 0; r < 4; r++) { sred_s[wave][kq * 4 + r] = s_r[r]; sred_s2[wave][kq * 4 + r] = s2_r[r]; }
  __syncthreads();
  if (tid < 16) {
    float s  = sred_s[0][tid] + sred_s[1][tid] + sred_s[2][tid] + sred_s[3][tid];
    float s2 = sred_s2[0][tid] + sred_s2[1][tid] + sred_s2[2][tid] + sred_s2[3][tid];
    size_t pi = ((size_t)bb * 3136 + yt) * 16 + tid;
    psum[pi] = s; psumsq[pi] = s2;
  }
}

__global__ __launch_bounds__(256) void conv_stats_kernel(
    const float* __restrict__ psum, const float* __restrict__ psumsq, float* __restrict__ stats) {
  int g = blockIdx.x;                 // 32 = (b, co)
  int bb = g >> 4, co = g & 15;
  int tid = threadIdx.x;
  float s = 0.f, s2 = 0.f;
  for (int t = tid; t < 3136; t += 256) {
    size_t pi = ((size_t)bb * 3136 + t) * 16 + co;
    s += psum[pi];
    s2 += psumsq[pi];
  }
  block_reduce2(s, s2);
  if (tid == 0) {
    const float inv = 1.f / 1254400.f;
    float mu = s * inv;
    float var = s2 * inv - mu * mu;
    stats[g * 2] = mu;
    stats[g * 2 + 1] = rsqrtf(var + 1e-5f);
  }
}

__global__ __launch_bounds__(256) void conv_apply_kernel(
    __hip_bfloat16* __restrict__ ra, const __hip_bfloat16* __restrict__ u,
    const float* __restrict__ stats) {
  const int total8 = 5017600;         // 40,140,800 / 8
  int stride = gridDim.x * 256;
  for (int i = blockIdx.x * 256 + threadIdx.x; i < total8; i += stride) {
    int g = i / 156800;               // 1,254,400 / 8 per (b,ch) group
    float mu = stats[g * 2], rstd = stats[g * 2 + 1];
    ushort8 uu = reinterpret_cast<const ushort8*>(u)[i];
    ushort8 rr = reinterpret_cast<const ushort8*>(ra)[i];
    ushort8 oo;
#pragma unroll
    for (int j = 0; j < 8; j++) {
      float rv = bf2f(rr[j]) + gelu_f((bf2f(uu[j]) - mu) * rstd);
      oo[j] = f2bf(rv);
    }
    reinterpret_cast<ushort8*>(ra)[i] = oo;
  }
}

// ---------------- fused MFMA attention (FUSE=1: P1 = ra + gelu(norm(u)) on the fly) ----------------
template <int FUSE>
__global__ __launch_bounds__(256) void attn_kernel(
    const __hip_bfloat16* __restrict__ ra_, const __hip_bfloat16* __restrict__ u_,
    const float* __restrict__ stats, const unsigned short* __restrict__ refvT,
    const __hip_bfloat16* __restrict__ kv_, const unsigned short* __restrict__ rpbT,
    const unsigned short* __restrict__ maskB, __hip_bfloat16* __restrict__ att_) {
  __shared__ __align__(16) char smem[36608];
  unsigned short* P1  = (unsigned short*)smem;              // stride 136
  unsigned short* rvT = (unsigned short*)(smem + 17408);    // stride 136
  unsigned short* P2  = (unsigned short*)smem;              // stride 72
  unsigned short* vT  = (unsigned short*)(smem + 9216);     // stride 72
  unsigned short* qn  = (unsigned short*)(smem + 26112);    // stride 40
  unsigned short* kb  = (unsigned short*)(smem + 31232);    // stride 40
  float* lsum         = (float*)(smem + 36352);             // 64 floats

  int blk = blockIdx.x;               // 8192
  int b_ = blk >> 4, h = blk & 15;
  int rb = b_ >> 8, win = b_ & 255;
  int tid = threadIdx.x;
  int wave = tid >> 6, lane = tid & 63;
  int lrow = lane & 15, kq = lane >> 4;
  const unsigned short* ra = (const unsigned short*)ra_;
  const unsigned short* ug = (const unsigned short*)u_;
  const unsigned short* kv = (const unsigned short*)kv_;
  unsigned short* att = (unsigned short*)att_;
  u32x2 zz = {};

  if (tid < 64) lsum[tid] = 1.0f;
  float mu = 0.f, rstd = 0.f;
  if (FUSE) { mu = stats[(rb * 16 + h) * 2]; rstd = stats[(rb * 16 + h) * 2 + 1]; }

  const size_t tile_off = ((size_t)(rb * 16 + h) * 12544 + win * 49) * 100;
  const unsigned short* rab = ra + tile_off;
  const unsigned short* uab = ug + tile_off;
  for (int i = tid; i < 1225; i += 256) {
    int n = i / 25, c = i % 25;
    u32x2 rv = *reinterpret_cast<const u32x2*>(&rab[n * 100 + c * 4]);
    if (FUSE) {
      u32x2 uv = *reinterpret_cast<const u32x2*>(&uab[n * 100 + c * 4]);
      unsigned short rr4[4] = {(unsigned short)(rv[0] & 0xffff), (unsigned short)(rv[0] >> 16),
                               (unsigned short)(rv[1] & 0xffff), (unsigned short)(rv[1] >> 16)};
      unsigned short uu4[4] = {(unsigned short)(uv[0] & 0xffff), (unsigned short)(uv[0] >> 16),
                               (unsigned short)(uv[1] & 0xffff), (unsigned short)(uv[1] >> 16)};
      unsigned short o4[4];
#pragma unroll
      for (int j = 0; j < 4; j++)
        o4[j] = f2bf(bf2f(rr4[j]) + gelu_f((bf2f(uu4[j]) - mu) * rstd));
      u32x2 w;
      w[0] = (unsigned int)o4[0] | ((unsigned int)o4[1] << 16);
      w[1] = (unsigned int)o4[2] | ((unsigned int)o4[3] << 16);
      *reinterpret_cast<u32x2*>(&P1[n * 136 + c * 4]) = w;
    } else {
      *reinterpret_cast<u32x2*>(&P1[n * 136 + c * 4]) = rv;
    }
  }
  for (int i = tid; i < 343; i += 256) {
    int n = i / 7, c = i % 7;
    *reinterpret_cast<u32x2*>(&P1[n * 136 + 100 + c * 4]) = zz;
  }
  const unsigned short* rvtg = refvT + (size_t)(rb * 16 + h) * 3200;
  for (int i = tid; i < 800; i += 256) {
    int d = i / 25, c = i % 25;
    *reinterpret_cast<u32x2*>(&rvT[d * 136 + c * 4]) =
        *reinterpret_cast<const u32x2*>(&rvtg[d * 100 + c * 4]);
  }
  for (int i = tid; i < 224; i += 256) {
    int d = i / 7, c = i % 7;
    *reinterpret_cast<u32x2*>(&rvT[d * 136 + 100 + c * 4]) = zz;
  }
  const unsigned short* kvb = kv + (size_t)b_ * 49 * 1024;
  for (int i = tid; i < 196; i += 256) {
    int m = i >> 2, c = i & 3;
    *reinterpret_cast<u32x4*>(&kb[m * 40 + c * 8]) =
        *reinterpret_cast<const u32x4*>(&kvb[m * 1024 + h * 32 + c * 8]);
  }
  __syncthreads();

  // ---- register softmax over 100 ref slots; store raw e, defer 1/l to qn epilogue ----
  if (tid < 196) {
    int n = tid >> 2, q = tid & 3;
    unsigned short* row = P1 + n * 136 + q * 25;
    float e[25];
#pragma unroll
    for (int r = 0; r < 25; r++) e[r] = bf2f(row[r]);
    float mx = -1e30f;
#pragma unroll
    for (int r = 0; r < 25; r++) mx = fmaxf(mx, e[r]);
    mx = fmaxf(mx, __shfl_xor(mx, 1));
    mx = fmaxf(mx, __shfl_xor(mx, 2));
    float sm = 0.f;
#pragma unroll
    for (int r = 0; r < 25; r++) { e[r] = __expf(e[r] - mx); sm += e[r]; }
    sm += __shfl_xor(sm, 1);
    sm += __shfl_xor(sm, 2);
#pragma unroll
    for (int r = 0; r < 25; r++) row[r] = f2bf(e[r]);
    if (q == 0) lsum[n] = sm;
  }
  __syncthreads();

  // ---- qnew = P1 @ rvT^T  (M=64, N=32, K=128); scale = SCALE / l_n ----
  f32x4 acc1[2] = {};
#pragma unroll
  for (int ks = 0; ks < 4; ks++) {
    short8 a = *reinterpret_cast<const short8*>(&P1[(wave * 16 + lrow) * 136 + ks * 32 + kq * 8]);
#pragma unroll
    for (int dt = 0; dt < 2; dt++) {
      short8 b = *reinterpret_cast<const short8*>(&rvT[(dt * 16 + lrow) * 136 + ks * 32 + kq * 8]);
      acc1[dt] = __builtin_amdgcn_mfma_f32_16x16x32_bf16(a, b, acc1[dt], 0, 0, 0);
    }
  }
  float invl[4];
#pragma unroll
  for (int r = 0; r < 4; r++)
    invl[r] = 0.17677669529663688f / lsum[wave * 16 + kq * 4 + r];
#pragma unroll
  for (int dt = 0; dt < 2; dt++)
#pragma unroll
    for (int r = 0; r < 4; r++) {
      int n = wave * 16 + kq * 4 + r;
      qn[n * 40 + dt * 16 + lrow] = f2bf(acc1[dt][r] * invl[r]);
    }
  __syncthreads();

  // ---- phase B: stage v^T via register transpose ----
  for (int i = tid; i < 196; i += 256) {
    int m = i >> 2, dg = (i & 3) * 8;
    ushort8 vv = *reinterpret_cast<const ushort8*>(&kvb[m * 1024 + 512 + h * 32 + dg]);
#pragma unroll
    for (int j = 0; j < 8; j++) vT[(dg + j) * 72 + m] = vv[j];
  }
  for (int i = tid; i < 480; i += 256) vT[(i / 15) * 72 + 49 + i % 15] = 0;

  // ---- logits = qn @ kb^T (N=64, K=32), +rpb+mask, register softmax ----
  const unsigned short* bt = maskB + (size_t)win * 2744;
  const unsigned short* rt = rpbT + (size_t)h * 2744;
  short8 aq = *reinterpret_cast<const short8*>(&qn[(wave * 16 + lrow) * 40 + kq * 8]);
  f32x4 zero = {};
  float val[4][4];
#pragma unroll
  for (int mt = 0; mt < 4; mt++) {
    short8 bk = *reinterpret_cast<const short8*>(&kb[(mt * 16 + lrow) * 40 + kq * 8]);
    f32x4 lg = __builtin_amdgcn_mfma_f32_16x16x32_bf16(aq, bk, zero, 0, 0, 0);
    int m = mt * 16 + lrow;
#pragma unroll
    for (int r = 0; r < 4; r++) {
      int n = wave * 16 + kq * 4 + r;
      float v;
      if (m < 49 && n < 49)
        v = lg[r] + bf2f(rt[n * 56 + m]) + bf2f(bt[n * 56 + m]);
      else v = -1e30f;
      val[mt][r] = v;
    }
  }
#pragma unroll
  for (int r = 0; r < 4; r++) {
    float mx = -1e30f;
#pragma unroll
    for (int mt = 0; mt < 4; mt++) mx = fmaxf(mx, val[mt][r]);
    mx = fmaxf(mx, __shfl_xor(mx, 1)); mx = fmaxf(mx, __shfl_xor(mx, 2));
    mx = fmaxf(mx, __shfl_xor(mx, 4)); mx = fmaxf(mx, __shfl_xor(mx, 8));
    float sm = 0.f, e[4];
#pragma unroll
    for (int mt = 0; mt < 4; mt++) { e[mt] = __expf(val[mt][r] - mx); sm += e[mt]; }
    sm += __shfl_xor(sm, 1); sm += __shfl_xor(sm, 2);
    sm += __shfl_xor(sm, 4); sm += __shfl_xor(sm, 8);
    float inv = 1.f / sm;
    int n = wave * 16 + kq * 4 + r;
#pragma unroll
    for (int mt = 0; mt < 4; mt++) P2[n * 72 + mt * 16 + lrow] = f2bf(e[mt] * inv);
  }
  __syncthreads();

  // ---- out = P2 @ vT^T (N=32, K=64) -> global bf16 ----
  f32x4 acc2[2] = {};
#pragma unroll
  for (int ks = 0; ks < 2; ks++) {
    short8 ap = *reinterpret_cast<const short8*>(&P2[(wave * 16 + lrow) * 72 + ks * 32 + kq * 8]);
#pragma unroll
    for (int dt = 0; dt < 2; dt++) {
      short8 bv = *reinterpret_cast<const short8*>(&vT[(dt * 16 + lrow) * 72 + ks * 32 + kq * 8]);
      acc2[dt] = __builtin_amdgcn_mfma_f32_16x16x32_bf16(ap, bv, acc2[dt], 0, 0, 0);
    }
  }
  unsigned short* ab = att + (size_t)b_ * 49 * 512 + h * 32;
#pragma unroll
  for (int dt = 0; dt < 2; dt++)
#pragma unroll
    for (int r = 0; r < 4; r++) {
      int n = wave * 16 + kq * 4 + r;
      if (n < 49) ab[n * 512 + dt * 16 + lrow] = f2bf(acc2[dt][r]);
    }
}

// ---------------- window-reverse gather + residual + LN2 ----------------
__global__ __launch_bounds__(256) void resid_ln2_kernel(
    const float* __restrict__ x, const __hip_bfloat16* __restrict__ proj_out,
    const float* __restrict__ w2, const float* __restrict__ b2,
    float* __restrict__ out, __hip_bfloat16* __restrict__ hout) {
  int blk = blockIdx.x;               // b*12544 + l
  int bb = blk / 12544, l = blk % 12544;
  int hh = l / 112, ww = l % 112;
  int hs = (hh + 109) % 112, wsx = (ww + 109) % 112;   // (h-3) mod 112
  int t = (bb * 256 + (hs / 7) * 16 + (wsx / 7)) * 49 + (hs % 7) * 7 + (wsx % 7);
  const float* xr = x + (size_t)blk * 512;
  const __hip_bfloat16* pr = proj_out + (size_t)t * 512;
  int tid = threadIdx.x;
  float v0 = xr[tid] + __bfloat162float(pr[tid]);
  float v1 = xr[tid + 256] + __bfloat162float(pr[tid + 256]);
  float* orow = out + (size_t)blk * 512;
  orow[tid] = v0;
  orow[tid + 256] = v1;
  float s = v0 + v1, s2 = v0 * v0 + v1 * v1;
  block_reduce2(s, s2);
  float mu = s * (1.f / 512.f);
  float rstd = rsqrtf(s2 * (1.f / 512.f) - mu * mu + 1e-5f);
  __hip_bfloat16* hrow = hout + (size_t)blk * 512;
  hrow[tid]       = __float2bfloat16((v0 - mu) * rstd * w2[tid] + b2[tid]);
  hrow[tid + 256] = __float2bfloat16((v1 - mu) * rstd * w2[tid + 256] + b2[tid + 256]);
}

// =======================================================================
extern "C" void kernel_launch(void* const* d_in, const int* in_sizes, int n_in,
                              void* d_out, int out_size, void* d_ws, size_t ws_size,
                              hipStream_t stream) {
  const float* x       = (const float*)d_in[0];
  const float* x_ref   = (const float*)d_in[1];
  const float* mask    = (const float*)d_in[2];
  const float* n1w     = (const float*)d_in[3];
  const float* n1b     = (const float*)d_in[4];
  const float* qkv_w   = (const float*)d_in[5];
  const float* qkv_b   = (const float*)d_in[6];
  const float* diff_mu = (const float*)d_in[7];
  const float* diff_ls = (const float*)d_in[8];
  const float* rpb     = (const float*)d_in[9];
  const float* ref_w   = (const float*)d_in[10];
  const float* ref_b   = (const float*)d_in[11];
  const float* conv_w  = (const float*)d_in[12];
  const float* conv_b  = (const float*)d_in[13];
  const float* proj_w  = (const float*)d_in[14];
  const float* proj_b  = (const float*)d_in[15];
  const float* n2w     = (const float*)d_in[16];
  const float* n2b     = (const float*)d_in[17];
  const float* fc1_w   = (const float*)d_in[18];
  const float* fc1_b   = (const float*)d_in[19];
  const float* fc2_w   = (const float*)d_in[20];
  const float* fc2_b   = (const float*)d_in[21];
  float* out = (float*)d_out;

  char* ws = (char*)d_ws;
  size_t off = 0;
  auto alloc = [&](size_t bytes) -> char* {
    char* p = ws + off;
    off += (bytes + 255) & ~(size_t)255;
    return p;
  };
  // ---- persistent small buffers ----
  __hip_bfloat16* wq_bf = (__hip_bfloat16*)alloc(1536ULL * 512 * 2);   // q rows 0..511, kv rows 512..1535
  __hip_bfloat16* wp_bf = (__hip_bfloat16*)alloc(512ULL * 512 * 2);
  __hip_bfloat16* w1_bf = (__hip_bfloat16*)alloc(2048ULL * 512 * 2);
  __hip_bfloat16* w2_bf = (__hip_bfloat16*)alloc(512ULL * 2048 * 2);
  unsigned short* refq  = (unsigned short*)alloc(2ULL * 16 * 100 * 32 * 2);
  unsigned short* refvT = (unsigned short*)alloc(2ULL * 16 * 32 * 100 * 2);
  unsigned short* maskB = (unsigned short*)alloc(256ULL * 49 * 56 * 2);
  unsigned short* rpbT  = (unsigned short*)alloc(16ULL * 49 * 56 * 2);
  float* psum  = (float*)alloc(2ULL * 3136 * 16 * 4);
  float* psumq = (float*)alloc(2ULL * 3136 * 16 * 4);
  float* stats = (float*)alloc(64 * 4);
  // ---- aliased regions ----
  char* regX  = alloc(25088ULL * 512 * 2);      // xw_bf -> att_bf            (25.7 MB)
  char* regQ  = alloc(25088ULL * 512 * 2);      // q_bf  -> h_bf              (25.7 MB)
  char* regRA = alloc(2ULL * 16 * 12544 * 100 * 2);  // ra    -> hg (per-chunk) (80.3 MB)
  char* regU  = alloc(2ULL * 16 * 12544 * 100 * 2);  // u -> (kv_bf) + proj_bf  (80.3 MB)

  __hip_bfloat16* xw_bf   = (__hip_bfloat16*)regX;
  __hip_bfloat16* att_bf  = (__hip_bfloat16*)regX;                      // after kv GEMM
  __hip_bfloat16* q_bf    = (__hip_bfloat16*)regQ;
  __hip_bfloat16* h_bf    = (__hip_bfloat16*)regQ;                      // after ra_kernel
  __hip_bfloat16* ra      = (__hip_bfloat16*)regRA;
  __hip_bfloat16* hg      = (__hip_bfloat16*)regRA;                     // after attn (51.4MB/chunk)
  __hip_bfloat16* u       = (__hip_bfloat16*)regU;
  __hip_bfloat16* proj_bf = (__hip_bfloat16*)(regU + 51380224);         // after attn (25.7MB)

  // fused path needs u live through attn -> kv in a dedicated region if ws allows
  const size_t kv_bytes = 25088ULL * 1024 * 2;   // 51.4 MB
  bool fused = (ws_size >= off + kv_bytes);
  __hip_bfloat16* kv_bf = fused ? (__hip_bfloat16*)alloc(kv_bytes)
                                : (__hip_bfloat16*)regU;   // classic: aliases dead u

  // 1. weights -> bf16 ; bias tables
  f2b_kernel<<<3072, 256, 0, stream>>>(qkv_w, wq_bf, 786432);
  f2b_kernel<<<1024, 256, 0, stream>>>(proj_w, wp_bf, 262144);
  f2b_kernel<<<4096, 256, 0, stream>>>(fc1_w, w1_bf, 1048576);
  f2b_kernel<<<4096, 256, 0, stream>>>(fc2_w, w2_bf, 1048576);
  maskb_kernel<<<2744, 256, 0, stream>>>(mask, maskB);
  rpbt_kernel<<<172, 256, 0, stream>>>(rpb, rpbT);
  // 2. LN1 + shift + window partition
  ln1_window_kernel<<<25088, 256, 0, stream>>>(x, n1w, n1b, xw_bf);
  // 3. q GEMM (bias -> bf16)
  gemm_bt<1><<<dim3(196, 4), 256, 0, stream>>>(xw_bf, wq_bf, qkv_b, nullptr, q_bf,
                                               25088, 512, 512);
  // 4. reference tokens
  ref_kernel<<<200, 256, 0, stream>>>(x_ref, ref_w, ref_b, diff_mu, diff_ls, refq, refvT);
  // 5. ra = q @ ref_q^T (MFMA)
  ra_kernel<<<8192, 256, 0, stream>>>(q_bf, refq, ra);
  // 6. conv diffusion x3 (apply of round 3 folded into attn when fused)
  for (int rd = 0; rd < 3; rd++) {
    conv_kernel<<<dim3(3136, 2), 256, 0, stream>>>(ra, conv_w, conv_b, u, psum, psumq);
    conv_stats_kernel<<<32, 256, 0, stream>>>(psum, psumq, stats);
    if (rd < 2 || !fused)
      conv_apply_kernel<<<4096, 256, 0, stream>>>(ra, u, stats);
  }
  // 7. kv GEMM (dedicated region when fused; else dead-u alias)
  gemm_bt<1><<<dim3(196, 8), 256, 0, stream>>>(xw_bf, wq_bf + 512 * 512, qkv_b + 512,
                                               nullptr, kv_bf, 25088, 1024, 512);
  // 8. fused MFMA attention (xw dead -> att_bf)
  if (fused)
    attn_kernel<1><<<8192, 256, 0, stream>>>(ra, u, stats, refvT, kv_bf, rpbT, maskB, att_bf);
  else
    attn_kernel<0><<<8192, 256, 0, stream>>>(ra, u, stats, refvT, kv_bf, rpbT, maskB, att_bf);
  // 9. proj GEMM (bias -> bf16, into regU tail; u dead after attn)
  gemm_bt<1><<<dim3(196, 4), 256, 0, stream>>>(att_bf, wp_bf, proj_b, nullptr, proj_bf,
                                               25088, 512, 512);
  // 10. window reverse + residual + LN2 (h_bf into dead q region)
  resid_ln2_kernel<<<25088, 256, 0, stream>>>(x, proj_bf, n2w, n2b, out, h_bf);
  // 11. MLP in two M-chunks; hg reuses dead ra region
  for (int ch = 0; ch < 2; ch++) {
    const __hip_bfloat16* hA = h_bf + (size_t)ch * 12544 * 512;
    gemm_bt<2><<<dim3(98, 16), 256, 0, stream>>>(hA, w1_bf, fc1_b, nullptr, hg,
                                                 12544, 2048, 512);
    gemm_bt<3><<<dim3(98, 4), 256, 0, stream>>>(hg, w2_bf, fc2_b,
                                                out + (size_t)ch * 12544 * 512, nullptr,
                                                12544, 512, 2048);
  }
}